// Round 15
// baseline (736.531 us; speedup 1.0000x reference)
//
#include <hip/hip_runtime.h>
#include <hip/hip_bf16.h>
#include <math.h>

#define B_TOT 512
#define SEQ   200
#define D     128
#define DH    256
#define DFF   512
#define LPAD  256
#define PADL  56
#define NLAY  2
#define SST   18   // scan LDS row stride (floats)

typedef __attribute__((ext_vector_type(8))) short bf16x8;
typedef __attribute__((ext_vector_type(4))) float floatx4;

static __device__ inline float bf2f(ushort u) {
    union { unsigned int i; float f; } v; v.i = ((unsigned int)u) << 16; return v.f;
}
static __device__ inline ushort f2bf(float x) {
    union { float f; unsigned int i; } v; v.f = x;
    unsigned int r = (v.i + 0x7FFFu + ((v.i >> 16) & 1u)) >> 16;   // RNE
    return (ushort)r;
}
// HW packed f32x2 -> bf16x2 (v_cvt_pk_bf16_f32 on gfx950), RNE
static __device__ inline unsigned int pkbf(float a, float b) {
    union { __hip_bfloat162 h; unsigned int u; } v;
    v.h = __float22bfloat162_rn(make_float2(a, b));
    return v.u;
}

// H layout: [b][g(8)][p(re/im)][s(200)][32 ch] bf16. k in 0..511: k<256 re, else im.
static __device__ inline size_t haddr(int b, int s, int k) {
    int p  = k >> 8;
    int ch = k & 255;
    int g  = ch >> 5;
    int cl = ch & 31;
    return (((((size_t)b * 8 + g) * 2 + p) * SEQ + s) * 32 + cl);
}

// ---------------------------------------------------------------------------
// lambda powers (TRANSPOSED: [ch][128] float2, entry j = lambda^{j+1})
// + in-proj epilogue scale/bias
// ---------------------------------------------------------------------------
__global__ void setup_params_kernel(const float* __restrict__ params_log,
                                    const float* __restrict__ in_br,
                                    const float* __restrict__ in_bi,
                                    float* __restrict__ lam_pow,   // [NLAY][256][128] float2
                                    float* __restrict__ scale_in,  // [NLAY][512]
                                    float* __restrict__ bias_in)   // [NLAY][512]
{
    int li = blockIdx.x;
    int c  = threadIdx.x;             // 256 threads
    const float* pl = params_log + (size_t)li * 3 * DH;
    float nu = expf(pl[c]);
    float th = expf(pl[DH + c]);
    float ga = expf(pl[2 * DH + c]);
    float mag = expf(-nu);
    float lr = mag * cosf(th);
    float lim = mag * sinf(th);
    float2* lp = (float2*)(lam_pow + (size_t)li * 65536) + (size_t)c * 128;
    float pr = lr, pi = lim;
    lp[0] = make_float2(pr, pi);
    for (int k = 1; k < 128; ++k) {
        float nr = pr * lr - pi * lim;
        float ni = pr * lim + pi * lr;
        pr = nr; pi = ni;
        lp[k] = make_float2(pr, pi);
    }
    scale_in[li * 2 * DH + c]      = ga;
    scale_in[li * 2 * DH + DH + c] = ga;
    bias_in[li * 2 * DH + c]       = in_br[li * DH + c] * ga;
    bias_in[li * 2 * DH + DH + c]  = in_bi[li * DH + c] * ga;
}

__global__ void setup_weights_kernel(const float* __restrict__ in_wr,
                                     const float* __restrict__ in_wi,
                                     const float* __restrict__ out_wr,
                                     const float* __restrict__ out_wi,
                                     const float* __restrict__ w1,
                                     const float* __restrict__ w2,
                                     ushort* __restrict__ Winb,
                                     ushort* __restrict__ W2effb,
                                     ushort* __restrict__ w1b,
                                     ushort* __restrict__ w2b)
{
    int idx = blockIdx.x * blockDim.x + threadIdx.x;   // NLAY*65536
    int li = idx >> 16;
    int r  = idx & 65535;

    int n = r >> 7, d = r & 127;
    float wv = (n < DH) ? in_wr[((size_t)li * DH + n) * D + d]
                        : in_wi[((size_t)li * DH + (n - DH)) * D + d];
    Winb[idx] = f2bf(wv);

    int dd = r >> 9, cc = r & 511;
    float w2v = (cc < DH) ? out_wr[((size_t)li * D + dd) * DH + cc]
                          : -out_wi[((size_t)li * D + dd) * DH + (cc - DH)];
    W2effb[idx] = f2bf(w2v);

    w1b[idx] = f2bf(w1[idx]);
    w2b[idx] = f2bf(w2[idx]);
}

// ---------------------------------------------------------------------------
// Embedding gather + LayerNorm -> bf16 x
// ---------------------------------------------------------------------------
__global__ __launch_bounds__(256) void embed_ln_kernel(
    const float* __restrict__ emb, const int* __restrict__ seq,
    const float* __restrict__ g, const float* __restrict__ bt,
    ushort* __restrict__ x)
{
    int row  = blockIdx.x * 4 + (threadIdx.x >> 6);
    int lane = threadIdx.x & 63;
    int item = seq[row];
    float2 v = *(const float2*)(emb + (size_t)item * D + lane * 2);
    float s = v.x + v.y;
#pragma unroll
    for (int o = 32; o > 0; o >>= 1) s += __shfl_xor(s, o);
    float mu = s * (1.0f / D);
    float d0 = v.x - mu, d1 = v.y - mu;
    float vs = d0 * d0 + d1 * d1;
#pragma unroll
    for (int o = 32; o > 0; o >>= 1) vs += __shfl_xor(vs, o);
    float rstd = rsqrtf(vs * (1.0f / D) + 1e-5f);
    float2 gg = *(const float2*)(g + lane * 2);
    float2 bb = *(const float2*)(bt + lane * 2);
    unsigned int o2 = pkbf(d0 * rstd * gg.x + bb.x, d1 * rstd * gg.y + bb.y);
    *(unsigned int*)(x + (size_t)row * D + lane * 2) = o2;
}

// ---------------------------------------------------------------------------
// FUSED in-proj + exact tree scan, two-stage x staging (R14 known-good).
// Grid = (gp, b): gp fast -> blocks sharing x[b] are dispatch-adjacent.
// ---------------------------------------------------------------------------
__global__ __launch_bounds__(512) void inproj_scan_kernel(
    const ushort* __restrict__ X, const ushort* __restrict__ Win,
    ushort* __restrict__ H, const float2* __restrict__ lamT,
    const int* __restrict__ seq,
    const float* __restrict__ scale_in, const float* __restrict__ bias_in)
{
    __shared__ __align__(16) char smem[36864];   // Ws 8192 + xs 28672 (phase A)
    __shared__ float mkf[LPAD];
    char*  Wsm = smem;                           // [32][128] bf16, swizzled
    char*  xs  = smem + 8192;                    // [112][128] bf16, swizzled
    float* stR = (float*)smem;                   // [256][SST] (phase B alias)
    float* stI = stR + LPAD * SST;               // ends at 36864 B
    float2* lamS = (float2*)smem;                // [16][130] (tree phase alias)
    float2* bc   = (float2*)(smem + 16 * 130 * 8);

    int gp = blockIdx.x, b = blockIdx.y;
    int tid = threadIdx.x;
    int l = tid & 63, w = tid >> 6;              // 8 waves
    int ct = w & 1;                              // 0=re tile, 1=im tile
    int rq = w >> 1;                             // row quarter 0..3
    int lr = l & 15, lq = l >> 4;

    int c  = tid & 15;                           // scan channel
    int tl = tid >> 4;                           // 0..31
    int t0 = tl * 8;

    const float2* myl = lamT + (size_t)(gp * 16 + c) * 128;
    float2 l14[4];
#pragma unroll
    for (int k = 0; k < 4; ++k) l14[k] = myl[k];

    if (tid < LPAD) {
        int t = tid;
        float m = 0.f;
        if (t >= PADL) m = (seq[(size_t)b * SEQ + (t - PADL)] > 0) ? 1.f : 0.f;
        mkf[t] = m;
    }

    // ---- Phase A: stage Ws + x stage A (rows 0..111)
    const ushort* xrow = X + (size_t)b * SEQ * 128;
    {
        int r = tid >> 4, c16 = tid & 15;
        int n = (r < 16) ? (gp * 16 + r) : (256 + gp * 16 + (r - 16));
        uint4 v = *(const uint4*)(Win + (size_t)n * 128 + c16 * 8);
        *(uint4*)(Wsm + r * 256 + ((c16 ^ (r & 7)) * 16)) = v;
    }
#pragma unroll
    for (int it = 0; it < 4; ++it) {
        int idx = it * 512 + tid;
        if (idx < 112 * 16) {
            int r = idx >> 4, c16 = idx & 15;
            uint4 v = *(const uint4*)(xrow + (size_t)r * 128 + c16 * 8);
            *(uint4*)(xs + r * 256 + ((c16 ^ (r & 7)) * 16)) = v;
        }
    }
    __syncthreads();

    bf16x8 wf[4];
#pragma unroll
    for (int kk = 0; kk < 4; ++kk) {
        int ca = kk * 4 + lq;
        int wr = ct * 16 + lr;
        wf[kk] = *(const bf16x8*)(Wsm + wr * 256 + ((ca ^ (wr & 7)) * 16));
    }
    int tstart = rq ? (3 * rq + 1) : 0;          // 0 / 4 / 7 / 10
    int tcnt   = rq ? 3 : 4;
    floatx4 acc[4];
#pragma unroll
    for (int tt = 0; tt < 4; ++tt) acc[tt] = (floatx4)0.f;

    if (rq < 2) {
#pragma unroll
        for (int tt = 0; tt < 4; ++tt) {
            if (tt < tcnt) {
                int t  = tstart + tt;
                int ar = t * 16 + lr;
#pragma unroll
                for (int kk = 0; kk < 4; ++kk) {
                    int ca = kk * 4 + lq;
                    bf16x8 af = *(const bf16x8*)(xs + ar * 256 + ((ca ^ (ar & 7)) * 16));
                    acc[tt] = __builtin_amdgcn_mfma_f32_16x16x32_bf16(wf[kk], af, acc[tt], 0, 0, 0);
                }
            }
        }
    }
    __syncthreads();

#pragma unroll
    for (int it = 0; it < 3; ++it) {
        int idx = it * 512 + tid;                // exactly 96*16 = 1536
        int r = idx >> 4, c16 = idx & 15;
        int gr = 112 + r;
        uint4 v = make_uint4(0u, 0u, 0u, 0u);
        if (gr < 200) v = *(const uint4*)(xrow + (size_t)gr * 128 + c16 * 8);
        *(uint4*)(xs + r * 256 + ((c16 ^ (r & 7)) * 16)) = v;
    }
    __syncthreads();

    if (rq >= 2) {
#pragma unroll
        for (int tt = 0; tt < 4; ++tt) {
            if (tt < tcnt) {
                int t  = tstart + tt;
                int ar = (t - 7) * 16 + lr;
#pragma unroll
                for (int kk = 0; kk < 4; ++kk) {
                    int ca = kk * 4 + lq;
                    bf16x8 af = *(const bf16x8*)(xs + ar * 256 + ((ca ^ (ar & 7)) * 16));
                    acc[tt] = __builtin_amdgcn_mfma_f32_16x16x32_bf16(wf[kk], af, acc[tt], 0, 0, 0);
                }
            }
        }
    }
    __syncthreads();

    // ---- Phase B: zero pad rows + epilogue -> stR/stI
    for (int idx = tid; idx < PADL * SST; idx += 512) { stR[idx] = 0.f; stI[idx] = 0.f; }
    {
        float4 g4 = *(const float4*)(scale_in + ct * 256 + gp * 16 + lq * 4);
        float4 b4 = *(const float4*)(bias_in  + ct * 256 + gp * 16 + lq * 4);
        float* dst = ct ? stI : stR;
#pragma unroll
        for (int tt = 0; tt < 4; ++tt) {
            if (tt < tcnt) {
                int t = tstart + tt;
                int s = t * 16 + lr;
                if (s < 200) {
                    int pos = s + PADL;
                    dst[pos * SST + lq * 4 + 0] = acc[tt][0] * g4.x + b4.x;
                    dst[pos * SST + lq * 4 + 1] = acc[tt][1] * g4.y + b4.y;
                    dst[pos * SST + lq * 4 + 2] = acc[tt][2] * g4.z + b4.z;
                    dst[pos * SST + lq * 4 + 3] = acc[tt][3] * g4.w + b4.w;
                }
            }
        }
    }
    __syncthreads();

    float xr[8], xi[8], mf[8];
#pragma unroll
    for (int k = 0; k < 8; ++k) {
        xr[k] = stR[(t0 + k) * SST + c];
        xi[k] = stI[(t0 + k) * SST + c];
        mf[k] = mkf[t0 + k];
    }
    __syncthreads();

    {
        const char* src = (const char*)(lamT + (size_t)gp * 16 * 128);
#pragma unroll
        for (int it = 0; it < 2; ++it) {
            int idx = it * 512 + tid;
            int row = idx >> 6, c4 = idx & 63;
            *(uint4*)((char*)lamS + row * 1040 + c4 * 16) =
                *(const uint4*)(src + row * 1024 + c4 * 16);
        }
    }

    {
#pragma unroll
        for (int k = 0; k < 8; k += 2) {
            float sr = xr[k] * mf[k], si = xi[k] * mf[k];
            xr[k+1] += l14[0].x * sr - l14[0].y * si;
            xi[k+1] += l14[0].x * si + l14[0].y * sr;
        }
#pragma unroll
        for (int k = 1; k < 8; k += 4) {
            float sr = xr[k] * mf[k], si = xi[k] * mf[k];
            xr[k+1] += l14[0].x * sr - l14[0].y * si;
            xi[k+1] += l14[0].x * si + l14[0].y * sr;
            xr[k+2] += l14[1].x * sr - l14[1].y * si;
            xi[k+2] += l14[1].x * si + l14[1].y * sr;
        }
        {
            float sr = xr[3] * mf[3], si = xi[3] * mf[3];
#pragma unroll
            for (int j = 0; j < 4; ++j) {
                xr[4+j] += l14[j].x * sr - l14[j].y * si;
                xi[4+j] += l14[j].x * si + l14[j].y * sr;
            }
        }
    }

#pragma unroll
    for (int i = 4; i <= 8; ++i) {
        int half = 1 << (i - 1);
        int buf  = (i & 1) * 544;
        bc[buf + tl * 17 + c] = make_float2(xr[7], xi[7]);
        __syncthreads();
        int off = t0 & ((half << 1) - 1);
        if (off >= half) {
            int src = t0 - off + half - 1;
            float m = mkf[src];
            float2 sv = bc[buf + (src >> 3) * 17 + c];
            float sr = sv.x * m, si = sv.y * m;
            int e = off - half;
            const float2* lp = lamS + c * 130 + e;
#pragma unroll
            for (int k = 0; k < 8; ++k) {
                float2 lv = lp[k];
                xr[k] += lv.x * sr - lv.y * si;
                xi[k] += lv.x * si + lv.y * sr;
            }
        }
    }
    __syncthreads();

#pragma unroll
    for (int k = 0; k < 8; ++k) {
        stR[(t0 + k) * SST + c] = xr[k];
        stI[(t0 + k) * SST + c] = xi[k];
    }
    __syncthreads();

    int g  = gp >> 1;
    int hc = (gp & 1) * 16;
    ushort* baseg = H + (size_t)(b * 8 + g) * 2 * SEQ * 32 + hc;
#pragma unroll
    for (int it = 0; it < 4; ++it) {
        int idx4 = it * 512 + tid;
        if (idx4 < 2 * SEQ * 4) {
            int q  = idx4 & 3;
            int ps = idx4 >> 2;
            int p  = ps >= SEQ;
            int s  = ps - p * SEQ;
            int t  = s + PADL;
            const float* sp = (p ? stI : stR) + t * SST + q * 4;
            float2 a = *(const float2*)(sp);
            float2 d = *(const float2*)(sp + 2);
            uint2 raw;
            raw.x = pkbf(a.x, a.y);
            raw.y = pkbf(d.x, d.y);
            *(uint2*)(baseg + (size_t)ps * 32 + q * 4) = raw;
        }
    }
}

// ---------------------------------------------------------------------------
// FUSED layer tail: x = ffnLN( ffn( lruLN( outproj(H) + ob + x ) ) ).
// 256 threads, 64-row tile. Out-proj activations loaded DIRECTLY from H
// (fragments are 16B-contiguous in H layout — no LDS staging). x1 round-trips
// through the Ps LDS region into af_x registers + a 16-VGPR residual copy.
// FFN body = v5 (fat 32KB weight stages). K-orders identical to the unfused
// kernels -> bit-identical numerics. In-place on X (block-local rows only).
// ---------------------------------------------------------------------------
__global__ __launch_bounds__(256) void tail_fused_kernel(
    ushort* __restrict__ X, const ushort* __restrict__ Hh,
    const ushort* __restrict__ W2e,
    const ushort* __restrict__ W1, const ushort* __restrict__ W2,
    const float* __restrict__ ob,
    const float* __restrict__ lng1, const float* __restrict__ lnb1,
    const float* __restrict__ b1, const float* __restrict__ b2,
    const float* __restrict__ lng2, const float* __restrict__ lnb2)
{
    __shared__ char Bs[32768];          // weight chunk (128 rows x 128K), swizzled
    __shared__ ushort Ps[64 * 136];     // x1 tile, then P tile
    __shared__ float2 lnS[2][64];
    int tid = threadIdx.x;
    int l = tid & 63, w = tid >> 6;
    int chh = w >> 1, rh = w & 1;
    int lr = l & 15, lq = l >> 4;
    int m0 = blockIdx.x * 64;

    int chb[4], arow[2], sbj[2], ssj[2];
#pragma unroll
    for (int i = 0; i < 4; ++i) chb[i] = chh * 64 + i * 16 + lq * 4;
#pragma unroll
    for (int j = 0; j < 2; ++j) {
        arow[j] = m0 + rh * 32 + j * 16 + lr;
        sbj[j] = arow[j] / SEQ;
        ssj[j] = arow[j] - sbj[j] * SEQ;
    }

    // ---- Phase OP: out-proj, K=512 in 4 chunks of 128
    floatx4 accp[4][2];
#pragma unroll
    for (int i = 0; i < 4; ++i)
#pragma unroll
        for (int j = 0; j < 2; ++j) accp[i][j] = (floatx4)0.f;

    for (int kc = 0; kc < 4; ++kc) {
        if (kc) __syncthreads();        // guard Bs overwrite
#pragma unroll
        for (int it = 0; it < 8; ++it) {
            int idx = it * 256 + tid;
            int r = idx >> 4, c16 = idx & 15;
            uint4 v = *(const uint4*)(W2e + (size_t)r * 512 + kc * 128 + c16 * 8);
            *(uint4*)(Bs + r * 256 + ((c16 ^ (r & 7)) * 16)) = v;
        }
        __syncthreads();
#pragma unroll
        for (int kk2 = 0; kk2 < 4; ++kk2) {
            int ca = kk2 * 4 + lq;
            bf16x8 wf[4], af[2];
#pragma unroll
            for (int i = 0; i < 4; ++i) {
                int rb = chh * 64 + i * 16 + lr;
                wf[i] = *(const bf16x8*)(Bs + rb * 256 + ((ca ^ (rb & 7)) * 16));
            }
#pragma unroll
            for (int j = 0; j < 2; ++j)
                af[j] = *(const bf16x8*)(Hh + haddr(sbj[j], ssj[j], kc * 128 + kk2 * 32 + lq * 8));
#pragma unroll
            for (int i = 0; i < 4; ++i)
#pragma unroll
                for (int j = 0; j < 2; ++j)
                    accp[i][j] = __builtin_amdgcn_mfma_f32_16x16x32_bf16(
                        wf[i], af[j], accp[i][j], 0, 0, 0);
        }
    }

    // ---- epilogue OP: + ob + residual(x_old), LN -> x1 (Ps tile + resx regs)
    uint2 resx[2][4];
    {
        float4 bias[4], gv[4], bv[4];
#pragma unroll
        for (int i = 0; i < 4; ++i) {
            bias[i] = *(const float4*)(ob + chb[i]);
            gv[i]   = *(const float4*)(lng1 + chb[i]);
            bv[i]   = *(const float4*)(lnb1 + chb[i]);
        }
#pragma unroll
        for (int j = 0; j < 2; ++j) {
#pragma unroll
            for (int i = 0; i < 4; ++i) {
                ushort4 r4 = *(const ushort4*)(X + (size_t)arow[j] * 128 + chb[i]);
                accp[i][j][0] += ((const float*)&bias[i])[0] + bf2f(r4.x);
                accp[i][j][1] += ((const float*)&bias[i])[1] + bf2f(r4.y);
                accp[i][j][2] += ((const float*)&bias[i])[2] + bf2f(r4.z);
                accp[i][j][3] += ((const float*)&bias[i])[3] + bf2f(r4.w);
            }
        }
#pragma unroll
        for (int j = 0; j < 2; ++j) {
            float s = 0.f, q = 0.f;
#pragma unroll
            for (int i = 0; i < 4; ++i)
#pragma unroll
                for (int reg = 0; reg < 4; ++reg) {
                    float v = accp[i][j][reg];
                    s += v; q += v * v;
                }
            s += __shfl_xor(s, 16); q += __shfl_xor(q, 16);
            s += __shfl_xor(s, 32); q += __shfl_xor(q, 32);
            if (lq == 0) lnS[chh][rh * 32 + j * 16 + lr] = make_float2(s, q);
        }
        __syncthreads();
#pragma unroll
        for (int j = 0; j < 2; ++j) {
            int rl = rh * 32 + j * 16 + lr;
            float2 s0 = lnS[0][rl], s1 = lnS[1][rl];
            float mu  = (s0.x + s1.x) * (1.0f / 128.0f);
            float var = (s0.y + s1.y) * (1.0f / 128.0f) - mu * mu;
            float rstd = rsqrtf(var + 1e-5f);
            int rowl = rh * 32 + j * 16 + lr;
#pragma unroll
            for (int i = 0; i < 4; ++i) {
                uint2 u;
                u.x = pkbf((accp[i][j][0] - mu) * rstd * ((const float*)&gv[i])[0] + ((const float*)&bv[i])[0],
                           (accp[i][j][1] - mu) * rstd * ((const float*)&gv[i])[1] + ((const float*)&bv[i])[1]);
                u.y = pkbf((accp[i][j][2] - mu) * rstd * ((const float*)&gv[i])[2] + ((const float*)&bv[i])[2],
                           (accp[i][j][3] - mu) * rstd * ((const float*)&gv[i])[3] + ((const float*)&bv[i])[3]);
                resx[j][i] = u;
                *(uint2*)(Ps + rowl * 136 + chb[i]) = u;
            }
        }
    }
    __syncthreads();   // x1 tile visible

    // af_x fragments from x1 tile
    bf16x8 af_x[8];
#pragma unroll
    for (int j = 0; j < 2; ++j)
#pragma unroll
        for (int kk2 = 0; kk2 < 4; ++kk2) {
            int rowl = rh * 32 + j * 16 + lr;
            af_x[(j << 2) | kk2] = *(const bf16x8*)(Ps + rowl * 136 + kk2 * 32 + lq * 8);
        }

    // ---- FFN (v5 body)
    floatx4 acc2[4][2];
#pragma unroll
    for (int i = 0; i < 4; ++i)
#pragma unroll
        for (int j = 0; j < 2; ++j) acc2[i][j] = (floatx4)0.f;

    for (int ffc = 0; ffc < 4; ++ffc) {
        // (Bs last read: OP kc=3 / prev FFN2 — both before a barrier above)
        if (ffc) __syncthreads();
#pragma unroll
        for (int it = 0; it < 8; ++it) {
            int idx = it * 256 + tid;
            int r = idx >> 4, c16 = idx & 15;
            uint4 v = *(const uint4*)(W1 + (size_t)(ffc * 128 + r) * 128 + c16 * 8);
            *(uint4*)(Bs + r * 256 + ((c16 ^ (r & 7)) * 16)) = v;
        }
        __syncthreads();                // W1 visible (also guards Ps: af_x read before)

        floatx4 acc1[4][2];
#pragma unroll
        for (int i = 0; i < 4; ++i)
#pragma unroll
            for (int j = 0; j < 2; ++j) acc1[i][j] = (floatx4)0.f;
#pragma unroll
        for (int kk2 = 0; kk2 < 4; ++kk2) {
            int ca = kk2 * 4 + lq;
            bf16x8 wf[4];
#pragma unroll
            for (int i = 0; i < 4; ++i) {
                int rb = chh * 64 + i * 16 + lr;
                wf[i] = *(const bf16x8*)(Bs + rb * 256 + ((ca ^ (rb & 7)) * 16));
            }
#pragma unroll
            for (int i = 0; i < 4; ++i)
#pragma unroll
                for (int j = 0; j < 2; ++j)
                    acc1[i][j] = __builtin_amdgcn_mfma_f32_16x16x32_bf16(
                        wf[i], af_x[(j << 2) | kk2], acc1[i][j], 0, 0, 0);
        }

#pragma unroll
        for (int j = 0; j < 2; ++j) {
            int rowl = rh * 32 + j * 16 + lr;
#pragma unroll
            for (int i = 0; i < 4; ++i) {
                int ch0 = chh * 64 + i * 16 + lq * 4;
                float4 bv = *(const float4*)(b1 + ffc * 128 + ch0);
                float g0, g1, g2, g3, v;
                v = acc1[i][j][0] + bv.x; g0 = 0.5f * v * (1.0f + erff(v * 0.70710678118654752f));
                v = acc1[i][j][1] + bv.y; g1 = 0.5f * v * (1.0f + erff(v * 0.70710678118654752f));
                v = acc1[i][j][2] + bv.z; g2 = 0.5f * v * (1.0f + erff(v * 0.70710678118654752f));
                v = acc1[i][j][3] + bv.w; g3 = 0.5f * v * (1.0f + erff(v * 0.70710678118654752f));
                uint2 u; u.x = pkbf(g0, g1); u.y = pkbf(g2, g3);
                *(uint2*)(Ps + rowl * 136 + ch0) = u;
            }
        }
        __syncthreads();                // FFN1 Bs reads done

#pragma unroll
        for (int it = 0; it < 8; ++it) {
            int idx = it * 256 + tid;
            int r = idx >> 4, c16 = idx & 15;
            uint4 v = *(const uint4*)(W2 + (size_t)r * 512 + ffc * 128 + c16 * 8);
            *(uint4*)(Bs + r * 256 + ((c16 ^ (r & 7)) * 16)) = v;
        }
        __syncthreads();                // W2 + Ps visible

#pragma unroll
        for (int kk2 = 0; kk2 < 4; ++kk2) {
            int ca = kk2 * 4 + lq;
            bf16x8 wf[4], af[2];
#pragma unroll
            for (int i = 0; i < 4; ++i) {
                int rb = chh * 64 + i * 16 + lr;
                wf[i] = *(const bf16x8*)(Bs + rb * 256 + ((ca ^ (rb & 7)) * 16));
            }
#pragma unroll
            for (int j = 0; j < 2; ++j) {
                int rowl = rh * 32 + j * 16 + lr;
                af[j] = *(const bf16x8*)(Ps + rowl * 136 + kk2 * 32 + lq * 8);
            }
#pragma unroll
            for (int i = 0; i < 4; ++i)
#pragma unroll
                for (int j = 0; j < 2; ++j)
                    acc2[i][j] = __builtin_amdgcn_mfma_f32_16x16x32_bf16(
                        wf[i], af[j], acc2[i][j], 0, 0, 0);
        }
    }

    // ---- epilogue: + b2 + residual(x1 from regs), LN, store
    float4 bias[4], gv[4], bv[4];
#pragma unroll
    for (int i = 0; i < 4; ++i) {
        bias[i] = *(const float4*)(b2 + chb[i]);
        gv[i]   = *(const float4*)(lng2 + chb[i]);
        bv[i]   = *(const float4*)(lnb2 + chb[i]);
    }
#pragma unroll
    for (int j = 0; j < 2; ++j) {
#pragma unroll
        for (int i = 0; i < 4; ++i) {
            uint2 u = resx[j][i];
            acc2[i][j][0] += ((const float*)&bias[i])[0] + bf2f((ushort)(u.x & 0xffff));
            acc2[i][j][1] += ((const float*)&bias[i])[1] + bf2f((ushort)(u.x >> 16));
            acc2[i][j][2] += ((const float*)&bias[i])[2] + bf2f((ushort)(u.y & 0xffff));
            acc2[i][j][3] += ((const float*)&bias[i])[3] + bf2f((ushort)(u.y >> 16));
        }
    }
    __syncthreads();   // lnS reuse guard
#pragma unroll
    for (int j = 0; j < 2; ++j) {
        float s = 0.f, q = 0.f;
#pragma unroll
        for (int i = 0; i < 4; ++i)
#pragma unroll
            for (int reg = 0; reg < 4; ++reg) {
                float v = acc2[i][j][reg];
                s += v; q += v * v;
            }
        s += __shfl_xor(s, 16); q += __shfl_xor(q, 16);
        s += __shfl_xor(s, 32); q += __shfl_xor(q, 32);
        if (lq == 0) lnS[chh][rh * 32 + j * 16 + lr] = make_float2(s, q);
    }
    __syncthreads();
#pragma unroll
    for (int j = 0; j < 2; ++j) {
        int rl = rh * 32 + j * 16 + lr;
        float2 s0 = lnS[0][rl], s1 = lnS[1][rl];
        float mu  = (s0.x + s1.x) * (1.0f / 128.0f);
        float var = (s0.y + s1.y) * (1.0f / 128.0f) - mu * mu;
        float rstd = rsqrtf(var + 1e-5f);
#pragma unroll
        for (int i = 0; i < 4; ++i) {
            uint2 u;
            u.x = pkbf((acc2[i][j][0] - mu) * rstd * ((const float*)&gv[i])[0] + ((const float*)&bv[i])[0],
                       (acc2[i][j][1] - mu) * rstd * ((const float*)&gv[i])[1] + ((const float*)&bv[i])[1]);
            u.y = pkbf((acc2[i][j][2] - mu) * rstd * ((const float*)&gv[i])[2] + ((const float*)&bv[i])[2],
                       (acc2[i][j][3] - mu) * rstd * ((const float*)&gv[i])[3] + ((const float*)&bv[i])[3]);
            *(uint2*)(X + (size_t)arow[j] * 128 + chb[i]) = u;
        }
    }
}

// ---------------------------------------------------------------------------
__global__ void gather_kernel(const ushort* __restrict__ x,
                              const int* __restrict__ seqlen,
                              float* __restrict__ out, int b0, int Bc)
{
    int i = blockIdx.x * 256 + threadIdx.x;
    if (i >= Bc * D) return;
    int b = i >> 7, d = i & 127;
    int idx = seqlen[b0 + b] - 1;
    out[(size_t)(b0 + b) * D + d] = bf2f(x[((size_t)b * SEQ + idx) * D + d]);
}

// ---------------------------------------------------------------------------
extern "C" void kernel_launch(void* const* d_in, const int* in_sizes, int n_in,
                              void* d_out, int out_size, void* d_ws, size_t ws_size,
                              hipStream_t stream)
{
    const float* token_emb  = (const float*)d_in[0];
    const float* emb_ln_g   = (const float*)d_in[1];
    const float* emb_ln_b   = (const float*)d_in[2];
    const float* params_log = (const float*)d_in[3];
    const float* in_wr      = (const float*)d_in[4];
    const float* in_wi      = (const float*)d_in[5];
    const float* in_br      = (const float*)d_in[6];
    const float* in_bi      = (const float*)d_in[7];
    const float* out_wr     = (const float*)d_in[8];
    const float* out_wi     = (const float*)d_in[9];
    const float* out_br     = (const float*)d_in[10];
    const float* lru_ln_g   = (const float*)d_in[12];
    const float* lru_ln_b   = (const float*)d_in[13];
    const float* w1         = (const float*)d_in[14];
    const float* b1         = (const float*)d_in[15];
    const float* w2         = (const float*)d_in[16];
    const float* b2         = (const float*)d_in[17];
    const float* ffn_ln_g   = (const float*)d_in[18];
    const float* ffn_ln_b   = (const float*)d_in[19];
    const int*   item_seq   = (const int*)d_in[20];
    const int*   item_seq_len = (const int*)d_in[21];
    float* out = (float*)d_out;

    char* ws = (char*)d_ws;
    ushort* Winb   = (ushort*)ws;                      ws += NLAY * 65536 * 2;
    ushort* W2effb = (ushort*)ws;                      ws += NLAY * 65536 * 2;
    ushort* w1b    = (ushort*)ws;                      ws += NLAY * 65536 * 2;
    ushort* w2b    = (ushort*)ws;                      ws += NLAY * 65536 * 2;
    float* lam_pow = (float*)ws;                       ws += NLAY * 65536 * 4;
    float* scale_in = (float*)ws;                      ws += NLAY * 512 * 4;
    float* bias_in  = (float*)ws;                      ws += NLAY * 512 * 4;
    size_t table_bytes = (size_t)(ws - (char*)d_ws);

    int Bc = B_TOT;
    while (Bc > 32) {
        size_t need = table_bytes + (size_t)Bc * SEQ * (D * 2 + 2 * DH * 2) + 1024;
        if (need <= ws_size) break;
        Bc >>= 1;
    }
    ushort* xb = (ushort*)ws;                          ws += (size_t)Bc * SEQ * D * 2;
    ushort* hb = (ushort*)ws;

    setup_params_kernel<<<NLAY, 256, 0, stream>>>(params_log, in_br, in_bi,
                                                  lam_pow, scale_in, bias_in);
    setup_weights_kernel<<<NLAY * 65536 / 256, 256, 0, stream>>>(
        in_wr, in_wi, out_wr, out_wi, w1, w2, Winb, W2effb, w1b, w2b);

    for (int b0 = 0; b0 < B_TOT; b0 += Bc) {
        int M = Bc * SEQ;
        embed_ln_kernel<<<M / 4, 256, 0, stream>>>(
            token_emb, item_seq + (size_t)b0 * SEQ, emb_ln_g, emb_ln_b, xb);

        for (int li = 0; li < NLAY; ++li) {
            // fused in-proj + exact tree scan -> H layout
            inproj_scan_kernel<<<dim3(16, Bc), 512, 0, stream>>>(
                xb, Winb + (size_t)li * 65536, hb,
                (const float2*)(lam_pow + (size_t)li * 65536),
                item_seq + (size_t)b0 * SEQ,
                scale_in + li * 512, bias_in + li * 512);
            // fused out-proj+LN+FFN+LN (in place on xb)
            tail_fused_kernel<<<dim3(M / 64), 256, 0, stream>>>(
                xb, hb, W2effb + (size_t)li * 65536,
                w1b + (size_t)li * 65536, w2b + (size_t)li * 65536,
                out_br + li * D, lru_ln_g + li * D, lru_ln_b + li * D,
                b1 + li * DFF, b2 + li * D,
                ffn_ln_g + li * D, ffn_ln_b + li * D);
        }
        gather_kernel<<<(Bc * D + 255) / 256, 256, 0, stream>>>(
            xb, item_seq_len, out, b0, Bc);
    }
}

// Round 16
// 614.286 us; speedup vs baseline: 1.1990x; 1.1990x over previous
//
#include <hip/hip_runtime.h>
#include <hip/hip_bf16.h>
#include <math.h>

#define B_TOT 512
#define SEQ   200
#define D     128
#define DH    256
#define DFF   512
#define LPAD  256
#define PADL  56
#define NLAY  2
#define SST   18   // scan LDS row stride (floats)

typedef __attribute__((ext_vector_type(8))) short bf16x8;
typedef __attribute__((ext_vector_type(4))) float floatx4;

static __device__ inline float bf2f(ushort u) {
    union { unsigned int i; float f; } v; v.i = ((unsigned int)u) << 16; return v.f;
}
static __device__ inline ushort f2bf(float x) {
    union { float f; unsigned int i; } v; v.f = x;
    unsigned int r = (v.i + 0x7FFFu + ((v.i >> 16) & 1u)) >> 16;   // RNE
    return (ushort)r;
}
// HW packed f32x2 -> bf16x2 (v_cvt_pk_bf16_f32 on gfx950), RNE
static __device__ inline unsigned int pkbf(float a, float b) {
    union { __hip_bfloat162 h; unsigned int u; } v;
    v.h = __float22bfloat162_rn(make_float2(a, b));
    return v.u;
}

// H layout: [b][g(8)][p(re/im)][s(200)][32 ch] bf16. k in 0..511: k<256 re, else im.
static __device__ inline size_t haddr(int b, int s, int k) {
    int p  = k >> 8;
    int ch = k & 255;
    int g  = ch >> 5;
    int cl = ch & 31;
    return (((((size_t)b * 8 + g) * 2 + p) * SEQ + s) * 32 + cl);
}

// ---------------------------------------------------------------------------
// lambda powers (TRANSPOSED: [ch][128] float2, entry j = lambda^{j+1})
// + in-proj epilogue scale/bias
// ---------------------------------------------------------------------------
__global__ void setup_params_kernel(const float* __restrict__ params_log,
                                    const float* __restrict__ in_br,
                                    const float* __restrict__ in_bi,
                                    float* __restrict__ lam_pow,   // [NLAY][256][128] float2
                                    float* __restrict__ scale_in,  // [NLAY][512]
                                    float* __restrict__ bias_in)   // [NLAY][512]
{
    int li = blockIdx.x;
    int c  = threadIdx.x;             // 256 threads
    const float* pl = params_log + (size_t)li * 3 * DH;
    float nu = expf(pl[c]);
    float th = expf(pl[DH + c]);
    float ga = expf(pl[2 * DH + c]);
    float mag = expf(-nu);
    float lr = mag * cosf(th);
    float lim = mag * sinf(th);
    float2* lp = (float2*)(lam_pow + (size_t)li * 65536) + (size_t)c * 128;
    float pr = lr, pi = lim;
    lp[0] = make_float2(pr, pi);
    for (int k = 1; k < 128; ++k) {
        float nr = pr * lr - pi * lim;
        float ni = pr * lim + pi * lr;
        pr = nr; pi = ni;
        lp[k] = make_float2(pr, pi);
    }
    scale_in[li * 2 * DH + c]      = ga;
    scale_in[li * 2 * DH + DH + c] = ga;
    bias_in[li * 2 * DH + c]       = in_br[li * DH + c] * ga;
    bias_in[li * 2 * DH + DH + c]  = in_bi[li * DH + c] * ga;
}

__global__ void setup_weights_kernel(const float* __restrict__ in_wr,
                                     const float* __restrict__ in_wi,
                                     const float* __restrict__ out_wr,
                                     const float* __restrict__ out_wi,
                                     const float* __restrict__ w1,
                                     const float* __restrict__ w2,
                                     ushort* __restrict__ Winb,
                                     ushort* __restrict__ W2effb,
                                     ushort* __restrict__ w1b,
                                     ushort* __restrict__ w2b)
{
    int idx = blockIdx.x * blockDim.x + threadIdx.x;   // NLAY*65536
    int li = idx >> 16;
    int r  = idx & 65535;

    int n = r >> 7, d = r & 127;
    float wv = (n < DH) ? in_wr[((size_t)li * DH + n) * D + d]
                        : in_wi[((size_t)li * DH + (n - DH)) * D + d];
    Winb[idx] = f2bf(wv);

    int dd = r >> 9, cc = r & 511;
    float w2v = (cc < DH) ? out_wr[((size_t)li * D + dd) * DH + cc]
                          : -out_wi[((size_t)li * D + dd) * DH + (cc - DH)];
    W2effb[idx] = f2bf(w2v);

    w1b[idx] = f2bf(w1[idx]);
    w2b[idx] = f2bf(w2[idx]);
}

// ---------------------------------------------------------------------------
// Embedding gather + LayerNorm -> bf16 x
// ---------------------------------------------------------------------------
__global__ __launch_bounds__(256) void embed_ln_kernel(
    const float* __restrict__ emb, const int* __restrict__ seq,
    const float* __restrict__ g, const float* __restrict__ bt,
    ushort* __restrict__ x)
{
    int row  = blockIdx.x * 4 + (threadIdx.x >> 6);
    int lane = threadIdx.x & 63;
    int item = seq[row];
    float2 v = *(const float2*)(emb + (size_t)item * D + lane * 2);
    float s = v.x + v.y;
#pragma unroll
    for (int o = 32; o > 0; o >>= 1) s += __shfl_xor(s, o);
    float mu = s * (1.0f / D);
    float d0 = v.x - mu, d1 = v.y - mu;
    float vs = d0 * d0 + d1 * d1;
#pragma unroll
    for (int o = 32; o > 0; o >>= 1) vs += __shfl_xor(vs, o);
    float rstd = rsqrtf(vs * (1.0f / D) + 1e-5f);
    float2 gg = *(const float2*)(g + lane * 2);
    float2 bb = *(const float2*)(bt + lane * 2);
    unsigned int o2 = pkbf(d0 * rstd * gg.x + bb.x, d1 * rstd * gg.y + bb.y);
    *(unsigned int*)(x + (size_t)row * D + lane * 2) = o2;
}

// ---------------------------------------------------------------------------
// FUSED in-proj + exact tree scan, two-stage x staging (R14 known-good).
// Grid = (gp, b): gp fast -> blocks sharing x[b] are dispatch-adjacent.
// ---------------------------------------------------------------------------
__global__ __launch_bounds__(512) void inproj_scan_kernel(
    const ushort* __restrict__ X, const ushort* __restrict__ Win,
    ushort* __restrict__ H, const float2* __restrict__ lamT,
    const int* __restrict__ seq,
    const float* __restrict__ scale_in, const float* __restrict__ bias_in)
{
    __shared__ __align__(16) char smem[36864];   // Ws 8192 + xs 28672 (phase A)
    __shared__ float mkf[LPAD];
    char*  Wsm = smem;                           // [32][128] bf16, swizzled
    char*  xs  = smem + 8192;                    // [112][128] bf16, swizzled
    float* stR = (float*)smem;                   // [256][SST] (phase B alias)
    float* stI = stR + LPAD * SST;               // ends at 36864 B
    float2* lamS = (float2*)smem;                // [16][130] (tree phase alias)
    float2* bc   = (float2*)(smem + 16 * 130 * 8);

    int gp = blockIdx.x, b = blockIdx.y;
    int tid = threadIdx.x;
    int l = tid & 63, w = tid >> 6;              // 8 waves
    int ct = w & 1;                              // 0=re tile, 1=im tile
    int rq = w >> 1;                             // row quarter 0..3
    int lr = l & 15, lq = l >> 4;

    int c  = tid & 15;                           // scan channel
    int tl = tid >> 4;                           // 0..31
    int t0 = tl * 8;

    const float2* myl = lamT + (size_t)(gp * 16 + c) * 128;
    float2 l14[4];
#pragma unroll
    for (int k = 0; k < 4; ++k) l14[k] = myl[k];

    if (tid < LPAD) {
        int t = tid;
        float m = 0.f;
        if (t >= PADL) m = (seq[(size_t)b * SEQ + (t - PADL)] > 0) ? 1.f : 0.f;
        mkf[t] = m;
    }

    // ---- Phase A: stage Ws + x stage A (rows 0..111)
    const ushort* xrow = X + (size_t)b * SEQ * 128;
    {
        int r = tid >> 4, c16 = tid & 15;
        int n = (r < 16) ? (gp * 16 + r) : (256 + gp * 16 + (r - 16));
        uint4 v = *(const uint4*)(Win + (size_t)n * 128 + c16 * 8);
        *(uint4*)(Wsm + r * 256 + ((c16 ^ (r & 7)) * 16)) = v;
    }
#pragma unroll
    for (int it = 0; it < 4; ++it) {
        int idx = it * 512 + tid;
        if (idx < 112 * 16) {
            int r = idx >> 4, c16 = idx & 15;
            uint4 v = *(const uint4*)(xrow + (size_t)r * 128 + c16 * 8);
            *(uint4*)(xs + r * 256 + ((c16 ^ (r & 7)) * 16)) = v;
        }
    }
    __syncthreads();

    bf16x8 wf[4];
#pragma unroll
    for (int kk = 0; kk < 4; ++kk) {
        int ca = kk * 4 + lq;
        int wr = ct * 16 + lr;
        wf[kk] = *(const bf16x8*)(Wsm + wr * 256 + ((ca ^ (wr & 7)) * 16));
    }
    int tstart = rq ? (3 * rq + 1) : 0;          // 0 / 4 / 7 / 10
    int tcnt   = rq ? 3 : 4;
    floatx4 acc[4];
#pragma unroll
    for (int tt = 0; tt < 4; ++tt) acc[tt] = (floatx4)0.f;

    if (rq < 2) {
#pragma unroll
        for (int tt = 0; tt < 4; ++tt) {
            if (tt < tcnt) {
                int t  = tstart + tt;
                int ar = t * 16 + lr;
#pragma unroll
                for (int kk = 0; kk < 4; ++kk) {
                    int ca = kk * 4 + lq;
                    bf16x8 af = *(const bf16x8*)(xs + ar * 256 + ((ca ^ (ar & 7)) * 16));
                    acc[tt] = __builtin_amdgcn_mfma_f32_16x16x32_bf16(wf[kk], af, acc[tt], 0, 0, 0);
                }
            }
        }
    }
    __syncthreads();

#pragma unroll
    for (int it = 0; it < 3; ++it) {
        int idx = it * 512 + tid;                // exactly 96*16 = 1536
        int r = idx >> 4, c16 = idx & 15;
        int gr = 112 + r;
        uint4 v = make_uint4(0u, 0u, 0u, 0u);
        if (gr < 200) v = *(const uint4*)(xrow + (size_t)gr * 128 + c16 * 8);
        *(uint4*)(xs + r * 256 + ((c16 ^ (r & 7)) * 16)) = v;
    }
    __syncthreads();

    if (rq >= 2) {
#pragma unroll
        for (int tt = 0; tt < 4; ++tt) {
            if (tt < tcnt) {
                int t  = tstart + tt;
                int ar = (t - 7) * 16 + lr;
#pragma unroll
                for (int kk = 0; kk < 4; ++kk) {
                    int ca = kk * 4 + lq;
                    bf16x8 af = *(const bf16x8*)(xs + ar * 256 + ((ca ^ (ar & 7)) * 16));
                    acc[tt] = __builtin_amdgcn_mfma_f32_16x16x32_bf16(wf[kk], af, acc[tt], 0, 0, 0);
                }
            }
        }
    }
    __syncthreads();

    // ---- Phase B: zero pad rows + epilogue -> stR/stI
    for (int idx = tid; idx < PADL * SST; idx += 512) { stR[idx] = 0.f; stI[idx] = 0.f; }
    {
        float4 g4 = *(const float4*)(scale_in + ct * 256 + gp * 16 + lq * 4);
        float4 b4 = *(const float4*)(bias_in  + ct * 256 + gp * 16 + lq * 4);
        float* dst = ct ? stI : stR;
#pragma unroll
        for (int tt = 0; tt < 4; ++tt) {
            if (tt < tcnt) {
                int t = tstart + tt;
                int s = t * 16 + lr;
                if (s < 200) {
                    int pos = s + PADL;
                    dst[pos * SST + lq * 4 + 0] = acc[tt][0] * g4.x + b4.x;
                    dst[pos * SST + lq * 4 + 1] = acc[tt][1] * g4.y + b4.y;
                    dst[pos * SST + lq * 4 + 2] = acc[tt][2] * g4.z + b4.z;
                    dst[pos * SST + lq * 4 + 3] = acc[tt][3] * g4.w + b4.w;
                }
            }
        }
    }
    __syncthreads();

    float xr[8], xi[8], mf[8];
#pragma unroll
    for (int k = 0; k < 8; ++k) {
        xr[k] = stR[(t0 + k) * SST + c];
        xi[k] = stI[(t0 + k) * SST + c];
        mf[k] = mkf[t0 + k];
    }
    __syncthreads();

    {
        const char* src = (const char*)(lamT + (size_t)gp * 16 * 128);
#pragma unroll
        for (int it = 0; it < 2; ++it) {
            int idx = it * 512 + tid;
            int row = idx >> 6, c4 = idx & 63;
            *(uint4*)((char*)lamS + row * 1040 + c4 * 16) =
                *(const uint4*)(src + row * 1024 + c4 * 16);
        }
    }

    {
#pragma unroll
        for (int k = 0; k < 8; k += 2) {
            float sr = xr[k] * mf[k], si = xi[k] * mf[k];
            xr[k+1] += l14[0].x * sr - l14[0].y * si;
            xi[k+1] += l14[0].x * si + l14[0].y * sr;
        }
#pragma unroll
        for (int k = 1; k < 8; k += 4) {
            float sr = xr[k] * mf[k], si = xi[k] * mf[k];
            xr[k+1] += l14[0].x * sr - l14[0].y * si;
            xi[k+1] += l14[0].x * si + l14[0].y * sr;
            xr[k+2] += l14[1].x * sr - l14[1].y * si;
            xi[k+2] += l14[1].x * si + l14[1].y * sr;
        }
        {
            float sr = xr[3] * mf[3], si = xi[3] * mf[3];
#pragma unroll
            for (int j = 0; j < 4; ++j) {
                xr[4+j] += l14[j].x * sr - l14[j].y * si;
                xi[4+j] += l14[j].x * si + l14[j].y * sr;
            }
        }
    }

#pragma unroll
    for (int i = 4; i <= 8; ++i) {
        int half = 1 << (i - 1);
        int buf  = (i & 1) * 544;
        bc[buf + tl * 17 + c] = make_float2(xr[7], xi[7]);
        __syncthreads();
        int off = t0 & ((half << 1) - 1);
        if (off >= half) {
            int src = t0 - off + half - 1;
            float m = mkf[src];
            float2 sv = bc[buf + (src >> 3) * 17 + c];
            float sr = sv.x * m, si = sv.y * m;
            int e = off - half;
            const float2* lp = lamS + c * 130 + e;
#pragma unroll
            for (int k = 0; k < 8; ++k) {
                float2 lv = lp[k];
                xr[k] += lv.x * sr - lv.y * si;
                xi[k] += lv.x * si + lv.y * sr;
            }
        }
    }
    __syncthreads();

#pragma unroll
    for (int k = 0; k < 8; ++k) {
        stR[(t0 + k) * SST + c] = xr[k];
        stI[(t0 + k) * SST + c] = xi[k];
    }
    __syncthreads();

    int g  = gp >> 1;
    int hc = (gp & 1) * 16;
    ushort* baseg = H + (size_t)(b * 8 + g) * 2 * SEQ * 32 + hc;
#pragma unroll
    for (int it = 0; it < 4; ++it) {
        int idx4 = it * 512 + tid;
        if (idx4 < 2 * SEQ * 4) {
            int q  = idx4 & 3;
            int ps = idx4 >> 2;
            int p  = ps >= SEQ;
            int s  = ps - p * SEQ;
            int t  = s + PADL;
            const float* sp = (p ? stI : stR) + t * SST + q * 4;
            float2 a = *(const float2*)(sp);
            float2 d = *(const float2*)(sp + 2);
            uint2 raw;
            raw.x = pkbf(a.x, a.y);
            raw.y = pkbf(d.x, d.y);
            *(uint2*)(baseg + (size_t)ps * 32 + q * 4) = raw;
        }
    }
}

// ---------------------------------------------------------------------------
// bf16 MFMA GEMM, 512 threads, 256-row M-tile x 128-col N-tile (out-proj).
// MODE 1: bf16 out = LayerNorm(acc + e0[n] + res[m][n])  (N=128)
// AHL: activation operand read from H layout.
// ---------------------------------------------------------------------------
template <int MODE, bool AHL>
__global__ __launch_bounds__(512) void gemm_bf16_kernel(
    const ushort* __restrict__ A, const ushort* __restrict__ W,
    ushort* __restrict__ Cout, int M, int N, int K,
    const float* __restrict__ e0, const float* __restrict__ e1,
    const ushort* __restrict__ res,
    const float* __restrict__ lng, const float* __restrict__ lnb)
{
    __shared__ char As[32768];          // 256 rows x 64K bf16, swizzled
    __shared__ char Bs[16384];          // 128 rows x 64K bf16, swizzled
    __shared__ float2 lnS[2][256];
    int tid = threadIdx.x;
    int l = tid & 63, w = tid >> 6;     // 8 waves
    int chh = w >> 2;                   // N half (0/1)
    int rh  = w & 3;                    // row quarter (0..3)
    int lr = l & 15, lq = l >> 4;
    int m0 = blockIdx.x * 256, n0 = blockIdx.y * 128;

    int cst = tid & 7;                  // staged chunk
    int rr  = tid >> 3;                 // staged row base (0..63)
    int sb[4], ss[4];
    if (AHL) {
#pragma unroll
        for (int it = 0; it < 4; ++it) {
            unsigned int gr = m0 + it * 64 + rr;
            sb[it] = gr / SEQ; ss[it] = gr - sb[it] * SEQ;
        }
    }

    floatx4 acc[4][4];
#pragma unroll
    for (int i = 0; i < 4; ++i)
#pragma unroll
        for (int j = 0; j < 4; ++j) acc[i][j] = (floatx4)0.f;

    for (int k0 = 0; k0 < K; k0 += 64) {
#pragma unroll
        for (int it = 0; it < 4; ++it) {
            int r = it * 64 + rr;
            uint4 va;
            if (AHL) {
                va = *(const uint4*)(A + haddr(sb[it], ss[it], k0 + cst * 8));
            } else {
                va = *(const uint4*)(A + (size_t)(m0 + r) * K + k0 + cst * 8);
            }
            *(uint4*)(As + r * 128 + ((cst ^ (r & 7)) * 16)) = va;
            if (it < 2) {
                uint4 vb = *(const uint4*)(W + (size_t)(n0 + r) * K + k0 + cst * 8);
                *(uint4*)(Bs + r * 128 + ((cst ^ (r & 7)) * 16)) = vb;
            }
        }
        __syncthreads();
#pragma unroll
        for (int kk = 0; kk < 2; ++kk) {
            bf16x8 wf[4], af[4];
            int ca = kk * 4 + lq;
#pragma unroll
            for (int i = 0; i < 4; ++i) {
                int rb = chh * 64 + i * 16 + lr;
                wf[i] = *(const bf16x8*)(Bs + rb * 128 + ((ca ^ (rb & 7)) * 16));
                int ra = rh * 64 + i * 16 + lr;
                af[i] = *(const bf16x8*)(As + ra * 128 + ((ca ^ (ra & 7)) * 16));
            }
#pragma unroll
            for (int i = 0; i < 4; ++i)
#pragma unroll
                for (int j = 0; j < 4; ++j)
                    acc[i][j] = __builtin_amdgcn_mfma_f32_16x16x32_bf16(
                        wf[i], af[j], acc[i][j], 0, 0, 0);
        }
        __syncthreads();
    }

    int chb[4], arow[4];
#pragma unroll
    for (int i = 0; i < 4; ++i) chb[i] = n0 + chh * 64 + i * 16 + lq * 4;
#pragma unroll
    for (int j = 0; j < 4; ++j) arow[j] = m0 + rh * 64 + j * 16 + lr;

    {
        float4 bias[4], gv[4], bv[4];
#pragma unroll
        for (int i = 0; i < 4; ++i) {
            bias[i] = *(const float4*)(e0 + chb[i]);
            gv[i]   = *(const float4*)(lng + chb[i]);
            bv[i]   = *(const float4*)(lnb + chb[i]);
        }
#pragma unroll
        for (int j = 0; j < 4; ++j) {
#pragma unroll
            for (int i = 0; i < 4; ++i) {
                ushort4 r4 = *(const ushort4*)(res + (size_t)arow[j] * 128 + chb[i]);
                acc[i][j][0] += ((const float*)&bias[i])[0] + bf2f(r4.x);
                acc[i][j][1] += ((const float*)&bias[i])[1] + bf2f(r4.y);
                acc[i][j][2] += ((const float*)&bias[i])[2] + bf2f(r4.z);
                acc[i][j][3] += ((const float*)&bias[i])[3] + bf2f(r4.w);
            }
        }
#pragma unroll
        for (int j = 0; j < 4; ++j) {
            float s = 0.f, q = 0.f;
#pragma unroll
            for (int i = 0; i < 4; ++i)
#pragma unroll
                for (int reg = 0; reg < 4; ++reg) {
                    float v = acc[i][j][reg];
                    s += v; q += v * v;
                }
            s += __shfl_xor(s, 16); q += __shfl_xor(q, 16);
            s += __shfl_xor(s, 32); q += __shfl_xor(q, 32);
            if (lq == 0) lnS[chh][rh * 64 + j * 16 + lr] = make_float2(s, q);
        }
        __syncthreads();
#pragma unroll
        for (int j = 0; j < 4; ++j) {
            int rl = rh * 64 + j * 16 + lr;
            float2 s0 = lnS[0][rl], s1 = lnS[1][rl];
            float mu  = (s0.x + s1.x) * (1.0f / 128.0f);
            float var = (s0.y + s1.y) * (1.0f / 128.0f) - mu * mu;
            float rstd = rsqrtf(var + 1e-5f);
#pragma unroll
            for (int i = 0; i < 4; ++i) {
                uint2 u;
                u.x = pkbf((acc[i][j][0] - mu) * rstd * ((const float*)&gv[i])[0] + ((const float*)&bv[i])[0],
                           (acc[i][j][1] - mu) * rstd * ((const float*)&gv[i])[1] + ((const float*)&bv[i])[1]);
                u.y = pkbf((acc[i][j][2] - mu) * rstd * ((const float*)&gv[i])[2] + ((const float*)&bv[i])[2],
                           (acc[i][j][3] - mu) * rstd * ((const float*)&gv[i])[3] + ((const float*)&bv[i])[3]);
                *(uint2*)(Cout + (size_t)arow[j] * 128 + chb[i]) = u;
            }
        }
    }
}

// ---------------------------------------------------------------------------
// Fused FFN v5: out = LN(x + b2 + W2 @ gelu(W1 @ x + b1)).
// 256 threads, 64-row tile, X fragments in registers (32 VGPR), erff gelu.
// ONE 32 KB weight buffer holds a FULL 128-K chunk per stage -> 16 barriers.
// ---------------------------------------------------------------------------
__global__ __launch_bounds__(256) void ffn_fused_kernel(
    const ushort* __restrict__ X, const ushort* __restrict__ W1,
    const ushort* __restrict__ W2, ushort* __restrict__ Out,
    const float* __restrict__ b1, const float* __restrict__ b2,
    const float* __restrict__ lng, const float* __restrict__ lnb)
{
    __shared__ char Bs[32768];          // 128 rows x 128K bf16, swizzled 256B rows
    __shared__ ushort Ps[64 * 136];     // P tile, row stride 136
    __shared__ float2 lnS[2][64];
    int tid = threadIdx.x;
    int l = tid & 63, w = tid >> 6;
    int chh = w >> 1, rh = w & 1;
    int lr = l & 15, lq = l >> 4;
    int m0 = blockIdx.x * 64;

    // X operand in registers: af_x[(j<<2)|kk2], K = kk2*32 + lq*8
    bf16x8 af_x[8];
#pragma unroll
    for (int j = 0; j < 2; ++j)
#pragma unroll
        for (int kk2 = 0; kk2 < 4; ++kk2) {
            int row = m0 + rh * 32 + j * 16 + lr;
            int k   = kk2 * 32 + lq * 8;
            af_x[(j << 2) | kk2] = *(const bf16x8*)(X + (size_t)row * 128 + k);
        }

    floatx4 acc2[4][2];
#pragma unroll
    for (int i = 0; i < 4; ++i)
#pragma unroll
        for (int j = 0; j < 2; ++j) acc2[i][j] = (floatx4)0.f;

    for (int ffc = 0; ffc < 4; ++ffc) {
        if (ffc) __syncthreads();       // guard Bs overwrite (prev FFN2 reads)
        // ---- load full W1 chunk (128 rows x 128 K = 32 KB)
#pragma unroll
        for (int it = 0; it < 8; ++it) {
            int idx = it * 256 + tid;
            int r = idx >> 4, c16 = idx & 15;
            uint4 v = *(const uint4*)(W1 + (size_t)(ffc * 128 + r) * 128 + c16 * 8);
            *(uint4*)(Bs + r * 256 + ((c16 ^ (r & 7)) * 16)) = v;
        }
        __syncthreads();                // W1 visible

        // ---- FFN1: acc1 = x @ W1chunk^T (x from registers)
        floatx4 acc1[4][2];
#pragma unroll
        for (int i = 0; i < 4; ++i)
#pragma unroll
            for (int j = 0; j < 2; ++j) acc1[i][j] = (floatx4)0.f;
#pragma unroll
        for (int kk2 = 0; kk2 < 4; ++kk2) {
            int ca = kk2 * 4 + lq;
            bf16x8 wf[4];
#pragma unroll
            for (int i = 0; i < 4; ++i) {
                int rb = chh * 64 + i * 16 + lr;
                wf[i] = *(const bf16x8*)(Bs + rb * 256 + ((ca ^ (rb & 7)) * 16));
            }
#pragma unroll
            for (int i = 0; i < 4; ++i)
#pragma unroll
                for (int j = 0; j < 2; ++j)
                    acc1[i][j] = __builtin_amdgcn_mfma_f32_16x16x32_bf16(
                        wf[i], af_x[(j << 2) | kk2], acc1[i][j], 0, 0, 0);
        }

        // ---- gelu -> Ps
#pragma unroll
        for (int j = 0; j < 2; ++j) {
            int rowl = rh * 32 + j * 16 + lr;
#pragma unroll
            for (int i = 0; i < 4; ++i) {
                int ch0 = chh * 64 + i * 16 + lq * 4;
                float4 bv = *(const float4*)(b1 + ffc * 128 + ch0);
                float g0, g1, g2, g3, v;
                v = acc1[i][j][0] + bv.x; g0 = 0.5f * v * (1.0f + erff(v * 0.70710678118654752f));
                v = acc1[i][j][1] + bv.y; g1 = 0.5f * v * (1.0f + erff(v * 0.70710678118654752f));
                v = acc1[i][j][2] + bv.z; g2 = 0.5f * v * (1.0f + erff(v * 0.70710678118654752f));
                v = acc1[i][j][3] + bv.w; g3 = 0.5f * v * (1.0f + erff(v * 0.70710678118654752f));
                uint2 u; u.x = pkbf(g0, g1); u.y = pkbf(g2, g3);
                *(uint2*)(Ps + rowl * 136 + ch0) = u;
            }
        }
        __syncthreads();                // FFN1 Bs reads done -> W2 may overwrite

        // ---- load full W2 chunk (128 rows x 128 K of this ffc)
#pragma unroll
        for (int it = 0; it < 8; ++it) {
            int idx = it * 256 + tid;
            int r = idx >> 4, c16 = idx & 15;
            uint4 v = *(const uint4*)(W2 + (size_t)r * 512 + ffc * 128 + c16 * 8);
            *(uint4*)(Bs + r * 256 + ((c16 ^ (r & 7)) * 16)) = v;
        }
        __syncthreads();                // W2 + Ps visible

        // ---- FFN2: acc2 += W2chunk @ P
#pragma unroll
        for (int kk2 = 0; kk2 < 4; ++kk2) {
            int ca = kk2 * 4 + lq;
            bf16x8 wf[4], af[2];
#pragma unroll
            for (int i = 0; i < 4; ++i) {
                int rb = chh * 64 + i * 16 + lr;
                wf[i] = *(const bf16x8*)(Bs + rb * 256 + ((ca ^ (rb & 7)) * 16));
            }
#pragma unroll
            for (int j = 0; j < 2; ++j) {
                int rowl = rh * 32 + j * 16 + lr;
                af[j] = *(const bf16x8*)(Ps + rowl * 136 + kk2 * 32 + lq * 8);
            }
#pragma unroll
            for (int i = 0; i < 4; ++i)
#pragma unroll
                for (int j = 0; j < 2; ++j)
                    acc2[i][j] = __builtin_amdgcn_mfma_f32_16x16x32_bf16(
                        wf[i], af[j], acc2[i][j], 0, 0, 0);
        }
    }

    // ---- epilogue: + b2 + residual, LayerNorm, store
    int chb[4], arow[2];
#pragma unroll
    for (int i = 0; i < 4; ++i) chb[i] = chh * 64 + i * 16 + lq * 4;
#pragma unroll
    for (int j = 0; j < 2; ++j) arow[j] = m0 + rh * 32 + j * 16 + lr;

    float4 bias[4], gv[4], bv[4];
#pragma unroll
    for (int i = 0; i < 4; ++i) {
        bias[i] = *(const float4*)(b2 + chb[i]);
        gv[i]   = *(const float4*)(lng + chb[i]);
        bv[i]   = *(const float4*)(lnb + chb[i]);
    }
#pragma unroll
    for (int j = 0; j < 2; ++j) {
#pragma unroll
        for (int i = 0; i < 4; ++i) {
            ushort4 r4 = *(const ushort4*)(X + (size_t)arow[j] * 128 + chb[i]);
            acc2[i][j][0] += ((const float*)&bias[i])[0] + bf2f(r4.x);
            acc2[i][j][1] += ((const float*)&bias[i])[1] + bf2f(r4.y);
            acc2[i][j][2] += ((const float*)&bias[i])[2] + bf2f(r4.z);
            acc2[i][j][3] += ((const float*)&bias[i])[3] + bf2f(r4.w);
        }
    }
#pragma unroll
    for (int j = 0; j < 2; ++j) {
        float s = 0.f, q = 0.f;
#pragma unroll
        for (int i = 0; i < 4; ++i)
#pragma unroll
            for (int reg = 0; reg < 4; ++reg) {
                float v = acc2[i][j][reg];
                s += v; q += v * v;
            }
        s += __shfl_xor(s, 16); q += __shfl_xor(q, 16);
        s += __shfl_xor(s, 32); q += __shfl_xor(q, 32);
        if (lq == 0) lnS[chh][rh * 32 + j * 16 + lr] = make_float2(s, q);
    }
    __syncthreads();
#pragma unroll
    for (int j = 0; j < 2; ++j) {
        int rl = rh * 32 + j * 16 + lr;
        float2 s0 = lnS[0][rl], s1 = lnS[1][rl];
        float mu  = (s0.x + s1.x) * (1.0f / 128.0f);
        float var = (s0.y + s1.y) * (1.0f / 128.0f) - mu * mu;
        float rstd = rsqrtf(var + 1e-5f);
#pragma unroll
        for (int i = 0; i < 4; ++i) {
            uint2 u;
            u.x = pkbf((acc2[i][j][0] - mu) * rstd * ((const float*)&gv[i])[0] + ((const float*)&bv[i])[0],
                       (acc2[i][j][1] - mu) * rstd * ((const float*)&gv[i])[1] + ((const float*)&bv[i])[1]);
            u.y = pkbf((acc2[i][j][2] - mu) * rstd * ((const float*)&gv[i])[2] + ((const float*)&bv[i])[2],
                       (acc2[i][j][3] - mu) * rstd * ((const float*)&gv[i])[3] + ((const float*)&bv[i])[3]);
            *(uint2*)(Out + (size_t)arow[j] * 128 + chb[i]) = u;
        }
    }
}

// ---------------------------------------------------------------------------
__global__ void gather_kernel(const ushort* __restrict__ x,
                              const int* __restrict__ seqlen,
                              float* __restrict__ out, int b0, int Bc)
{
    int i = blockIdx.x * 256 + threadIdx.x;
    if (i >= Bc * D) return;
    int b = i >> 7, d = i & 127;
    int idx = seqlen[b0 + b] - 1;
    out[(size_t)(b0 + b) * D + d] = bf2f(x[((size_t)b * SEQ + idx) * D + d]);
}

// ---------------------------------------------------------------------------
extern "C" void kernel_launch(void* const* d_in, const int* in_sizes, int n_in,
                              void* d_out, int out_size, void* d_ws, size_t ws_size,
                              hipStream_t stream)
{
    const float* token_emb  = (const float*)d_in[0];
    const float* emb_ln_g   = (const float*)d_in[1];
    const float* emb_ln_b   = (const float*)d_in[2];
    const float* params_log = (const float*)d_in[3];
    const float* in_wr      = (const float*)d_in[4];
    const float* in_wi      = (const float*)d_in[5];
    const float* in_br      = (const float*)d_in[6];
    const float* in_bi      = (const float*)d_in[7];
    const float* out_wr     = (const float*)d_in[8];
    const float* out_wi     = (const float*)d_in[9];
    const float* out_br     = (const float*)d_in[10];
    const float* lru_ln_g   = (const float*)d_in[12];
    const float* lru_ln_b   = (const float*)d_in[13];
    const float* w1         = (const float*)d_in[14];
    const float* b1         = (const float*)d_in[15];
    const float* w2         = (const float*)d_in[16];
    const float* b2         = (const float*)d_in[17];
    const float* ffn_ln_g   = (const float*)d_in[18];
    const float* ffn_ln_b   = (const float*)d_in[19];
    const int*   item_seq   = (const int*)d_in[20];
    const int*   item_seq_len = (const int*)d_in[21];
    float* out = (float*)d_out;

    char* ws = (char*)d_ws;
    ushort* Winb   = (ushort*)ws;                      ws += NLAY * 65536 * 2;
    ushort* W2effb = (ushort*)ws;                      ws += NLAY * 65536 * 2;
    ushort* w1b    = (ushort*)ws;                      ws += NLAY * 65536 * 2;
    ushort* w2b    = (ushort*)ws;                      ws += NLAY * 65536 * 2;
    float* lam_pow = (float*)ws;                       ws += NLAY * 65536 * 4;
    float* scale_in = (float*)ws;                      ws += NLAY * 512 * 4;
    float* bias_in  = (float*)ws;                      ws += NLAY * 512 * 4;
    size_t table_bytes = (size_t)(ws - (char*)d_ws);

    int Bc = B_TOT;
    while (Bc > 32) {
        size_t need = table_bytes + (size_t)Bc * SEQ * (D * 2 + 2 * DH * 2) + 1024;
        if (need <= ws_size) break;
        Bc >>= 1;
    }
    ushort* xb = (ushort*)ws;                          ws += (size_t)Bc * SEQ * D * 2;
    ushort* hb = (ushort*)ws;

    setup_params_kernel<<<NLAY, 256, 0, stream>>>(params_log, in_br, in_bi,
                                                  lam_pow, scale_in, bias_in);
    setup_weights_kernel<<<NLAY * 65536 / 256, 256, 0, stream>>>(
        in_wr, in_wi, out_wr, out_wi, w1, w2, Winb, W2effb, w1b, w2b);

    for (int b0 = 0; b0 < B_TOT; b0 += Bc) {
        int M = Bc * SEQ;
        embed_ln_kernel<<<M / 4, 256, 0, stream>>>(
            token_emb, item_seq + (size_t)b0 * SEQ, emb_ln_g, emb_ln_b, xb);

        for (int li = 0; li < NLAY; ++li) {
            // fused in-proj + exact tree scan -> H layout
            inproj_scan_kernel<<<dim3(16, Bc), 512, 0, stream>>>(
                xb, Winb + (size_t)li * 65536, hb,
                (const float2*)(lam_pow + (size_t)li * 65536),
                item_seq + (size_t)b0 * SEQ,
                scale_in + li * 512, bias_in + li * 512);
            // out-proj + bias + residual + LN -> bf16 x (256-row tiles)
            gemm_bf16_kernel<1, true><<<dim3(M / 256, 1), 512, 0, stream>>>(
                hb, W2effb + (size_t)li * 65536, xb, M, D, 2 * DH,
                out_br + li * D, (const float*)0, xb,
                lru_ln_g + li * D, lru_ln_b + li * D);
            // fused FFN1+gelu+FFN2+residual+LN (in place on xb), fat stages
            ffn_fused_kernel<<<dim3(M / 64), 256, 0, stream>>>(
                xb, w1b + (size_t)li * 65536, w2b + (size_t)li * 65536, xb,
                b1 + li * DFF, b2 + li * D,
                ffn_ln_g + li * D, ffn_ln_b + li * D);
        }
        gather_kernel<<<(Bc * D + 255) / 256, 256, 0, stream>>>(
            xb, item_seq_len, out, b0, Bc);
    }
}

// Round 17
// 609.802 us; speedup vs baseline: 1.2078x; 1.0074x over previous
//
#include <hip/hip_runtime.h>
#include <hip/hip_bf16.h>
#include <math.h>

#define B_TOT 512
#define SEQ   200
#define D     128
#define DH    256
#define DFF   512
#define LPAD  256
#define PADL  56
#define NLAY  2
#define SST   18   // scan LDS row stride (floats)

typedef __attribute__((ext_vector_type(8))) short bf16x8;
typedef __attribute__((ext_vector_type(4))) float floatx4;

static __device__ inline float bf2f(ushort u) {
    union { unsigned int i; float f; } v; v.i = ((unsigned int)u) << 16; return v.f;
}
static __device__ inline ushort f2bf(float x) {
    union { float f; unsigned int i; } v; v.f = x;
    unsigned int r = (v.i + 0x7FFFu + ((v.i >> 16) & 1u)) >> 16;   // RNE
    return (ushort)r;
}
// HW packed f32x2 -> bf16x2 (v_cvt_pk_bf16_f32 on gfx950), RNE
static __device__ inline unsigned int pkbf(float a, float b) {
    union { __hip_bfloat162 h; unsigned int u; } v;
    v.h = __float22bfloat162_rn(make_float2(a, b));
    return v.u;
}
// async global->LDS, 16B per lane; LDS dest = wave-uniform base + lane*16
static __device__ inline void gld_lds16(const void* g, void* l) {
    __builtin_amdgcn_global_load_lds(
        (const __attribute__((address_space(1))) unsigned int*)g,
        (__attribute__((address_space(3))) unsigned int*)l, 16, 0, 0);
}

// H layout: [b][g(8)][p(re/im)][s(200)][32 ch] bf16. k in 0..511: k<256 re, else im.
static __device__ inline size_t haddr(int b, int s, int k) {
    int p  = k >> 8;
    int ch = k & 255;
    int g  = ch >> 5;
    int cl = ch & 31;
    return (((((size_t)b * 8 + g) * 2 + p) * SEQ + s) * 32 + cl);
}

// ---------------------------------------------------------------------------
// lambda powers (TRANSPOSED: [ch][128] float2, entry j = lambda^{j+1})
// + in-proj epilogue scale/bias
// ---------------------------------------------------------------------------
__global__ void setup_params_kernel(const float* __restrict__ params_log,
                                    const float* __restrict__ in_br,
                                    const float* __restrict__ in_bi,
                                    float* __restrict__ lam_pow,   // [NLAY][256][128] float2
                                    float* __restrict__ scale_in,  // [NLAY][512]
                                    float* __restrict__ bias_in)   // [NLAY][512]
{
    int li = blockIdx.x;
    int c  = threadIdx.x;             // 256 threads
    const float* pl = params_log + (size_t)li * 3 * DH;
    float nu = expf(pl[c]);
    float th = expf(pl[DH + c]);
    float ga = expf(pl[2 * DH + c]);
    float mag = expf(-nu);
    float lr = mag * cosf(th);
    float lim = mag * sinf(th);
    float2* lp = (float2*)(lam_pow + (size_t)li * 65536) + (size_t)c * 128;
    float pr = lr, pi = lim;
    lp[0] = make_float2(pr, pi);
    for (int k = 1; k < 128; ++k) {
        float nr = pr * lr - pi * lim;
        float ni = pr * lim + pi * lr;
        pr = nr; pi = ni;
        lp[k] = make_float2(pr, pi);
    }
    scale_in[li * 2 * DH + c]      = ga;
    scale_in[li * 2 * DH + DH + c] = ga;
    bias_in[li * 2 * DH + c]       = in_br[li * DH + c] * ga;
    bias_in[li * 2 * DH + DH + c]  = in_bi[li * DH + c] * ga;
}

// w1b/w2b are stored as PRE-SWIZZLED LDS images (R17): per ffc-chunk, 16B
// chunk q holds W[r][(q&15)^(r&7)] with r=q>>4 — so a lane-linear
// global_load_lds fill reproduces the XOR-swizzled LDS layout exactly.
__global__ void setup_weights_kernel(const float* __restrict__ in_wr,
                                     const float* __restrict__ in_wi,
                                     const float* __restrict__ out_wr,
                                     const float* __restrict__ out_wi,
                                     const float* __restrict__ w1,
                                     const float* __restrict__ w2,
                                     ushort* __restrict__ Winb,
                                     ushort* __restrict__ W2effb,
                                     ushort* __restrict__ w1b,
                                     ushort* __restrict__ w2b)
{
    int idx = blockIdx.x * blockDim.x + threadIdx.x;   // NLAY*65536
    int li = idx >> 16;
    int r  = idx & 65535;

    int n = r >> 7, d = r & 127;
    float wv = (n < DH) ? in_wr[((size_t)li * DH + n) * D + d]
                        : in_wi[((size_t)li * DH + (n - DH)) * D + d];
    Winb[idx] = f2bf(wv);

    int dd = r >> 9, cc = r & 511;
    float w2v = (cc < DH) ? out_wr[((size_t)li * D + dd) * DH + cc]
                          : -out_wi[((size_t)li * D + dd) * DH + (cc - DH)];
    W2effb[idx] = f2bf(w2v);

    {   // W1 logical [512][128] -> swizzled image
        int row = r >> 7, col = r & 127;
        int ffc = row >> 7, rl = row & 127;
        int c16 = col >> 3, e8 = col & 7;
        int cs = c16 ^ (rl & 7);
        w1b[li * 65536 + ffc * 16384 + rl * 128 + cs * 8 + e8] = f2bf(w1[idx]);
    }
    {   // W2 logical [128][512] -> swizzled image
        int dd2 = r >> 9, kk = r & 511;
        int ffc = kk >> 7, klc = kk & 127;
        int c16 = klc >> 3, e8 = klc & 7;
        int cs = c16 ^ (dd2 & 7);
        w2b[li * 65536 + ffc * 16384 + dd2 * 128 + cs * 8 + e8] = f2bf(w2[idx]);
    }
}

// ---------------------------------------------------------------------------
// Embedding gather + LayerNorm -> bf16 x
// ---------------------------------------------------------------------------
__global__ __launch_bounds__(256) void embed_ln_kernel(
    const float* __restrict__ emb, const int* __restrict__ seq,
    const float* __restrict__ g, const float* __restrict__ bt,
    ushort* __restrict__ x)
{
    int row  = blockIdx.x * 4 + (threadIdx.x >> 6);
    int lane = threadIdx.x & 63;
    int item = seq[row];
    float2 v = *(const float2*)(emb + (size_t)item * D + lane * 2);
    float s = v.x + v.y;
#pragma unroll
    for (int o = 32; o > 0; o >>= 1) s += __shfl_xor(s, o);
    float mu = s * (1.0f / D);
    float d0 = v.x - mu, d1 = v.y - mu;
    float vs = d0 * d0 + d1 * d1;
#pragma unroll
    for (int o = 32; o > 0; o >>= 1) vs += __shfl_xor(vs, o);
    float rstd = rsqrtf(vs * (1.0f / D) + 1e-5f);
    float2 gg = *(const float2*)(g + lane * 2);
    float2 bb = *(const float2*)(bt + lane * 2);
    unsigned int o2 = pkbf(d0 * rstd * gg.x + bb.x, d1 * rstd * gg.y + bb.y);
    *(unsigned int*)(x + (size_t)row * D + lane * 2) = o2;
}

// ---------------------------------------------------------------------------
// FUSED in-proj + exact tree scan, two-stage x staging (R14 known-good).
// Grid = (gp, b): gp fast -> blocks sharing x[b] are dispatch-adjacent.
// ---------------------------------------------------------------------------
__global__ __launch_bounds__(512) void inproj_scan_kernel(
    const ushort* __restrict__ X, const ushort* __restrict__ Win,
    ushort* __restrict__ H, const float2* __restrict__ lamT,
    const int* __restrict__ seq,
    const float* __restrict__ scale_in, const float* __restrict__ bias_in)
{
    __shared__ __align__(16) char smem[36864];   // Ws 8192 + xs 28672 (phase A)
    __shared__ float mkf[LPAD];
    char*  Wsm = smem;                           // [32][128] bf16, swizzled
    char*  xs  = smem + 8192;                    // [112][128] bf16, swizzled
    float* stR = (float*)smem;                   // [256][SST] (phase B alias)
    float* stI = stR + LPAD * SST;               // ends at 36864 B
    float2* lamS = (float2*)smem;                // [16][130] (tree phase alias)
    float2* bc   = (float2*)(smem + 16 * 130 * 8);

    int gp = blockIdx.x, b = blockIdx.y;
    int tid = threadIdx.x;
    int l = tid & 63, w = tid >> 6;              // 8 waves
    int ct = w & 1;                              // 0=re tile, 1=im tile
    int rq = w >> 1;                             // row quarter 0..3
    int lr = l & 15, lq = l >> 4;

    int c  = tid & 15;                           // scan channel
    int tl = tid >> 4;                           // 0..31
    int t0 = tl * 8;

    const float2* myl = lamT + (size_t)(gp * 16 + c) * 128;
    float2 l14[4];
#pragma unroll
    for (int k = 0; k < 4; ++k) l14[k] = myl[k];

    if (tid < LPAD) {
        int t = tid;
        float m = 0.f;
        if (t >= PADL) m = (seq[(size_t)b * SEQ + (t - PADL)] > 0) ? 1.f : 0.f;
        mkf[t] = m;
    }

    // ---- Phase A: stage Ws + x stage A (rows 0..111)
    const ushort* xrow = X + (size_t)b * SEQ * 128;
    {
        int r = tid >> 4, c16 = tid & 15;
        int n = (r < 16) ? (gp * 16 + r) : (256 + gp * 16 + (r - 16));
        uint4 v = *(const uint4*)(Win + (size_t)n * 128 + c16 * 8);
        *(uint4*)(Wsm + r * 256 + ((c16 ^ (r & 7)) * 16)) = v;
    }
#pragma unroll
    for (int it = 0; it < 4; ++it) {
        int idx = it * 512 + tid;
        if (idx < 112 * 16) {
            int r = idx >> 4, c16 = idx & 15;
            uint4 v = *(const uint4*)(xrow + (size_t)r * 128 + c16 * 8);
            *(uint4*)(xs + r * 256 + ((c16 ^ (r & 7)) * 16)) = v;
        }
    }
    __syncthreads();

    bf16x8 wf[4];
#pragma unroll
    for (int kk = 0; kk < 4; ++kk) {
        int ca = kk * 4 + lq;
        int wr = ct * 16 + lr;
        wf[kk] = *(const bf16x8*)(Wsm + wr * 256 + ((ca ^ (wr & 7)) * 16));
    }
    int tstart = rq ? (3 * rq + 1) : 0;          // 0 / 4 / 7 / 10
    int tcnt   = rq ? 3 : 4;
    floatx4 acc[4];
#pragma unroll
    for (int tt = 0; tt < 4; ++tt) acc[tt] = (floatx4)0.f;

    if (rq < 2) {
#pragma unroll
        for (int tt = 0; tt < 4; ++tt) {
            if (tt < tcnt) {
                int t  = tstart + tt;
                int ar = t * 16 + lr;
#pragma unroll
                for (int kk = 0; kk < 4; ++kk) {
                    int ca = kk * 4 + lq;
                    bf16x8 af = *(const bf16x8*)(xs + ar * 256 + ((ca ^ (ar & 7)) * 16));
                    acc[tt] = __builtin_amdgcn_mfma_f32_16x16x32_bf16(wf[kk], af, acc[tt], 0, 0, 0);
                }
            }
        }
    }
    __syncthreads();

#pragma unroll
    for (int it = 0; it < 3; ++it) {
        int idx = it * 512 + tid;                // exactly 96*16 = 1536
        int r = idx >> 4, c16 = idx & 15;
        int gr = 112 + r;
        uint4 v = make_uint4(0u, 0u, 0u, 0u);
        if (gr < 200) v = *(const uint4*)(xrow + (size_t)gr * 128 + c16 * 8);
        *(uint4*)(xs + r * 256 + ((c16 ^ (r & 7)) * 16)) = v;
    }
    __syncthreads();

    if (rq >= 2) {
#pragma unroll
        for (int tt = 0; tt < 4; ++tt) {
            if (tt < tcnt) {
                int t  = tstart + tt;
                int ar = (t - 7) * 16 + lr;
#pragma unroll
                for (int kk = 0; kk < 4; ++kk) {
                    int ca = kk * 4 + lq;
                    bf16x8 af = *(const bf16x8*)(xs + ar * 256 + ((ca ^ (ar & 7)) * 16));
                    acc[tt] = __builtin_amdgcn_mfma_f32_16x16x32_bf16(wf[kk], af, acc[tt], 0, 0, 0);
                }
            }
        }
    }
    __syncthreads();

    // ---- Phase B: zero pad rows + epilogue -> stR/stI
    for (int idx = tid; idx < PADL * SST; idx += 512) { stR[idx] = 0.f; stI[idx] = 0.f; }
    {
        float4 g4 = *(const float4*)(scale_in + ct * 256 + gp * 16 + lq * 4);
        float4 b4 = *(const float4*)(bias_in  + ct * 256 + gp * 16 + lq * 4);
        float* dst = ct ? stI : stR;
#pragma unroll
        for (int tt = 0; tt < 4; ++tt) {
            if (tt < tcnt) {
                int t = tstart + tt;
                int s = t * 16 + lr;
                if (s < 200) {
                    int pos = s + PADL;
                    dst[pos * SST + lq * 4 + 0] = acc[tt][0] * g4.x + b4.x;
                    dst[pos * SST + lq * 4 + 1] = acc[tt][1] * g4.y + b4.y;
                    dst[pos * SST + lq * 4 + 2] = acc[tt][2] * g4.z + b4.z;
                    dst[pos * SST + lq * 4 + 3] = acc[tt][3] * g4.w + b4.w;
                }
            }
        }
    }
    __syncthreads();

    float xr[8], xi[8], mf[8];
#pragma unroll
    for (int k = 0; k < 8; ++k) {
        xr[k] = stR[(t0 + k) * SST + c];
        xi[k] = stI[(t0 + k) * SST + c];
        mf[k] = mkf[t0 + k];
    }
    __syncthreads();

    {
        const char* src = (const char*)(lamT + (size_t)gp * 16 * 128);
#pragma unroll
        for (int it = 0; it < 2; ++it) {
            int idx = it * 512 + tid;
            int row = idx >> 6, c4 = idx & 63;
            *(uint4*)((char*)lamS + row * 1040 + c4 * 16) =
                *(const uint4*)(src + row * 1024 + c4 * 16);
        }
    }

    {
#pragma unroll
        for (int k = 0; k < 8; k += 2) {
            float sr = xr[k] * mf[k], si = xi[k] * mf[k];
            xr[k+1] += l14[0].x * sr - l14[0].y * si;
            xi[k+1] += l14[0].x * si + l14[0].y * sr;
        }
#pragma unroll
        for (int k = 1; k < 8; k += 4) {
            float sr = xr[k] * mf[k], si = xi[k] * mf[k];
            xr[k+1] += l14[0].x * sr - l14[0].y * si;
            xi[k+1] += l14[0].x * si + l14[0].y * sr;
            xr[k+2] += l14[1].x * sr - l14[1].y * si;
            xi[k+2] += l14[1].x * si + l14[1].y * sr;
        }
        {
            float sr = xr[3] * mf[3], si = xi[3] * mf[3];
#pragma unroll
            for (int j = 0; j < 4; ++j) {
                xr[4+j] += l14[j].x * sr - l14[j].y * si;
                xi[4+j] += l14[j].x * si + l14[j].y * sr;
            }
        }
    }

#pragma unroll
    for (int i = 4; i <= 8; ++i) {
        int half = 1 << (i - 1);
        int buf  = (i & 1) * 544;
        bc[buf + tl * 17 + c] = make_float2(xr[7], xi[7]);
        __syncthreads();
        int off = t0 & ((half << 1) - 1);
        if (off >= half) {
            int src = t0 - off + half - 1;
            float m = mkf[src];
            float2 sv = bc[buf + (src >> 3) * 17 + c];
            float sr = sv.x * m, si = sv.y * m;
            int e = off - half;
            const float2* lp = lamS + c * 130 + e;
#pragma unroll
            for (int k = 0; k < 8; ++k) {
                float2 lv = lp[k];
                xr[k] += lv.x * sr - lv.y * si;
                xi[k] += lv.x * si + lv.y * sr;
            }
        }
    }
    __syncthreads();

#pragma unroll
    for (int k = 0; k < 8; ++k) {
        stR[(t0 + k) * SST + c] = xr[k];
        stI[(t0 + k) * SST + c] = xi[k];
    }
    __syncthreads();

    int g  = gp >> 1;
    int hc = (gp & 1) * 16;
    ushort* baseg = H + (size_t)(b * 8 + g) * 2 * SEQ * 32 + hc;
#pragma unroll
    for (int it = 0; it < 4; ++it) {
        int idx4 = it * 512 + tid;
        if (idx4 < 2 * SEQ * 4) {
            int q  = idx4 & 3;
            int ps = idx4 >> 2;
            int p  = ps >= SEQ;
            int s  = ps - p * SEQ;
            int t  = s + PADL;
            const float* sp = (p ? stI : stR) + t * SST + q * 4;
            float2 a = *(const float2*)(sp);
            float2 d = *(const float2*)(sp + 2);
            uint2 raw;
            raw.x = pkbf(a.x, a.y);
            raw.y = pkbf(d.x, d.y);
            *(uint2*)(baseg + (size_t)ps * 32 + q * 4) = raw;
        }
    }
}

// ---------------------------------------------------------------------------
// bf16 MFMA GEMM, 512 threads, 256-row M-tile x 128-col N-tile (out-proj).
// MODE 1: bf16 out = LayerNorm(acc + e0[n] + res[m][n])  (N=128)
// AHL: activation operand read from H layout.
// ---------------------------------------------------------------------------
template <int MODE, bool AHL>
__global__ __launch_bounds__(512) void gemm_bf16_kernel(
    const ushort* __restrict__ A, const ushort* __restrict__ W,
    ushort* __restrict__ Cout, int M, int N, int K,
    const float* __restrict__ e0, const float* __restrict__ e1,
    const ushort* __restrict__ res,
    const float* __restrict__ lng, const float* __restrict__ lnb)
{
    __shared__ char As[32768];          // 256 rows x 64K bf16, swizzled
    __shared__ char Bs[16384];          // 128 rows x 64K bf16, swizzled
    __shared__ float2 lnS[2][256];
    int tid = threadIdx.x;
    int l = tid & 63, w = tid >> 6;     // 8 waves
    int chh = w >> 2;                   // N half (0/1)
    int rh  = w & 3;                    // row quarter (0..3)
    int lr = l & 15, lq = l >> 4;
    int m0 = blockIdx.x * 256, n0 = blockIdx.y * 128;

    int cst = tid & 7;                  // staged chunk
    int rr  = tid >> 3;                 // staged row base (0..63)
    int sb[4], ss[4];
    if (AHL) {
#pragma unroll
        for (int it = 0; it < 4; ++it) {
            unsigned int gr = m0 + it * 64 + rr;
            sb[it] = gr / SEQ; ss[it] = gr - sb[it] * SEQ;
        }
    }

    floatx4 acc[4][4];
#pragma unroll
    for (int i = 0; i < 4; ++i)
#pragma unroll
        for (int j = 0; j < 4; ++j) acc[i][j] = (floatx4)0.f;

    for (int k0 = 0; k0 < K; k0 += 64) {
#pragma unroll
        for (int it = 0; it < 4; ++it) {
            int r = it * 64 + rr;
            uint4 va;
            if (AHL) {
                va = *(const uint4*)(A + haddr(sb[it], ss[it], k0 + cst * 8));
            } else {
                va = *(const uint4*)(A + (size_t)(m0 + r) * K + k0 + cst * 8);
            }
            *(uint4*)(As + r * 128 + ((cst ^ (r & 7)) * 16)) = va;
            if (it < 2) {
                uint4 vb = *(const uint4*)(W + (size_t)(n0 + r) * K + k0 + cst * 8);
                *(uint4*)(Bs + r * 128 + ((cst ^ (r & 7)) * 16)) = vb;
            }
        }
        __syncthreads();
#pragma unroll
        for (int kk = 0; kk < 2; ++kk) {
            bf16x8 wf[4], af[4];
            int ca = kk * 4 + lq;
#pragma unroll
            for (int i = 0; i < 4; ++i) {
                int rb = chh * 64 + i * 16 + lr;
                wf[i] = *(const bf16x8*)(Bs + rb * 128 + ((ca ^ (rb & 7)) * 16));
                int ra = rh * 64 + i * 16 + lr;
                af[i] = *(const bf16x8*)(As + ra * 128 + ((ca ^ (ra & 7)) * 16));
            }
#pragma unroll
            for (int i = 0; i < 4; ++i)
#pragma unroll
                for (int j = 0; j < 4; ++j)
                    acc[i][j] = __builtin_amdgcn_mfma_f32_16x16x32_bf16(
                        wf[i], af[j], acc[i][j], 0, 0, 0);
        }
        __syncthreads();
    }

    int chb[4], arow[4];
#pragma unroll
    for (int i = 0; i < 4; ++i) chb[i] = n0 + chh * 64 + i * 16 + lq * 4;
#pragma unroll
    for (int j = 0; j < 4; ++j) arow[j] = m0 + rh * 64 + j * 16 + lr;

    {
        float4 bias[4], gv[4], bv[4];
#pragma unroll
        for (int i = 0; i < 4; ++i) {
            bias[i] = *(const float4*)(e0 + chb[i]);
            gv[i]   = *(const float4*)(lng + chb[i]);
            bv[i]   = *(const float4*)(lnb + chb[i]);
        }
#pragma unroll
        for (int j = 0; j < 4; ++j) {
#pragma unroll
            for (int i = 0; i < 4; ++i) {
                ushort4 r4 = *(const ushort4*)(res + (size_t)arow[j] * 128 + chb[i]);
                acc[i][j][0] += ((const float*)&bias[i])[0] + bf2f(r4.x);
                acc[i][j][1] += ((const float*)&bias[i])[1] + bf2f(r4.y);
                acc[i][j][2] += ((const float*)&bias[i])[2] + bf2f(r4.z);
                acc[i][j][3] += ((const float*)&bias[i])[3] + bf2f(r4.w);
            }
        }
#pragma unroll
        for (int j = 0; j < 4; ++j) {
            float s = 0.f, q = 0.f;
#pragma unroll
            for (int i = 0; i < 4; ++i)
#pragma unroll
                for (int reg = 0; reg < 4; ++reg) {
                    float v = acc[i][j][reg];
                    s += v; q += v * v;
                }
            s += __shfl_xor(s, 16); q += __shfl_xor(q, 16);
            s += __shfl_xor(s, 32); q += __shfl_xor(q, 32);
            if (lq == 0) lnS[chh][rh * 64 + j * 16 + lr] = make_float2(s, q);
        }
        __syncthreads();
#pragma unroll
        for (int j = 0; j < 4; ++j) {
            int rl = rh * 64 + j * 16 + lr;
            float2 s0 = lnS[0][rl], s1 = lnS[1][rl];
            float mu  = (s0.x + s1.x) * (1.0f / 128.0f);
            float var = (s0.y + s1.y) * (1.0f / 128.0f) - mu * mu;
            float rstd = rsqrtf(var + 1e-5f);
#pragma unroll
            for (int i = 0; i < 4; ++i) {
                uint2 u;
                u.x = pkbf((acc[i][j][0] - mu) * rstd * ((const float*)&gv[i])[0] + ((const float*)&bv[i])[0],
                           (acc[i][j][1] - mu) * rstd * ((const float*)&gv[i])[1] + ((const float*)&bv[i])[1]);
                u.y = pkbf((acc[i][j][2] - mu) * rstd * ((const float*)&gv[i])[2] + ((const float*)&bv[i])[2],
                           (acc[i][j][3] - mu) * rstd * ((const float*)&gv[i])[3] + ((const float*)&bv[i])[3]);
                *(uint2*)(Cout + (size_t)arow[j] * 128 + chb[i]) = u;
            }
        }
    }
}

// ---------------------------------------------------------------------------
// Fused FFN v6: out = LN(x + b2 + W2 @ gelu(W1 @ x + b1)).
// 256 threads, 64-row tile, X fragments in registers, erff gelu.
// R17: weight stages use global_load_lds_dwordx4 into pre-swizzled images —
// no VGPR round-trip, no ds_write instructions. 16 barriers as v5.
// ---------------------------------------------------------------------------
__global__ __launch_bounds__(256) void ffn_fused_kernel(
    const ushort* __restrict__ X, const ushort* __restrict__ W1,
    const ushort* __restrict__ W2, ushort* __restrict__ Out,
    const float* __restrict__ b1, const float* __restrict__ b2,
    const float* __restrict__ lng, const float* __restrict__ lnb)
{
    __shared__ __align__(16) char Bs[32768];   // pre-swizzled 32KB weight chunk
    __shared__ ushort Ps[64 * 136];     // P tile, row stride 136
    __shared__ float2 lnS[2][64];
    int tid = threadIdx.x;
    int l = tid & 63, w = tid >> 6;
    int chh = w >> 1, rh = w & 1;
    int lr = l & 15, lq = l >> 4;
    int m0 = blockIdx.x * 64;
    int wbase = tid & ~63;              // wave-uniform chunk base

    // X operand in registers: af_x[(j<<2)|kk2], K = kk2*32 + lq*8
    bf16x8 af_x[8];
#pragma unroll
    for (int j = 0; j < 2; ++j)
#pragma unroll
        for (int kk2 = 0; kk2 < 4; ++kk2) {
            int row = m0 + rh * 32 + j * 16 + lr;
            int k   = kk2 * 32 + lq * 8;
            af_x[(j << 2) | kk2] = *(const bf16x8*)(X + (size_t)row * 128 + k);
        }

    floatx4 acc2[4][2];
#pragma unroll
    for (int i = 0; i < 4; ++i)
#pragma unroll
        for (int j = 0; j < 2; ++j) acc2[i][j] = (floatx4)0.f;

    for (int ffc = 0; ffc < 4; ++ffc) {
        if (ffc) __syncthreads();       // guard Bs overwrite (prev FFN2 reads)
        // ---- async load full W1 chunk image (32 KB, lane-linear)
        {
            const ushort* img = W1 + (size_t)ffc * 16384;
#pragma unroll
            for (int it = 0; it < 8; ++it)
                gld_lds16(img + (size_t)(it * 256 + tid) * 8,
                          Bs + (size_t)(it * 256 + wbase) * 16);
        }
        __syncthreads();                // W1 visible (vmcnt drained at barrier)

        // ---- FFN1: acc1 = x @ W1chunk^T (x from registers)
        floatx4 acc1[4][2];
#pragma unroll
        for (int i = 0; i < 4; ++i)
#pragma unroll
            for (int j = 0; j < 2; ++j) acc1[i][j] = (floatx4)0.f;
#pragma unroll
        for (int kk2 = 0; kk2 < 4; ++kk2) {
            int ca = kk2 * 4 + lq;
            bf16x8 wf[4];
#pragma unroll
            for (int i = 0; i < 4; ++i) {
                int rb = chh * 64 + i * 16 + lr;
                wf[i] = *(const bf16x8*)(Bs + rb * 256 + ((ca ^ (rb & 7)) * 16));
            }
#pragma unroll
            for (int i = 0; i < 4; ++i)
#pragma unroll
                for (int j = 0; j < 2; ++j)
                    acc1[i][j] = __builtin_amdgcn_mfma_f32_16x16x32_bf16(
                        wf[i], af_x[(j << 2) | kk2], acc1[i][j], 0, 0, 0);
        }

        // ---- gelu -> Ps
#pragma unroll
        for (int j = 0; j < 2; ++j) {
            int rowl = rh * 32 + j * 16 + lr;
#pragma unroll
            for (int i = 0; i < 4; ++i) {
                int ch0 = chh * 64 + i * 16 + lq * 4;
                float4 bv = *(const float4*)(b1 + ffc * 128 + ch0);
                float g0, g1, g2, g3, v;
                v = acc1[i][j][0] + bv.x; g0 = 0.5f * v * (1.0f + erff(v * 0.70710678118654752f));
                v = acc1[i][j][1] + bv.y; g1 = 0.5f * v * (1.0f + erff(v * 0.70710678118654752f));
                v = acc1[i][j][2] + bv.z; g2 = 0.5f * v * (1.0f + erff(v * 0.70710678118654752f));
                v = acc1[i][j][3] + bv.w; g3 = 0.5f * v * (1.0f + erff(v * 0.70710678118654752f));
                uint2 u; u.x = pkbf(g0, g1); u.y = pkbf(g2, g3);
                *(uint2*)(Ps + rowl * 136 + ch0) = u;
            }
        }
        __syncthreads();                // FFN1 Bs reads done -> W2 may overwrite

        // ---- async load full W2 chunk image (32 KB, lane-linear)
        {
            const ushort* img = W2 + (size_t)ffc * 16384;
#pragma unroll
            for (int it = 0; it < 8; ++it)
                gld_lds16(img + (size_t)(it * 256 + tid) * 8,
                          Bs + (size_t)(it * 256 + wbase) * 16);
        }
        __syncthreads();                // W2 + Ps visible

        // ---- FFN2: acc2 += W2chunk @ P
#pragma unroll
        for (int kk2 = 0; kk2 < 4; ++kk2) {
            int ca = kk2 * 4 + lq;
            bf16x8 wf[4], af[2];
#pragma unroll
            for (int i = 0; i < 4; ++i) {
                int rb = chh * 64 + i * 16 + lr;
                wf[i] = *(const bf16x8*)(Bs + rb * 256 + ((ca ^ (rb & 7)) * 16));
            }
#pragma unroll
            for (int j = 0; j < 2; ++j) {
                int rowl = rh * 32 + j * 16 + lr;
                af[j] = *(const bf16x8*)(Ps + rowl * 136 + kk2 * 32 + lq * 8);
            }
#pragma unroll
            for (int i = 0; i < 4; ++i)
#pragma unroll
                for (int j = 0; j < 2; ++j)
                    acc2[i][j] = __builtin_amdgcn_mfma_f32_16x16x32_bf16(
                        wf[i], af[j], acc2[i][j], 0, 0, 0);
        }
    }

    // ---- epilogue: + b2 + residual, LayerNorm, store
    int chb[4], arow[2];
#pragma unroll
    for (int i = 0; i < 4; ++i) chb[i] = chh * 64 + i * 16 + lq * 4;
#pragma unroll
    for (int j = 0; j < 2; ++j) arow[j] = m0 + rh * 32 + j * 16 + lr;

    float4 bias[4], gv[4], bv[4];
#pragma unroll
    for (int i = 0; i < 4; ++i) {
        bias[i] = *(const float4*)(b2 + chb[i]);
        gv[i]   = *(const float4*)(lng + chb[i]);
        bv[i]   = *(const float4*)(lnb + chb[i]);
    }
#pragma unroll
    for (int j = 0; j < 2; ++j) {
#pragma unroll
        for (int i = 0; i < 4; ++i) {
            ushort4 r4 = *(const ushort4*)(X + (size_t)arow[j] * 128 + chb[i]);
            acc2[i][j][0] += ((const float*)&bias[i])[0] + bf2f(r4.x);
            acc2[i][j][1] += ((const float*)&bias[i])[1] + bf2f(r4.y);
            acc2[i][j][2] += ((const float*)&bias[i])[2] + bf2f(r4.z);
            acc2[i][j][3] += ((const float*)&bias[i])[3] + bf2f(r4.w);
        }
    }
#pragma unroll
    for (int j = 0; j < 2; ++j) {
        float s = 0.f, q = 0.f;
#pragma unroll
        for (int i = 0; i < 4; ++i)
#pragma unroll
            for (int reg = 0; reg < 4; ++reg) {
                float v = acc2[i][j][reg];
                s += v; q += v * v;
            }
        s += __shfl_xor(s, 16); q += __shfl_xor(q, 16);
        s += __shfl_xor(s, 32); q += __shfl_xor(q, 32);
        if (lq == 0) lnS[chh][rh * 32 + j * 16 + lr] = make_float2(s, q);
    }
    __syncthreads();
#pragma unroll
    for (int j = 0; j < 2; ++j) {
        int rl = rh * 32 + j * 16 + lr;
        float2 s0 = lnS[0][rl], s1 = lnS[1][rl];
        float mu  = (s0.x + s1.x) * (1.0f / 128.0f);
        float var = (s0.y + s1.y) * (1.0f / 128.0f) - mu * mu;
        float rstd = rsqrtf(var + 1e-5f);
#pragma unroll
        for (int i = 0; i < 4; ++i) {
            uint2 u;
            u.x = pkbf((acc2[i][j][0] - mu) * rstd * ((const float*)&gv[i])[0] + ((const float*)&bv[i])[0],
                       (acc2[i][j][1] - mu) * rstd * ((const float*)&gv[i])[1] + ((const float*)&bv[i])[1]);
            u.y = pkbf((acc2[i][j][2] - mu) * rstd * ((const float*)&gv[i])[2] + ((const float*)&bv[i])[2],
                       (acc2[i][j][3] - mu) * rstd * ((const float*)&gv[i])[3] + ((const float*)&bv[i])[3]);
            *(uint2*)(Out + (size_t)arow[j] * 128 + chb[i]) = u;
        }
    }
}

// ---------------------------------------------------------------------------
__global__ void gather_kernel(const ushort* __restrict__ x,
                              const int* __restrict__ seqlen,
                              float* __restrict__ out, int b0, int Bc)
{
    int i = blockIdx.x * 256 + threadIdx.x;
    if (i >= Bc * D) return;
    int b = i >> 7, d = i & 127;
    int idx = seqlen[b0 + b] - 1;
    out[(size_t)(b0 + b) * D + d] = bf2f(x[((size_t)b * SEQ + idx) * D + d]);
}

// ---------------------------------------------------------------------------
extern "C" void kernel_launch(void* const* d_in, const int* in_sizes, int n_in,
                              void* d_out, int out_size, void* d_ws, size_t ws_size,
                              hipStream_t stream)
{
    const float* token_emb  = (const float*)d_in[0];
    const float* emb_ln_g   = (const float*)d_in[1];
    const float* emb_ln_b   = (const float*)d_in[2];
    const float* params_log = (const float*)d_in[3];
    const float* in_wr      = (const float*)d_in[4];
    const float* in_wi      = (const float*)d_in[5];
    const float* in_br      = (const float*)d_in[6];
    const float* in_bi      = (const float*)d_in[7];
    const float* out_wr     = (const float*)d_in[8];
    const float* out_wi     = (const float*)d_in[9];
    const float* out_br     = (const float*)d_in[10];
    const float* lru_ln_g   = (const float*)d_in[12];
    const float* lru_ln_b   = (const float*)d_in[13];
    const float* w1         = (const float*)d_in[14];
    const float* b1         = (const float*)d_in[15];
    const float* w2         = (const float*)d_in[16];
    const float* b2         = (const float*)d_in[17];
    const float* ffn_ln_g   = (const float*)d_in[18];
    const float* ffn_ln_b   = (const float*)d_in[19];
    const int*   item_seq   = (const int*)d_in[20];
    const int*   item_seq_len = (const int*)d_in[21];
    float* out = (float*)d_out;

    char* ws = (char*)d_ws;
    ushort* Winb   = (ushort*)ws;                      ws += NLAY * 65536 * 2;
    ushort* W2effb = (ushort*)ws;                      ws += NLAY * 65536 * 2;
    ushort* w1b    = (ushort*)ws;                      ws += NLAY * 65536 * 2;
    ushort* w2b    = (ushort*)ws;                      ws += NLAY * 65536 * 2;
    float* lam_pow = (float*)ws;                       ws += NLAY * 65536 * 4;
    float* scale_in = (float*)ws;                      ws += NLAY * 512 * 4;
    float* bias_in  = (float*)ws;                      ws += NLAY * 512 * 4;
    size_t table_bytes = (size_t)(ws - (char*)d_ws);

    int Bc = B_TOT;
    while (Bc > 32) {
        size_t need = table_bytes + (size_t)Bc * SEQ * (D * 2 + 2 * DH * 2) + 1024;
        if (need <= ws_size) break;
        Bc >>= 1;
    }
    ushort* xb = (ushort*)ws;                          ws += (size_t)Bc * SEQ * D * 2;
    ushort* hb = (ushort*)ws;

    setup_params_kernel<<<NLAY, 256, 0, stream>>>(params_log, in_br, in_bi,
                                                  lam_pow, scale_in, bias_in);
    setup_weights_kernel<<<NLAY * 65536 / 256, 256, 0, stream>>>(
        in_wr, in_wi, out_wr, out_wi, w1, w2, Winb, W2effb, w1b, w2b);

    for (int b0 = 0; b0 < B_TOT; b0 += Bc) {
        int M = Bc * SEQ;
        embed_ln_kernel<<<M / 4, 256, 0, stream>>>(
            token_emb, item_seq + (size_t)b0 * SEQ, emb_ln_g, emb_ln_b, xb);

        for (int li = 0; li < NLAY; ++li) {
            // fused in-proj + exact tree scan -> H layout
            inproj_scan_kernel<<<dim3(16, Bc), 512, 0, stream>>>(
                xb, Winb + (size_t)li * 65536, hb,
                (const float2*)(lam_pow + (size_t)li * 65536),
                item_seq + (size_t)b0 * SEQ,
                scale_in + li * 512, bias_in + li * 512);
            // out-proj + bias + residual + LN -> bf16 x (256-row tiles)
            gemm_bf16_kernel<1, true><<<dim3(M / 256, 1), 512, 0, stream>>>(
                hb, W2effb + (size_t)li * 65536, xb, M, D, 2 * DH,
                out_br + li * D, (const float*)0, xb,
                lru_ln_g + li * D, lru_ln_b + li * D);
            // fused FFN1+gelu+FFN2+residual+LN (in place on xb), async staging
            ffn_fused_kernel<<<dim3(M / 64), 256, 0, stream>>>(
                xb, w1b + (size_t)li * 65536, w2b + (size_t)li * 65536, xb,
                b1 + li * DFF, b2 + li * D,
                ffn_ln_g + li * D, ffn_ln_b + li * D);
        }
        gather_kernel<<<(Bc * D + 255) / 256, 256, 0, stream>>>(
            xb, item_seq_len, out, b0, Bc);
    }
}

// Round 18
// 609.740 us; speedup vs baseline: 1.2079x; 1.0001x over previous
//
#include <hip/hip_runtime.h>
#include <hip/hip_bf16.h>
#include <math.h>

#define B_TOT 512
#define SEQ   200
#define D     128
#define DH    256
#define DFF   512
#define LPAD  256
#define PADL  56
#define NLAY  2
#define SST   18   // scan LDS row stride (floats)

typedef __attribute__((ext_vector_type(8))) short bf16x8;
typedef __attribute__((ext_vector_type(4))) float floatx4;

static __device__ inline float bf2f(ushort u) {
    union { unsigned int i; float f; } v; v.i = ((unsigned int)u) << 16; return v.f;
}
static __device__ inline ushort f2bf(float x) {
    union { float f; unsigned int i; } v; v.f = x;
    unsigned int r = (v.i + 0x7FFFu + ((v.i >> 16) & 1u)) >> 16;   // RNE
    return (ushort)r;
}
// HW packed f32x2 -> bf16x2 (v_cvt_pk_bf16_f32 on gfx950), RNE
static __device__ inline unsigned int pkbf(float a, float b) {
    union { __hip_bfloat162 h; unsigned int u; } v;
    v.h = __float22bfloat162_rn(make_float2(a, b));
    return v.u;
}
// async global->LDS, 16B per lane; LDS dest = wave-uniform base + lane*16
static __device__ inline void gld_lds16(const void* g, void* l) {
    __builtin_amdgcn_global_load_lds(
        (const __attribute__((address_space(1))) unsigned int*)g,
        (__attribute__((address_space(3))) unsigned int*)l, 16, 0, 0);
}

// H layout: [b][g(8)][p(re/im)][s(200)][32 ch] bf16. k in 0..511: k<256 re, else im.
static __device__ inline size_t haddr(int b, int s, int k) {
    int p  = k >> 8;
    int ch = k & 255;
    int g  = ch >> 5;
    int cl = ch & 31;
    return (((((size_t)b * 8 + g) * 2 + p) * SEQ + s) * 32 + cl);
}

// ---------------------------------------------------------------------------
// Unified setup (R18): one dispatch. Every thread fills one element of each
// pre-swizzled weight image; blocks 0..NLAY-1 additionally compute lambda
// powers + in-proj scale/bias (li = blockIdx.x).
// Image layouts (per li):
//   Winb  : [gp(16)][q(512): r=q>>4, cs=q&15, c16=cs^(r&7)][e8]  (inproj Ws)
//   W2effb: [k0c(8)][q(1024): r=q>>3, cs=q&7, c16=cs^(r&7)][e8]  (out-proj W)
//   w1b   : [ffc(4)][rl(128)][cs(16)=c16^(rl&7)][e8]             (ffn W1)
//   w2b   : [ffc(4)][dd(128)][cs(16)=c16^(dd&7)][e8]             (ffn W2)
// ---------------------------------------------------------------------------
__global__ void setup_all_kernel(const float* __restrict__ params_log,
                                 const float* __restrict__ in_br,
                                 const float* __restrict__ in_bi,
                                 const float* __restrict__ in_wr,
                                 const float* __restrict__ in_wi,
                                 const float* __restrict__ out_wr,
                                 const float* __restrict__ out_wi,
                                 const float* __restrict__ w1,
                                 const float* __restrict__ w2,
                                 ushort* __restrict__ Winb,
                                 ushort* __restrict__ W2effb,
                                 ushort* __restrict__ w1b,
                                 ushort* __restrict__ w2b,
                                 float* __restrict__ lam_pow,
                                 float* __restrict__ scale_in,
                                 float* __restrict__ bias_in)
{
    int idx = blockIdx.x * blockDim.x + threadIdx.x;   // NLAY*65536
    int li = idx >> 16;
    int e  = idx & 65535;

    {   // inproj Ws image
        int gp = e >> 12, rem = e & 4095;
        int q = rem >> 3, e8 = rem & 7;
        int r = q >> 4, cs = q & 15;
        int c16 = cs ^ (r & 7);
        int n = (r < 16) ? (gp * 16 + r) : (256 + gp * 16 + (r - 16));
        int d = c16 * 8 + e8;
        float wv = (n < DH) ? in_wr[((size_t)li * DH + n) * D + d]
                            : in_wi[((size_t)li * DH + (n - DH)) * D + d];
        Winb[idx] = f2bf(wv);
    }
    {   // out-proj W2eff image
        int k0c = e >> 13, rem = e & 8191;
        int q = rem >> 3, e8 = rem & 7;
        int r = q >> 3, cs = q & 7;
        int c16 = cs ^ (r & 7);
        int k = k0c * 64 + c16 * 8 + e8;
        float w2v = (k < DH) ? out_wr[((size_t)li * D + r) * DH + k]
                             : -out_wi[((size_t)li * D + r) * DH + (k - DH)];
        W2effb[idx] = f2bf(w2v);
    }
    {   // ffn W1 image: logical [512][128]
        int row = e >> 7, col = e & 127;
        int ffc = row >> 7, rl = row & 127;
        int c16 = col >> 3, e8 = col & 7;
        int cs = c16 ^ (rl & 7);
        w1b[li * 65536 + ffc * 16384 + rl * 128 + cs * 8 + e8] = f2bf(w1[idx]);
    }
    {   // ffn W2 image: logical [128][512]
        int dd2 = e >> 9, kk = e & 511;
        int ffc = kk >> 7, klc = kk & 127;
        int c16 = klc >> 3, e8 = klc & 7;
        int cs = c16 ^ (dd2 & 7);
        w2b[li * 65536 + ffc * 16384 + dd2 * 128 + cs * 8 + e8] = f2bf(w2[idx]);
    }

    // params (blocks 0..NLAY-1 only; 256 threads = 256 channels)
    if (blockIdx.x < NLAY) {
        int pli = blockIdx.x;
        int c = threadIdx.x;
        const float* pl = params_log + (size_t)pli * 3 * DH;
        float nu = expf(pl[c]);
        float th = expf(pl[DH + c]);
        float ga = expf(pl[2 * DH + c]);
        float mag = expf(-nu);
        float lr = mag * cosf(th);
        float lim = mag * sinf(th);
        float2* lp = (float2*)(lam_pow + (size_t)pli * 65536) + (size_t)c * 128;
        float pr = lr, pi = lim;
        lp[0] = make_float2(pr, pi);
        for (int k = 1; k < 128; ++k) {
            float nr = pr * lr - pi * lim;
            float ni = pr * lim + pi * lr;
            pr = nr; pi = ni;
            lp[k] = make_float2(pr, pi);
        }
        scale_in[pli * 2 * DH + c]      = ga;
        scale_in[pli * 2 * DH + DH + c] = ga;
        bias_in[pli * 2 * DH + c]       = in_br[pli * DH + c] * ga;
        bias_in[pli * 2 * DH + DH + c]  = in_bi[pli * DH + c] * ga;
    }
}

// ---------------------------------------------------------------------------
// Embedding gather + LayerNorm -> bf16 x
// ---------------------------------------------------------------------------
__global__ __launch_bounds__(256) void embed_ln_kernel(
    const float* __restrict__ emb, const int* __restrict__ seq,
    const float* __restrict__ g, const float* __restrict__ bt,
    ushort* __restrict__ x)
{
    int row  = blockIdx.x * 4 + (threadIdx.x >> 6);
    int lane = threadIdx.x & 63;
    int item = seq[row];
    float2 v = *(const float2*)(emb + (size_t)item * D + lane * 2);
    float s = v.x + v.y;
#pragma unroll
    for (int o = 32; o > 0; o >>= 1) s += __shfl_xor(s, o);
    float mu = s * (1.0f / D);
    float d0 = v.x - mu, d1 = v.y - mu;
    float vs = d0 * d0 + d1 * d1;
#pragma unroll
    for (int o = 32; o > 0; o >>= 1) vs += __shfl_xor(vs, o);
    float rstd = rsqrtf(vs * (1.0f / D) + 1e-5f);
    float2 gg = *(const float2*)(g + lane * 2);
    float2 bb = *(const float2*)(bt + lane * 2);
    unsigned int o2 = pkbf(d0 * rstd * gg.x + bb.x, d1 * rstd * gg.y + bb.y);
    *(unsigned int*)(x + (size_t)row * D + lane * 2) = o2;
}

// ---------------------------------------------------------------------------
// FUSED in-proj + exact tree scan, two-stage x staging (R14 known-good).
// R18: Ws staged via global_load_lds from the pre-swizzled Winb image.
// Grid = (gp, b): gp fast -> blocks sharing x[b] are dispatch-adjacent.
// ---------------------------------------------------------------------------
__global__ __launch_bounds__(512) void inproj_scan_kernel(
    const ushort* __restrict__ X, const ushort* __restrict__ Win,
    ushort* __restrict__ H, const float2* __restrict__ lamT,
    const int* __restrict__ seq,
    const float* __restrict__ scale_in, const float* __restrict__ bias_in)
{
    __shared__ __align__(16) char smem[36864];   // Ws 8192 + xs 28672 (phase A)
    __shared__ float mkf[LPAD];
    char*  Wsm = smem;                           // [32][128] bf16, swizzled
    char*  xs  = smem + 8192;                    // [112][128] bf16, swizzled
    float* stR = (float*)smem;                   // [256][SST] (phase B alias)
    float* stI = stR + LPAD * SST;               // ends at 36864 B
    float2* lamS = (float2*)smem;                // [16][130] (tree phase alias)
    float2* bc   = (float2*)(smem + 16 * 130 * 8);

    int gp = blockIdx.x, b = blockIdx.y;
    int tid = threadIdx.x;
    int l = tid & 63, w = tid >> 6;              // 8 waves
    int ct = w & 1;                              // 0=re tile, 1=im tile
    int rq = w >> 1;                             // row quarter 0..3
    int lr = l & 15, lq = l >> 4;
    int wbase = tid & ~63;

    int c  = tid & 15;                           // scan channel
    int tl = tid >> 4;                           // 0..31
    int t0 = tl * 8;

    const float2* myl = lamT + (size_t)(gp * 16 + c) * 128;
    float2 l14[4];
#pragma unroll
    for (int k = 0; k < 4; ++k) l14[k] = myl[k];

    if (tid < LPAD) {
        int t = tid;
        float m = 0.f;
        if (t >= PADL) m = (seq[(size_t)b * SEQ + (t - PADL)] > 0) ? 1.f : 0.f;
        mkf[t] = m;
    }

    // ---- Phase A: async Ws stage (pre-swizzled image) + x stage A (rows 0..111)
    const ushort* xrow = X + (size_t)b * SEQ * 128;
    gld_lds16(Win + (size_t)gp * 4096 + (size_t)tid * 8,
              Wsm + (size_t)wbase * 16);
#pragma unroll
    for (int it = 0; it < 4; ++it) {
        int idx = it * 512 + tid;
        if (idx < 112 * 16) {
            int r = idx >> 4, c16 = idx & 15;
            uint4 v = *(const uint4*)(xrow + (size_t)r * 128 + c16 * 8);
            *(uint4*)(xs + r * 256 + ((c16 ^ (r & 7)) * 16)) = v;
        }
    }
    __syncthreads();

    bf16x8 wf[4];
#pragma unroll
    for (int kk = 0; kk < 4; ++kk) {
        int ca = kk * 4 + lq;
        int wr = ct * 16 + lr;
        wf[kk] = *(const bf16x8*)(Wsm + wr * 256 + ((ca ^ (wr & 7)) * 16));
    }
    int tstart = rq ? (3 * rq + 1) : 0;          // 0 / 4 / 7 / 10
    int tcnt   = rq ? 3 : 4;
    floatx4 acc[4];
#pragma unroll
    for (int tt = 0; tt < 4; ++tt) acc[tt] = (floatx4)0.f;

    if (rq < 2) {
#pragma unroll
        for (int tt = 0; tt < 4; ++tt) {
            if (tt < tcnt) {
                int t  = tstart + tt;
                int ar = t * 16 + lr;
#pragma unroll
                for (int kk = 0; kk < 4; ++kk) {
                    int ca = kk * 4 + lq;
                    bf16x8 af = *(const bf16x8*)(xs + ar * 256 + ((ca ^ (ar & 7)) * 16));
                    acc[tt] = __builtin_amdgcn_mfma_f32_16x16x32_bf16(wf[kk], af, acc[tt], 0, 0, 0);
                }
            }
        }
    }
    __syncthreads();

#pragma unroll
    for (int it = 0; it < 3; ++it) {
        int idx = it * 512 + tid;                // exactly 96*16 = 1536
        int r = idx >> 4, c16 = idx & 15;
        int gr = 112 + r;
        uint4 v = make_uint4(0u, 0u, 0u, 0u);
        if (gr < 200) v = *(const uint4*)(xrow + (size_t)gr * 128 + c16 * 8);
        *(uint4*)(xs + r * 256 + ((c16 ^ (r & 7)) * 16)) = v;
    }
    __syncthreads();

    if (rq >= 2) {
#pragma unroll
        for (int tt = 0; tt < 4; ++tt) {
            if (tt < tcnt) {
                int t  = tstart + tt;
                int ar = (t - 7) * 16 + lr;
#pragma unroll
                for (int kk = 0; kk < 4; ++kk) {
                    int ca = kk * 4 + lq;
                    bf16x8 af = *(const bf16x8*)(xs + ar * 256 + ((ca ^ (ar & 7)) * 16));
                    acc[tt] = __builtin_amdgcn_mfma_f32_16x16x32_bf16(wf[kk], af, acc[tt], 0, 0, 0);
                }
            }
        }
    }
    __syncthreads();

    // ---- Phase B: zero pad rows + epilogue -> stR/stI
    for (int idx = tid; idx < PADL * SST; idx += 512) { stR[idx] = 0.f; stI[idx] = 0.f; }
    {
        float4 g4 = *(const float4*)(scale_in + ct * 256 + gp * 16 + lq * 4);
        float4 b4 = *(const float4*)(bias_in  + ct * 256 + gp * 16 + lq * 4);
        float* dst = ct ? stI : stR;
#pragma unroll
        for (int tt = 0; tt < 4; ++tt) {
            if (tt < tcnt) {
                int t = tstart + tt;
                int s = t * 16 + lr;
                if (s < 200) {
                    int pos = s + PADL;
                    dst[pos * SST + lq * 4 + 0] = acc[tt][0] * g4.x + b4.x;
                    dst[pos * SST + lq * 4 + 1] = acc[tt][1] * g4.y + b4.y;
                    dst[pos * SST + lq * 4 + 2] = acc[tt][2] * g4.z + b4.z;
                    dst[pos * SST + lq * 4 + 3] = acc[tt][3] * g4.w + b4.w;
                }
            }
        }
    }
    __syncthreads();

    float xr[8], xi[8], mf[8];
#pragma unroll
    for (int k = 0; k < 8; ++k) {
        xr[k] = stR[(t0 + k) * SST + c];
        xi[k] = stI[(t0 + k) * SST + c];
        mf[k] = mkf[t0 + k];
    }
    __syncthreads();

    {
        const char* src = (const char*)(lamT + (size_t)gp * 16 * 128);
#pragma unroll
        for (int it = 0; it < 2; ++it) {
            int idx = it * 512 + tid;
            int row = idx >> 6, c4 = idx & 63;
            *(uint4*)((char*)lamS + row * 1040 + c4 * 16) =
                *(const uint4*)(src + row * 1024 + c4 * 16);
        }
    }

    {
#pragma unroll
        for (int k = 0; k < 8; k += 2) {
            float sr = xr[k] * mf[k], si = xi[k] * mf[k];
            xr[k+1] += l14[0].x * sr - l14[0].y * si;
            xi[k+1] += l14[0].x * si + l14[0].y * sr;
        }
#pragma unroll
        for (int k = 1; k < 8; k += 4) {
            float sr = xr[k] * mf[k], si = xi[k] * mf[k];
            xr[k+1] += l14[0].x * sr - l14[0].y * si;
            xi[k+1] += l14[0].x * si + l14[0].y * sr;
            xr[k+2] += l14[1].x * sr - l14[1].y * si;
            xi[k+2] += l14[1].x * si + l14[1].y * sr;
        }
        {
            float sr = xr[3] * mf[3], si = xi[3] * mf[3];
#pragma unroll
            for (int j = 0; j < 4; ++j) {
                xr[4+j] += l14[j].x * sr - l14[j].y * si;
                xi[4+j] += l14[j].x * si + l14[j].y * sr;
            }
        }
    }

#pragma unroll
    for (int i = 4; i <= 8; ++i) {
        int half = 1 << (i - 1);
        int buf  = (i & 1) * 544;
        bc[buf + tl * 17 + c] = make_float2(xr[7], xi[7]);
        __syncthreads();
        int off = t0 & ((half << 1) - 1);
        if (off >= half) {
            int src = t0 - off + half - 1;
            float m = mkf[src];
            float2 sv = bc[buf + (src >> 3) * 17 + c];
            float sr = sv.x * m, si = sv.y * m;
            int e = off - half;
            const float2* lp = lamS + c * 130 + e;
#pragma unroll
            for (int k = 0; k < 8; ++k) {
                float2 lv = lp[k];
                xr[k] += lv.x * sr - lv.y * si;
                xi[k] += lv.x * si + lv.y * sr;
            }
        }
    }
    __syncthreads();

#pragma unroll
    for (int k = 0; k < 8; ++k) {
        stR[(t0 + k) * SST + c] = xr[k];
        stI[(t0 + k) * SST + c] = xi[k];
    }
    __syncthreads();

    int g  = gp >> 1;
    int hc = (gp & 1) * 16;
    ushort* baseg = H + (size_t)(b * 8 + g) * 2 * SEQ * 32 + hc;
#pragma unroll
    for (int it = 0; it < 4; ++it) {
        int idx4 = it * 512 + tid;
        if (idx4 < 2 * SEQ * 4) {
            int q  = idx4 & 3;
            int ps = idx4 >> 2;
            int p  = ps >= SEQ;
            int s  = ps - p * SEQ;
            int t  = s + PADL;
            const float* sp = (p ? stI : stR) + t * SST + q * 4;
            float2 a = *(const float2*)(sp);
            float2 d = *(const float2*)(sp + 2);
            uint2 raw;
            raw.x = pkbf(a.x, a.y);
            raw.y = pkbf(d.x, d.y);
            *(uint2*)(baseg + (size_t)ps * 32 + q * 4) = raw;
        }
    }
}

// ---------------------------------------------------------------------------
// Out-proj GEMM, 512 threads, 256-row M-tile x 128-col N-tile (N=128, n0=0).
// bf16 out = LayerNorm(acc + e0[n] + res[m][n]).
// R18: W staged via global_load_lds from the pre-swizzled W2eff image.
// Activations read from H layout (per-lane gather into swizzled As).
// ---------------------------------------------------------------------------
__global__ __launch_bounds__(512) void outproj_kernel(
    const ushort* __restrict__ A, const ushort* __restrict__ Wimg,
    ushort* __restrict__ Cout, int M,
    const float* __restrict__ e0,
    const ushort* __restrict__ res,
    const float* __restrict__ lng, const float* __restrict__ lnb)
{
    __shared__ __align__(16) char As[32768];    // 256 rows x 64K bf16, swizzled
    __shared__ __align__(16) char Bs[16384];    // 128 rows x 64K bf16, swizzled
    __shared__ float2 lnS[2][256];
    int tid = threadIdx.x;
    int l = tid & 63, w = tid >> 6;     // 8 waves
    int chh = w >> 2;                   // N half (0/1)
    int rh  = w & 3;                    // row quarter (0..3)
    int lr = l & 15, lq = l >> 4;
    int m0 = blockIdx.x * 256;
    int wbase = tid & ~63;

    int cst = tid & 7;                  // staged chunk
    int rr  = tid >> 3;                 // staged row base (0..63)
    int sb[4], ss[4];
#pragma unroll
    for (int it = 0; it < 4; ++it) {
        unsigned int gr = m0 + it * 64 + rr;
        sb[it] = gr / SEQ; ss[it] = gr - sb[it] * SEQ;
    }

    floatx4 acc[4][4];
#pragma unroll
    for (int i = 0; i < 4; ++i)
#pragma unroll
        for (int j = 0; j < 4; ++j) acc[i][j] = (floatx4)0.f;

    for (int k0c = 0; k0c < 8; ++k0c) {
        int k0 = k0c * 64;
        // async W stage: 16KB pre-swizzled image chunk, lane-linear
        {
            const ushort* img = Wimg + (size_t)k0c * 8192;
#pragma unroll
            for (int it = 0; it < 2; ++it)
                gld_lds16(img + (size_t)(it * 512 + tid) * 8,
                          Bs + (size_t)(it * 512 + wbase) * 16);
        }
        // A stage: H-layout gather (per-lane), swizzled LDS write
#pragma unroll
        for (int it = 0; it < 4; ++it) {
            int r = it * 64 + rr;
            uint4 va = *(const uint4*)(A + haddr(sb[it], ss[it], k0 + cst * 8));
            *(uint4*)(As + r * 128 + ((cst ^ (r & 7)) * 16)) = va;
        }
        __syncthreads();
#pragma unroll
        for (int kk = 0; kk < 2; ++kk) {
            bf16x8 wf[4], af[4];
            int ca = kk * 4 + lq;
#pragma unroll
            for (int i = 0; i < 4; ++i) {
                int rb = chh * 64 + i * 16 + lr;
                wf[i] = *(const bf16x8*)(Bs + rb * 128 + ((ca ^ (rb & 7)) * 16));
                int ra = rh * 64 + i * 16 + lr;
                af[i] = *(const bf16x8*)(As + ra * 128 + ((ca ^ (ra & 7)) * 16));
            }
#pragma unroll
            for (int i = 0; i < 4; ++i)
#pragma unroll
                for (int j = 0; j < 4; ++j)
                    acc[i][j] = __builtin_amdgcn_mfma_f32_16x16x32_bf16(
                        wf[i], af[j], acc[i][j], 0, 0, 0);
        }
        __syncthreads();
    }

    int chb[4], arow[4];
#pragma unroll
    for (int i = 0; i < 4; ++i) chb[i] = chh * 64 + i * 16 + lq * 4;
#pragma unroll
    for (int j = 0; j < 4; ++j) arow[j] = m0 + rh * 64 + j * 16 + lr;

    {
        float4 bias[4], gv[4], bv[4];
#pragma unroll
        for (int i = 0; i < 4; ++i) {
            bias[i] = *(const float4*)(e0 + chb[i]);
            gv[i]   = *(const float4*)(lng + chb[i]);
            bv[i]   = *(const float4*)(lnb + chb[i]);
        }
#pragma unroll
        for (int j = 0; j < 4; ++j) {
#pragma unroll
            for (int i = 0; i < 4; ++i) {
                ushort4 r4 = *(const ushort4*)(res + (size_t)arow[j] * 128 + chb[i]);
                acc[i][j][0] += ((const float*)&bias[i])[0] + bf2f(r4.x);
                acc[i][j][1] += ((const float*)&bias[i])[1] + bf2f(r4.y);
                acc[i][j][2] += ((const float*)&bias[i])[2] + bf2f(r4.z);
                acc[i][j][3] += ((const float*)&bias[i])[3] + bf2f(r4.w);
            }
        }
#pragma unroll
        for (int j = 0; j < 4; ++j) {
            float s = 0.f, q = 0.f;
#pragma unroll
            for (int i = 0; i < 4; ++i)
#pragma unroll
                for (int reg = 0; reg < 4; ++reg) {
                    float v = acc[i][j][reg];
                    s += v; q += v * v;
                }
            s += __shfl_xor(s, 16); q += __shfl_xor(q, 16);
            s += __shfl_xor(s, 32); q += __shfl_xor(q, 32);
            if (lq == 0) lnS[chh][rh * 64 + j * 16 + lr] = make_float2(s, q);
        }
        __syncthreads();
#pragma unroll
        for (int j = 0; j < 4; ++j) {
            int rl = rh * 64 + j * 16 + lr;
            float2 s0 = lnS[0][rl], s1 = lnS[1][rl];
            float mu  = (s0.x + s1.x) * (1.0f / 128.0f);
            float var = (s0.y + s1.y) * (1.0f / 128.0f) - mu * mu;
            float rstd = rsqrtf(var + 1e-5f);
#pragma unroll
            for (int i = 0; i < 4; ++i) {
                uint2 u;
                u.x = pkbf((acc[i][j][0] - mu) * rstd * ((const float*)&gv[i])[0] + ((const float*)&bv[i])[0],
                           (acc[i][j][1] - mu) * rstd * ((const float*)&gv[i])[1] + ((const float*)&bv[i])[1]);
                u.y = pkbf((acc[i][j][2] - mu) * rstd * ((const float*)&gv[i])[2] + ((const float*)&bv[i])[2],
                           (acc[i][j][3] - mu) * rstd * ((const float*)&gv[i])[3] + ((const float*)&bv[i])[3]);
                *(uint2*)(Cout + (size_t)arow[j] * 128 + chb[i]) = u;
            }
        }
    }
}

// ---------------------------------------------------------------------------
// Fused FFN v6 (R17 known-good): out = LN(x + b2 + W2 @ gelu(W1 @ x + b1)).
// 256 threads, 64-row tile, X fragments in registers, erff gelu.
// Weight stages use global_load_lds from pre-swizzled images.
// ---------------------------------------------------------------------------
__global__ __launch_bounds__(256) void ffn_fused_kernel(
    const ushort* __restrict__ X, const ushort* __restrict__ W1,
    const ushort* __restrict__ W2, ushort* __restrict__ Out,
    const float* __restrict__ b1, const float* __restrict__ b2,
    const float* __restrict__ lng, const float* __restrict__ lnb)
{
    __shared__ __align__(16) char Bs[32768];   // pre-swizzled 32KB weight chunk
    __shared__ ushort Ps[64 * 136];     // P tile, row stride 136
    __shared__ float2 lnS[2][64];
    int tid = threadIdx.x;
    int l = tid & 63, w = tid >> 6;
    int chh = w >> 1, rh = w & 1;
    int lr = l & 15, lq = l >> 4;
    int m0 = blockIdx.x * 64;
    int wbase = tid & ~63;              // wave-uniform chunk base

    // X operand in registers: af_x[(j<<2)|kk2], K = kk2*32 + lq*8
    bf16x8 af_x[8];
#pragma unroll
    for (int j = 0; j < 2; ++j)
#pragma unroll
        for (int kk2 = 0; kk2 < 4; ++kk2) {
            int row = m0 + rh * 32 + j * 16 + lr;
            int k   = kk2 * 32 + lq * 8;
            af_x[(j << 2) | kk2] = *(const bf16x8*)(X + (size_t)row * 128 + k);
        }

    floatx4 acc2[4][2];
#pragma unroll
    for (int i = 0; i < 4; ++i)
#pragma unroll
        for (int j = 0; j < 2; ++j) acc2[i][j] = (floatx4)0.f;

    for (int ffc = 0; ffc < 4; ++ffc) {
        if (ffc) __syncthreads();       // guard Bs overwrite (prev FFN2 reads)
        {
            const ushort* img = W1 + (size_t)ffc * 16384;
#pragma unroll
            for (int it = 0; it < 8; ++it)
                gld_lds16(img + (size_t)(it * 256 + tid) * 8,
                          Bs + (size_t)(it * 256 + wbase) * 16);
        }
        __syncthreads();                // W1 visible

        floatx4 acc1[4][2];
#pragma unroll
        for (int i = 0; i < 4; ++i)
#pragma unroll
            for (int j = 0; j < 2; ++j) acc1[i][j] = (floatx4)0.f;
#pragma unroll
        for (int kk2 = 0; kk2 < 4; ++kk2) {
            int ca = kk2 * 4 + lq;
            bf16x8 wf[4];
#pragma unroll
            for (int i = 0; i < 4; ++i) {
                int rb = chh * 64 + i * 16 + lr;
                wf[i] = *(const bf16x8*)(Bs + rb * 256 + ((ca ^ (rb & 7)) * 16));
            }
#pragma unroll
            for (int i = 0; i < 4; ++i)
#pragma unroll
                for (int j = 0; j < 2; ++j)
                    acc1[i][j] = __builtin_amdgcn_mfma_f32_16x16x32_bf16(
                        wf[i], af_x[(j << 2) | kk2], acc1[i][j], 0, 0, 0);
        }

#pragma unroll
        for (int j = 0; j < 2; ++j) {
            int rowl = rh * 32 + j * 16 + lr;
#pragma unroll
            for (int i = 0; i < 4; ++i) {
                int ch0 = chh * 64 + i * 16 + lq * 4;
                float4 bv = *(const float4*)(b1 + ffc * 128 + ch0);
                float g0, g1, g2, g3, v;
                v = acc1[i][j][0] + bv.x; g0 = 0.5f * v * (1.0f + erff(v * 0.70710678118654752f));
                v = acc1[i][j][1] + bv.y; g1 = 0.5f * v * (1.0f + erff(v * 0.70710678118654752f));
                v = acc1[i][j][2] + bv.z; g2 = 0.5f * v * (1.0f + erff(v * 0.70710678118654752f));
                v = acc1[i][j][3] + bv.w; g3 = 0.5f * v * (1.0f + erff(v * 0.70710678118654752f));
                uint2 u; u.x = pkbf(g0, g1); u.y = pkbf(g2, g3);
                *(uint2*)(Ps + rowl * 136 + ch0) = u;
            }
        }
        __syncthreads();                // FFN1 Bs reads done -> W2 may overwrite

        {
            const ushort* img = W2 + (size_t)ffc * 16384;
#pragma unroll
            for (int it = 0; it < 8; ++it)
                gld_lds16(img + (size_t)(it * 256 + tid) * 8,
                          Bs + (size_t)(it * 256 + wbase) * 16);
        }
        __syncthreads();                // W2 + Ps visible

#pragma unroll
        for (int kk2 = 0; kk2 < 4; ++kk2) {
            int ca = kk2 * 4 + lq;
            bf16x8 wf[4], af[2];
#pragma unroll
            for (int i = 0; i < 4; ++i) {
                int rb = chh * 64 + i * 16 + lr;
                wf[i] = *(const bf16x8*)(Bs + rb * 256 + ((ca ^ (rb & 7)) * 16));
            }
#pragma unroll
            for (int j = 0; j < 2; ++j) {
                int rowl = rh * 32 + j * 16 + lr;
                af[j] = *(const bf16x8*)(Ps + rowl * 136 + kk2 * 32 + lq * 8);
            }
#pragma unroll
            for (int i = 0; i < 4; ++i)
#pragma unroll
                for (int j = 0; j < 2; ++j)
                    acc2[i][j] = __builtin_amdgcn_mfma_f32_16x16x32_bf16(
                        wf[i], af[j], acc2[i][j], 0, 0, 0);
        }
    }

    // ---- epilogue: + b2 + residual, LayerNorm, store
    int chb[4], arow[2];
#pragma unroll
    for (int i = 0; i < 4; ++i) chb[i] = chh * 64 + i * 16 + lq * 4;
#pragma unroll
    for (int j = 0; j < 2; ++j) arow[j] = m0 + rh * 32 + j * 16 + lr;

    float4 bias[4], gv[4], bv[4];
#pragma unroll
    for (int i = 0; i < 4; ++i) {
        bias[i] = *(const float4*)(b2 + chb[i]);
        gv[i]   = *(const float4*)(lng + chb[i]);
        bv[i]   = *(const float4*)(lnb + chb[i]);
    }
#pragma unroll
    for (int j = 0; j < 2; ++j) {
#pragma unroll
        for (int i = 0; i < 4; ++i) {
            ushort4 r4 = *(const ushort4*)(X + (size_t)arow[j] * 128 + chb[i]);
            acc2[i][j][0] += ((const float*)&bias[i])[0] + bf2f(r4.x);
            acc2[i][j][1] += ((const float*)&bias[i])[1] + bf2f(r4.y);
            acc2[i][j][2] += ((const float*)&bias[i])[2] + bf2f(r4.z);
            acc2[i][j][3] += ((const float*)&bias[i])[3] + bf2f(r4.w);
        }
    }
#pragma unroll
    for (int j = 0; j < 2; ++j) {
        float s = 0.f, q = 0.f;
#pragma unroll
        for (int i = 0; i < 4; ++i)
#pragma unroll
            for (int reg = 0; reg < 4; ++reg) {
                float v = acc2[i][j][reg];
                s += v; q += v * v;
            }
        s += __shfl_xor(s, 16); q += __shfl_xor(q, 16);
        s += __shfl_xor(s, 32); q += __shfl_xor(q, 32);
        if (lq == 0) lnS[chh][rh * 32 + j * 16 + lr] = make_float2(s, q);
    }
    __syncthreads();
#pragma unroll
    for (int j = 0; j < 2; ++j) {
        int rl = rh * 32 + j * 16 + lr;
        float2 s0 = lnS[0][rl], s1 = lnS[1][rl];
        float mu  = (s0.x + s1.x) * (1.0f / 128.0f);
        float var = (s0.y + s1.y) * (1.0f / 128.0f) - mu * mu;
        float rstd = rsqrtf(var + 1e-5f);
#pragma unroll
        for (int i = 0; i < 4; ++i) {
            uint2 u;
            u.x = pkbf((acc2[i][j][0] - mu) * rstd * ((const float*)&gv[i])[0] + ((const float*)&bv[i])[0],
                       (acc2[i][j][1] - mu) * rstd * ((const float*)&gv[i])[1] + ((const float*)&bv[i])[1]);
            u.y = pkbf((acc2[i][j][2] - mu) * rstd * ((const float*)&gv[i])[2] + ((const float*)&bv[i])[2],
                       (acc2[i][j][3] - mu) * rstd * ((const float*)&gv[i])[3] + ((const float*)&bv[i])[3]);
            *(uint2*)(Out + (size_t)arow[j] * 128 + chb[i]) = u;
        }
    }
}

// ---------------------------------------------------------------------------
__global__ void gather_kernel(const ushort* __restrict__ x,
                              const int* __restrict__ seqlen,
                              float* __restrict__ out, int b0, int Bc)
{
    int i = blockIdx.x * 256 + threadIdx.x;
    if (i >= Bc * D) return;
    int b = i >> 7, d = i & 127;
    int idx = seqlen[b0 + b] - 1;
    out[(size_t)(b0 + b) * D + d] = bf2f(x[((size_t)b * SEQ + idx) * D + d]);
}

// ---------------------------------------------------------------------------
extern "C" void kernel_launch(void* const* d_in, const int* in_sizes, int n_in,
                              void* d_out, int out_size, void* d_ws, size_t ws_size,
                              hipStream_t stream)
{
    const float* token_emb  = (const float*)d_in[0];
    const float* emb_ln_g   = (const float*)d_in[1];
    const float* emb_ln_b   = (const float*)d_in[2];
    const float* params_log = (const float*)d_in[3];
    const float* in_wr      = (const float*)d_in[4];
    const float* in_wi      = (const float*)d_in[5];
    const float* in_br      = (const float*)d_in[6];
    const float* in_bi      = (const float*)d_in[7];
    const float* out_wr     = (const float*)d_in[8];
    const float* out_wi     = (const float*)d_in[9];
    const float* out_br     = (const float*)d_in[10];
    const float* lru_ln_g   = (const float*)d_in[12];
    const float* lru_ln_b   = (const float*)d_in[13];
    const float* w1         = (const float*)d_in[14];
    const float* b1         = (const float*)d_in[15];
    const float* w2         = (const float*)d_in[16];
    const float* b2         = (const float*)d_in[17];
    const float* ffn_ln_g   = (const float*)d_in[18];
    const float* ffn_ln_b   = (const float*)d_in[19];
    const int*   item_seq   = (const int*)d_in[20];
    const int*   item_seq_len = (const int*)d_in[21];
    float* out = (float*)d_out;

    char* ws = (char*)d_ws;
    ushort* Winb   = (ushort*)ws;                      ws += NLAY * 65536 * 2;
    ushort* W2effb = (ushort*)ws;                      ws += NLAY * 65536 * 2;
    ushort* w1b    = (ushort*)ws;                      ws += NLAY * 65536 * 2;
    ushort* w2b    = (ushort*)ws;                      ws += NLAY * 65536 * 2;
    float* lam_pow = (float*)ws;                       ws += NLAY * 65536 * 4;
    float* scale_in = (float*)ws;                      ws += NLAY * 512 * 4;
    float* bias_in  = (float*)ws;                      ws += NLAY * 512 * 4;
    size_t table_bytes = (size_t)(ws - (char*)d_ws);

    int Bc = B_TOT;
    while (Bc > 32) {
        size_t need = table_bytes + (size_t)Bc * SEQ * (D * 2 + 2 * DH * 2) + 1024;
        if (need <= ws_size) break;
        Bc >>= 1;
    }
    ushort* xb = (ushort*)ws;                          ws += (size_t)Bc * SEQ * D * 2;
    ushort* hb = (ushort*)ws;

    setup_all_kernel<<<NLAY * 65536 / 256, 256, 0, stream>>>(
        params_log, in_br, in_bi, in_wr, in_wi, out_wr, out_wi, w1, w2,
        Winb, W2effb, w1b, w2b, lam_pow, scale_in, bias_in);

    for (int b0 = 0; b0 < B_TOT; b0 += Bc) {
        int M = Bc * SEQ;
        embed_ln_kernel<<<M / 4, 256, 0, stream>>>(
            token_emb, item_seq + (size_t)b0 * SEQ, emb_ln_g, emb_ln_b, xb);

        for (int li = 0; li < NLAY; ++li) {
            // fused in-proj + exact tree scan -> H layout
            inproj_scan_kernel<<<dim3(16, Bc), 512, 0, stream>>>(
                xb, Winb + (size_t)li * 65536, hb,
                (const float2*)(lam_pow + (size_t)li * 65536),
                item_seq + (size_t)b0 * SEQ,
                scale_in + li * 512, bias_in + li * 512);
            // out-proj + bias + residual + LN -> bf16 x (256-row tiles)
            outproj_kernel<<<dim3(M / 256), 512, 0, stream>>>(
                hb, W2effb + (size_t)li * 65536, xb, M,
                out_br + li * D, xb,
                lru_ln_g + li * D, lru_ln_b + li * D);
            // fused FFN1+gelu+FFN2+residual+LN (in place on xb), async staging
            ffn_fused_kernel<<<dim3(M / 64), 256, 0, stream>>>(
                xb, w1b + (size_t)li * 65536, w2b + (size_t)li * 65536, xb,
                b1 + li * DFF, b2 + li * D,
                ffn_ln_g + li * D, ffn_ln_b + li * D);
        }
        gather_kernel<<<(Bc * D + 255) / 256, 256, 0, stream>>>(
            xb, item_seq_len, out, b0, Bc);
    }
}

// Round 19
// 512.228 us; speedup vs baseline: 1.4379x; 1.1904x over previous
//
#include <hip/hip_runtime.h>
#include <hip/hip_bf16.h>
#include <math.h>

#define B_TOT 512
#define SEQ   200
#define D     128
#define DH    256
#define DFF   512
#define LPAD  256
#define PADL  56
#define NLAY  2
#define SST   18   // scan LDS row stride (floats)

typedef __attribute__((ext_vector_type(8))) short bf16x8;
typedef __attribute__((ext_vector_type(4))) float floatx4;

static __device__ inline float bf2f(ushort u) {
    union { unsigned int i; float f; } v; v.i = ((unsigned int)u) << 16; return v.f;
}
static __device__ inline ushort f2bf(float x) {
    union { float f; unsigned int i; } v; v.f = x;
    unsigned int r = (v.i + 0x7FFFu + ((v.i >> 16) & 1u)) >> 16;   // RNE
    return (ushort)r;
}
// HW packed f32x2 -> bf16x2 (v_cvt_pk_bf16_f32 on gfx950), RNE
static __device__ inline unsigned int pkbf(float a, float b) {
    union { __hip_bfloat162 h; unsigned int u; } v;
    v.h = __float22bfloat162_rn(make_float2(a, b));
    return v.u;
}
// async global->LDS, 16B per lane; LDS dest = wave-uniform base + lane*16
static __device__ inline void gld_lds16(const void* g, void* l) {
    __builtin_amdgcn_global_load_lds(
        (const __attribute__((address_space(1))) unsigned int*)g,
        (__attribute__((address_space(3))) unsigned int*)l, 16, 0, 0);
}

// H layout: [b][g(8)][p(re/im)][s(200)][32 ch] bf16. k in 0..511: k<256 re, else im.
static __device__ inline size_t haddr(int b, int s, int k) {
    int p  = k >> 8;
    int ch = k & 255;
    int g  = ch >> 5;
    int cl = ch & 31;
    return (((((size_t)b * 8 + g) * 2 + p) * SEQ + s) * 32 + cl);
}

// ---------------------------------------------------------------------------
// Unified setup (R18): pre-swizzled weight images + lambda powers/scales.
// ---------------------------------------------------------------------------
__global__ void setup_all_kernel(const float* __restrict__ params_log,
                                 const float* __restrict__ in_br,
                                 const float* __restrict__ in_bi,
                                 const float* __restrict__ in_wr,
                                 const float* __restrict__ in_wi,
                                 const float* __restrict__ out_wr,
                                 const float* __restrict__ out_wi,
                                 const float* __restrict__ w1,
                                 const float* __restrict__ w2,
                                 ushort* __restrict__ Winb,
                                 ushort* __restrict__ W2effb,
                                 ushort* __restrict__ w1b,
                                 ushort* __restrict__ w2b,
                                 float* __restrict__ lam_pow,
                                 float* __restrict__ scale_in,
                                 float* __restrict__ bias_in)
{
    int idx = blockIdx.x * blockDim.x + threadIdx.x;   // NLAY*65536
    int li = idx >> 16;
    int e  = idx & 65535;

    {   // inproj Ws image
        int gp = e >> 12, rem = e & 4095;
        int q = rem >> 3, e8 = rem & 7;
        int r = q >> 4, cs = q & 15;
        int c16 = cs ^ (r & 7);
        int n = (r < 16) ? (gp * 16 + r) : (256 + gp * 16 + (r - 16));
        int d = c16 * 8 + e8;
        float wv = (n < DH) ? in_wr[((size_t)li * DH + n) * D + d]
                            : in_wi[((size_t)li * DH + (n - DH)) * D + d];
        Winb[idx] = f2bf(wv);
    }
    {   // out-proj W2eff image
        int k0c = e >> 13, rem = e & 8191;
        int q = rem >> 3, e8 = rem & 7;
        int r = q >> 3, cs = q & 7;
        int c16 = cs ^ (r & 7);
        int k = k0c * 64 + c16 * 8 + e8;
        float w2v = (k < DH) ? out_wr[((size_t)li * D + r) * DH + k]
                             : -out_wi[((size_t)li * D + r) * DH + (k - DH)];
        W2effb[idx] = f2bf(w2v);
    }
    {   // ffn W1 image: logical [512][128]
        int row = e >> 7, col = e & 127;
        int ffc = row >> 7, rl = row & 127;
        int c16 = col >> 3, e8 = col & 7;
        int cs = c16 ^ (rl & 7);
        w1b[li * 65536 + ffc * 16384 + rl * 128 + cs * 8 + e8] = f2bf(w1[idx]);
    }
    {   // ffn W2 image: logical [128][512]
        int dd2 = e >> 9, kk = e & 511;
        int ffc = kk >> 7, klc = kk & 127;
        int c16 = klc >> 3, e8 = klc & 7;
        int cs = c16 ^ (dd2 & 7);
        w2b[li * 65536 + ffc * 16384 + dd2 * 128 + cs * 8 + e8] = f2bf(w2[idx]);
    }

    if (blockIdx.x < NLAY) {
        int pli = blockIdx.x;
        int c = threadIdx.x;
        const float* pl = params_log + (size_t)pli * 3 * DH;
        float nu = expf(pl[c]);
        float th = expf(pl[DH + c]);
        float ga = expf(pl[2 * DH + c]);
        float mag = expf(-nu);
        float lr = mag * cosf(th);
        float lim = mag * sinf(th);
        float2* lp = (float2*)(lam_pow + (size_t)pli * 65536) + (size_t)c * 128;
        float pr = lr, pi = lim;
        lp[0] = make_float2(pr, pi);
        for (int k = 1; k < 128; ++k) {
            float nr = pr * lr - pi * lim;
            float ni = pr * lim + pi * lr;
            pr = nr; pi = ni;
            lp[k] = make_float2(pr, pi);
        }
        scale_in[pli * 2 * DH + c]      = ga;
        scale_in[pli * 2 * DH + DH + c] = ga;
        bias_in[pli * 2 * DH + c]       = in_br[pli * DH + c] * ga;
        bias_in[pli * 2 * DH + DH + c]  = in_bi[pli * DH + c] * ga;
    }
}

// ---------------------------------------------------------------------------
// Embedding gather + LayerNorm -> bf16 x
// ---------------------------------------------------------------------------
__global__ __launch_bounds__(256) void embed_ln_kernel(
    const float* __restrict__ emb, const int* __restrict__ seq,
    const float* __restrict__ g, const float* __restrict__ bt,
    ushort* __restrict__ x)
{
    int row  = blockIdx.x * 4 + (threadIdx.x >> 6);
    int lane = threadIdx.x & 63;
    int item = seq[row];
    float2 v = *(const float2*)(emb + (size_t)item * D + lane * 2);
    float s = v.x + v.y;
#pragma unroll
    for (int o = 32; o > 0; o >>= 1) s += __shfl_xor(s, o);
    float mu = s * (1.0f / D);
    float d0 = v.x - mu, d1 = v.y - mu;
    float vs = d0 * d0 + d1 * d1;
#pragma unroll
    for (int o = 32; o > 0; o >>= 1) vs += __shfl_xor(vs, o);
    float rstd = rsqrtf(vs * (1.0f / D) + 1e-5f);
    float2 gg = *(const float2*)(g + lane * 2);
    float2 bb = *(const float2*)(bt + lane * 2);
    unsigned int o2 = pkbf(d0 * rstd * gg.x + bb.x, d1 * rstd * gg.y + bb.y);
    *(unsigned int*)(x + (size_t)row * D + lane * 2) = o2;
}

// ---------------------------------------------------------------------------
// FUSED in-proj + exact tree scan (R14/R18 structure).
// LAST=false: full H-layout store. LAST=true: store only the h slice at
// position s_b = lenp[b]-1 into compact Hc[b][512] (R19 — last layer only
// needs the gathered row downstream).
// ---------------------------------------------------------------------------
template <bool LAST>
__global__ __launch_bounds__(512) void inproj_scan_kernel(
    const ushort* __restrict__ X, const ushort* __restrict__ Win,
    ushort* __restrict__ H, const float2* __restrict__ lamT,
    const int* __restrict__ seq, const int* __restrict__ lenp,
    const float* __restrict__ scale_in, const float* __restrict__ bias_in)
{
    __shared__ __align__(16) char smem[36864];   // Ws 8192 + xs 28672 (phase A)
    __shared__ float mkf[LPAD];
    char*  Wsm = smem;                           // [32][128] bf16, swizzled
    char*  xs  = smem + 8192;                    // [112][128] bf16, swizzled
    float* stR = (float*)smem;                   // [256][SST] (phase B alias)
    float* stI = stR + LPAD * SST;               // ends at 36864 B
    float2* lamS = (float2*)smem;                // [16][130] (tree phase alias)
    float2* bc   = (float2*)(smem + 16 * 130 * 8);

    int gp = blockIdx.x, b = blockIdx.y;
    int tid = threadIdx.x;
    int l = tid & 63, w = tid >> 6;              // 8 waves
    int ct = w & 1;                              // 0=re tile, 1=im tile
    int rq = w >> 1;                             // row quarter 0..3
    int lr = l & 15, lq = l >> 4;
    int wbase = tid & ~63;

    int c  = tid & 15;                           // scan channel
    int tl = tid >> 4;                           // 0..31
    int t0 = tl * 8;

    const float2* myl = lamT + (size_t)(gp * 16 + c) * 128;
    float2 l14[4];
#pragma unroll
    for (int k = 0; k < 4; ++k) l14[k] = myl[k];

    if (tid < LPAD) {
        int t = tid;
        float m = 0.f;
        if (t >= PADL) m = (seq[(size_t)b * SEQ + (t - PADL)] > 0) ? 1.f : 0.f;
        mkf[t] = m;
    }

    // ---- Phase A: async Ws stage (pre-swizzled image) + x stage A (rows 0..111)
    const ushort* xrow = X + (size_t)b * SEQ * 128;
    gld_lds16(Win + (size_t)gp * 4096 + (size_t)tid * 8,
              Wsm + (size_t)wbase * 16);
#pragma unroll
    for (int it = 0; it < 4; ++it) {
        int idx = it * 512 + tid;
        if (idx < 112 * 16) {
            int r = idx >> 4, c16 = idx & 15;
            uint4 v = *(const uint4*)(xrow + (size_t)r * 128 + c16 * 8);
            *(uint4*)(xs + r * 256 + ((c16 ^ (r & 7)) * 16)) = v;
        }
    }
    __syncthreads();

    bf16x8 wf[4];
#pragma unroll
    for (int kk = 0; kk < 4; ++kk) {
        int ca = kk * 4 + lq;
        int wr = ct * 16 + lr;
        wf[kk] = *(const bf16x8*)(Wsm + wr * 256 + ((ca ^ (wr & 7)) * 16));
    }
    int tstart = rq ? (3 * rq + 1) : 0;          // 0 / 4 / 7 / 10
    int tcnt   = rq ? 3 : 4;
    floatx4 acc[4];
#pragma unroll
    for (int tt = 0; tt < 4; ++tt) acc[tt] = (floatx4)0.f;

    if (rq < 2) {
#pragma unroll
        for (int tt = 0; tt < 4; ++tt) {
            if (tt < tcnt) {
                int t  = tstart + tt;
                int ar = t * 16 + lr;
#pragma unroll
                for (int kk = 0; kk < 4; ++kk) {
                    int ca = kk * 4 + lq;
                    bf16x8 af = *(const bf16x8*)(xs + ar * 256 + ((ca ^ (ar & 7)) * 16));
                    acc[tt] = __builtin_amdgcn_mfma_f32_16x16x32_bf16(wf[kk], af, acc[tt], 0, 0, 0);
                }
            }
        }
    }
    __syncthreads();

#pragma unroll
    for (int it = 0; it < 3; ++it) {
        int idx = it * 512 + tid;                // exactly 96*16 = 1536
        int r = idx >> 4, c16 = idx & 15;
        int gr = 112 + r;
        uint4 v = make_uint4(0u, 0u, 0u, 0u);
        if (gr < 200) v = *(const uint4*)(xrow + (size_t)gr * 128 + c16 * 8);
        *(uint4*)(xs + r * 256 + ((c16 ^ (r & 7)) * 16)) = v;
    }
    __syncthreads();

    if (rq >= 2) {
#pragma unroll
        for (int tt = 0; tt < 4; ++tt) {
            if (tt < tcnt) {
                int t  = tstart + tt;
                int ar = (t - 7) * 16 + lr;
#pragma unroll
                for (int kk = 0; kk < 4; ++kk) {
                    int ca = kk * 4 + lq;
                    bf16x8 af = *(const bf16x8*)(xs + ar * 256 + ((ca ^ (ar & 7)) * 16));
                    acc[tt] = __builtin_amdgcn_mfma_f32_16x16x32_bf16(wf[kk], af, acc[tt], 0, 0, 0);
                }
            }
        }
    }
    __syncthreads();

    // ---- Phase B: zero pad rows + epilogue -> stR/stI
    for (int idx = tid; idx < PADL * SST; idx += 512) { stR[idx] = 0.f; stI[idx] = 0.f; }
    {
        float4 g4 = *(const float4*)(scale_in + ct * 256 + gp * 16 + lq * 4);
        float4 b4 = *(const float4*)(bias_in  + ct * 256 + gp * 16 + lq * 4);
        float* dst = ct ? stI : stR;
#pragma unroll
        for (int tt = 0; tt < 4; ++tt) {
            if (tt < tcnt) {
                int t = tstart + tt;
                int s = t * 16 + lr;
                if (s < 200) {
                    int pos = s + PADL;
                    dst[pos * SST + lq * 4 + 0] = acc[tt][0] * g4.x + b4.x;
                    dst[pos * SST + lq * 4 + 1] = acc[tt][1] * g4.y + b4.y;
                    dst[pos * SST + lq * 4 + 2] = acc[tt][2] * g4.z + b4.z;
                    dst[pos * SST + lq * 4 + 3] = acc[tt][3] * g4.w + b4.w;
                }
            }
        }
    }
    __syncthreads();

    float xr[8], xi[8], mf[8];
#pragma unroll
    for (int k = 0; k < 8; ++k) {
        xr[k] = stR[(t0 + k) * SST + c];
        xi[k] = stI[(t0 + k) * SST + c];
        mf[k] = mkf[t0 + k];
    }
    __syncthreads();

    {
        const char* src = (const char*)(lamT + (size_t)gp * 16 * 128);
#pragma unroll
        for (int it = 0; it < 2; ++it) {
            int idx = it * 512 + tid;
            int row = idx >> 6, c4 = idx & 63;
            *(uint4*)((char*)lamS + row * 1040 + c4 * 16) =
                *(const uint4*)(src + row * 1024 + c4 * 16);
        }
    }

    {
#pragma unroll
        for (int k = 0; k < 8; k += 2) {
            float sr = xr[k] * mf[k], si = xi[k] * mf[k];
            xr[k+1] += l14[0].x * sr - l14[0].y * si;
            xi[k+1] += l14[0].x * si + l14[0].y * sr;
        }
#pragma unroll
        for (int k = 1; k < 8; k += 4) {
            float sr = xr[k] * mf[k], si = xi[k] * mf[k];
            xr[k+1] += l14[0].x * sr - l14[0].y * si;
            xi[k+1] += l14[0].x * si + l14[0].y * sr;
            xr[k+2] += l14[1].x * sr - l14[1].y * si;
            xi[k+2] += l14[1].x * si + l14[1].y * sr;
        }
        {
            float sr = xr[3] * mf[3], si = xi[3] * mf[3];
#pragma unroll
            for (int j = 0; j < 4; ++j) {
                xr[4+j] += l14[j].x * sr - l14[j].y * si;
                xi[4+j] += l14[j].x * si + l14[j].y * sr;
            }
        }
    }

#pragma unroll
    for (int i = 4; i <= 8; ++i) {
        int half = 1 << (i - 1);
        int buf  = (i & 1) * 544;
        bc[buf + tl * 17 + c] = make_float2(xr[7], xi[7]);
        __syncthreads();
        int off = t0 & ((half << 1) - 1);
        if (off >= half) {
            int src = t0 - off + half - 1;
            float m = mkf[src];
            float2 sv = bc[buf + (src >> 3) * 17 + c];
            float sr = sv.x * m, si = sv.y * m;
            int e = off - half;
            const float2* lp = lamS + c * 130 + e;
#pragma unroll
            for (int k = 0; k < 8; ++k) {
                float2 lv = lp[k];
                xr[k] += lv.x * sr - lv.y * si;
                xi[k] += lv.x * si + lv.y * sr;
            }
        }
    }
    __syncthreads();

#pragma unroll
    for (int k = 0; k < 8; ++k) {
        stR[(t0 + k) * SST + c] = xr[k];
        stI[(t0 + k) * SST + c] = xi[k];
    }
    __syncthreads();

    if (LAST) {
        // store only h at position s_b into compact Hc[b][512]
        if (tid < 32) {
            int t = lenp[b] - 1 + PADL;
            int p = tid >> 4, cc = tid & 15;
            float v = (p ? stI : stR)[t * SST + cc];
            H[(size_t)b * 512 + p * 256 + gp * 16 + cc] = f2bf(v);
        }
    } else {
        int g  = gp >> 1;
        int hc = (gp & 1) * 16;
        ushort* baseg = H + (size_t)(b * 8 + g) * 2 * SEQ * 32 + hc;
#pragma unroll
        for (int it = 0; it < 4; ++it) {
            int idx4 = it * 512 + tid;
            if (idx4 < 2 * SEQ * 4) {
                int q  = idx4 & 3;
                int ps = idx4 >> 2;
                int p  = ps >= SEQ;
                int s  = ps - p * SEQ;
                int t  = s + PADL;
                const float* sp = (p ? stI : stR) + t * SST + q * 4;
                float2 a = *(const float2*)(sp);
                float2 d = *(const float2*)(sp + 2);
                uint2 raw;
                raw.x = pkbf(a.x, a.y);
                raw.y = pkbf(d.x, d.y);
                *(uint2*)(baseg + (size_t)ps * 32 + q * 4) = raw;
            }
        }
    }
}

// ---------------------------------------------------------------------------
// Out-proj GEMM (full path), 512 threads, 256-row M-tile (R18 known-good).
// ---------------------------------------------------------------------------
__global__ __launch_bounds__(512) void outproj_kernel(
    const ushort* __restrict__ A, const ushort* __restrict__ Wimg,
    ushort* __restrict__ Cout, int M,
    const float* __restrict__ e0,
    const ushort* __restrict__ res,
    const float* __restrict__ lng, const float* __restrict__ lnb)
{
    __shared__ __align__(16) char As[32768];
    __shared__ __align__(16) char Bs[16384];
    __shared__ float2 lnS[2][256];
    int tid = threadIdx.x;
    int l = tid & 63, w = tid >> 6;
    int chh = w >> 2;
    int rh  = w & 3;
    int lr = l & 15, lq = l >> 4;
    int m0 = blockIdx.x * 256;
    int wbase = tid & ~63;

    int cst = tid & 7;
    int rr  = tid >> 3;
    int sb[4], ss[4];
#pragma unroll
    for (int it = 0; it < 4; ++it) {
        unsigned int gr = m0 + it * 64 + rr;
        sb[it] = gr / SEQ; ss[it] = gr - sb[it] * SEQ;
    }

    floatx4 acc[4][4];
#pragma unroll
    for (int i = 0; i < 4; ++i)
#pragma unroll
        for (int j = 0; j < 4; ++j) acc[i][j] = (floatx4)0.f;

    for (int k0c = 0; k0c < 8; ++k0c) {
        int k0 = k0c * 64;
        {
            const ushort* img = Wimg + (size_t)k0c * 8192;
#pragma unroll
            for (int it = 0; it < 2; ++it)
                gld_lds16(img + (size_t)(it * 512 + tid) * 8,
                          Bs + (size_t)(it * 512 + wbase) * 16);
        }
#pragma unroll
        for (int it = 0; it < 4; ++it) {
            int r = it * 64 + rr;
            uint4 va = *(const uint4*)(A + haddr(sb[it], ss[it], k0 + cst * 8));
            *(uint4*)(As + r * 128 + ((cst ^ (r & 7)) * 16)) = va;
        }
        __syncthreads();
#pragma unroll
        for (int kk = 0; kk < 2; ++kk) {
            bf16x8 wf[4], af[4];
            int ca = kk * 4 + lq;
#pragma unroll
            for (int i = 0; i < 4; ++i) {
                int rb = chh * 64 + i * 16 + lr;
                wf[i] = *(const bf16x8*)(Bs + rb * 128 + ((ca ^ (rb & 7)) * 16));
                int ra = rh * 64 + i * 16 + lr;
                af[i] = *(const bf16x8*)(As + ra * 128 + ((ca ^ (ra & 7)) * 16));
            }
#pragma unroll
            for (int i = 0; i < 4; ++i)
#pragma unroll
                for (int j = 0; j < 4; ++j)
                    acc[i][j] = __builtin_amdgcn_mfma_f32_16x16x32_bf16(
                        wf[i], af[j], acc[i][j], 0, 0, 0);
        }
        __syncthreads();
    }

    int chb[4], arow[4];
#pragma unroll
    for (int i = 0; i < 4; ++i) chb[i] = chh * 64 + i * 16 + lq * 4;
#pragma unroll
    for (int j = 0; j < 4; ++j) arow[j] = m0 + rh * 64 + j * 16 + lr;

    {
        float4 bias[4], gv[4], bv[4];
#pragma unroll
        for (int i = 0; i < 4; ++i) {
            bias[i] = *(const float4*)(e0 + chb[i]);
            gv[i]   = *(const float4*)(lng + chb[i]);
            bv[i]   = *(const float4*)(lnb + chb[i]);
        }
#pragma unroll
        for (int j = 0; j < 4; ++j) {
#pragma unroll
            for (int i = 0; i < 4; ++i) {
                ushort4 r4 = *(const ushort4*)(res + (size_t)arow[j] * 128 + chb[i]);
                acc[i][j][0] += ((const float*)&bias[i])[0] + bf2f(r4.x);
                acc[i][j][1] += ((const float*)&bias[i])[1] + bf2f(r4.y);
                acc[i][j][2] += ((const float*)&bias[i])[2] + bf2f(r4.z);
                acc[i][j][3] += ((const float*)&bias[i])[3] + bf2f(r4.w);
            }
        }
#pragma unroll
        for (int j = 0; j < 4; ++j) {
            float s = 0.f, q = 0.f;
#pragma unroll
            for (int i = 0; i < 4; ++i)
#pragma unroll
                for (int reg = 0; reg < 4; ++reg) {
                    float v = acc[i][j][reg];
                    s += v; q += v * v;
                }
            s += __shfl_xor(s, 16); q += __shfl_xor(q, 16);
            s += __shfl_xor(s, 32); q += __shfl_xor(q, 32);
            if (lq == 0) lnS[chh][rh * 64 + j * 16 + lr] = make_float2(s, q);
        }
        __syncthreads();
#pragma unroll
        for (int j = 0; j < 4; ++j) {
            int rl = rh * 64 + j * 16 + lr;
            float2 s0 = lnS[0][rl], s1 = lnS[1][rl];
            float mu  = (s0.x + s1.x) * (1.0f / 128.0f);
            float var = (s0.y + s1.y) * (1.0f / 128.0f) - mu * mu;
            float rstd = rsqrtf(var + 1e-5f);
#pragma unroll
            for (int i = 0; i < 4; ++i) {
                uint2 u;
                u.x = pkbf((acc[i][j][0] - mu) * rstd * ((const float*)&gv[i])[0] + ((const float*)&bv[i])[0],
                           (acc[i][j][1] - mu) * rstd * ((const float*)&gv[i])[1] + ((const float*)&bv[i])[1]);
                u.y = pkbf((acc[i][j][2] - mu) * rstd * ((const float*)&gv[i])[2] + ((const float*)&bv[i])[2],
                           (acc[i][j][3] - mu) * rstd * ((const float*)&gv[i])[3] + ((const float*)&bv[i])[3]);
                *(uint2*)(Cout + (size_t)arow[j] * 128 + chb[i]) = u;
            }
        }
    }
}

// ---------------------------------------------------------------------------
// Out-proj LAST (R19): compact M=Bc rows from Hc[b][512]; residual gathered
// from xb at (b, len[b]-1); LN; output compact xc[b][128].
// ---------------------------------------------------------------------------
__global__ __launch_bounds__(512) void outproj_last_kernel(
    const ushort* __restrict__ Hc, const ushort* __restrict__ Wimg,
    ushort* __restrict__ xc, int Bc,
    const float* __restrict__ e0,
    const ushort* __restrict__ Xres, const int* __restrict__ lenp,
    const float* __restrict__ lng, const float* __restrict__ lnb)
{
    __shared__ __align__(16) char As[32768];
    __shared__ __align__(16) char Bs[16384];
    __shared__ float2 lnS[2][256];
    int tid = threadIdx.x;
    int l = tid & 63, w = tid >> 6;
    int chh = w >> 2;
    int rh  = w & 3;
    int lr = l & 15, lq = l >> 4;
    int m0 = blockIdx.x * 256;
    int wbase = tid & ~63;

    int cst = tid & 7;
    int rr  = tid >> 3;

    floatx4 acc[4][4];
#pragma unroll
    for (int i = 0; i < 4; ++i)
#pragma unroll
        for (int j = 0; j < 4; ++j) acc[i][j] = (floatx4)0.f;

    for (int k0c = 0; k0c < 8; ++k0c) {
        int k0 = k0c * 64;
        {
            const ushort* img = Wimg + (size_t)k0c * 8192;
#pragma unroll
            for (int it = 0; it < 2; ++it)
                gld_lds16(img + (size_t)(it * 512 + tid) * 8,
                          Bs + (size_t)(it * 512 + wbase) * 16);
        }
#pragma unroll
        for (int it = 0; it < 4; ++it) {
            int r = it * 64 + rr;
            int gr = m0 + r; if (gr >= Bc) gr = Bc - 1;
            uint4 va = *(const uint4*)(Hc + (size_t)gr * 512 + k0 + cst * 8);
            *(uint4*)(As + r * 128 + ((cst ^ (r & 7)) * 16)) = va;
        }
        __syncthreads();
#pragma unroll
        for (int kk = 0; kk < 2; ++kk) {
            bf16x8 wf[4], af[4];
            int ca = kk * 4 + lq;
#pragma unroll
            for (int i = 0; i < 4; ++i) {
                int rb = chh * 64 + i * 16 + lr;
                wf[i] = *(const bf16x8*)(Bs + rb * 128 + ((ca ^ (rb & 7)) * 16));
                int ra = rh * 64 + i * 16 + lr;
                af[i] = *(const bf16x8*)(As + ra * 128 + ((ca ^ (ra & 7)) * 16));
            }
#pragma unroll
            for (int i = 0; i < 4; ++i)
#pragma unroll
                for (int j = 0; j < 4; ++j)
                    acc[i][j] = __builtin_amdgcn_mfma_f32_16x16x32_bf16(
                        wf[i], af[j], acc[i][j], 0, 0, 0);
        }
        __syncthreads();
    }

    int chb[4], arow[4];
#pragma unroll
    for (int i = 0; i < 4; ++i) chb[i] = chh * 64 + i * 16 + lq * 4;
#pragma unroll
    for (int j = 0; j < 4; ++j) arow[j] = m0 + rh * 64 + j * 16 + lr;

    {
        float4 bias[4], gv[4], bv[4];
#pragma unroll
        for (int i = 0; i < 4; ++i) {
            bias[i] = *(const float4*)(e0 + chb[i]);
            gv[i]   = *(const float4*)(lng + chb[i]);
            bv[i]   = *(const float4*)(lnb + chb[i]);
        }
#pragma unroll
        for (int j = 0; j < 4; ++j) {
            int br = arow[j] < Bc ? arow[j] : Bc - 1;
            int sb_ = lenp[br] - 1;
            const ushort* rbase = Xres + ((size_t)br * SEQ + sb_) * 128;
#pragma unroll
            for (int i = 0; i < 4; ++i) {
                ushort4 r4 = *(const ushort4*)(rbase + chb[i]);
                acc[i][j][0] += ((const float*)&bias[i])[0] + bf2f(r4.x);
                acc[i][j][1] += ((const float*)&bias[i])[1] + bf2f(r4.y);
                acc[i][j][2] += ((const float*)&bias[i])[2] + bf2f(r4.z);
                acc[i][j][3] += ((const float*)&bias[i])[3] + bf2f(r4.w);
            }
        }
#pragma unroll
        for (int j = 0; j < 4; ++j) {
            float s = 0.f, q = 0.f;
#pragma unroll
            for (int i = 0; i < 4; ++i)
#pragma unroll
                for (int reg = 0; reg < 4; ++reg) {
                    float v = acc[i][j][reg];
                    s += v; q += v * v;
                }
            s += __shfl_xor(s, 16); q += __shfl_xor(q, 16);
            s += __shfl_xor(s, 32); q += __shfl_xor(q, 32);
            if (lq == 0) lnS[chh][rh * 64 + j * 16 + lr] = make_float2(s, q);
        }
        __syncthreads();
#pragma unroll
        for (int j = 0; j < 4; ++j) {
            int rl = rh * 64 + j * 16 + lr;
            float2 s0 = lnS[0][rl], s1 = lnS[1][rl];
            float mu  = (s0.x + s1.x) * (1.0f / 128.0f);
            float var = (s0.y + s1.y) * (1.0f / 128.0f) - mu * mu;
            float rstd = rsqrtf(var + 1e-5f);
            if (arow[j] < Bc) {
#pragma unroll
                for (int i = 0; i < 4; ++i) {
                    uint2 u;
                    u.x = pkbf((acc[i][j][0] - mu) * rstd * ((const float*)&gv[i])[0] + ((const float*)&bv[i])[0],
                               (acc[i][j][1] - mu) * rstd * ((const float*)&gv[i])[1] + ((const float*)&bv[i])[1]);
                    u.y = pkbf((acc[i][j][2] - mu) * rstd * ((const float*)&gv[i])[2] + ((const float*)&bv[i])[2],
                               (acc[i][j][3] - mu) * rstd * ((const float*)&gv[i])[3] + ((const float*)&bv[i])[3]);
                    *(uint2*)(xc + (size_t)arow[j] * 128 + chb[i]) = u;
                }
            }
        }
    }
}

// ---------------------------------------------------------------------------
// Fused FFN v6 (R17/R18 structure) + row guards (Mtot): full path passes
// Mtot = M (multiple of 64, guards never fire); last path passes Mtot = Bc.
// ---------------------------------------------------------------------------
__global__ __launch_bounds__(256) void ffn_fused_kernel(
    const ushort* __restrict__ X, const ushort* __restrict__ W1,
    const ushort* __restrict__ W2, ushort* __restrict__ Out,
    const float* __restrict__ b1, const float* __restrict__ b2,
    const float* __restrict__ lng, const float* __restrict__ lnb,
    int Mtot)
{
    __shared__ __align__(16) char Bs[32768];   // pre-swizzled 32KB weight chunk
    __shared__ ushort Ps[64 * 136];     // P tile, row stride 136
    __shared__ float2 lnS[2][64];
    int tid = threadIdx.x;
    int l = tid & 63, w = tid >> 6;
    int chh = w >> 1, rh = w & 1;
    int lr = l & 15, lq = l >> 4;
    int m0 = blockIdx.x * 64;
    int wbase = tid & ~63;              // wave-uniform chunk base

    bf16x8 af_x[8];
#pragma unroll
    for (int j = 0; j < 2; ++j)
#pragma unroll
        for (int kk2 = 0; kk2 < 4; ++kk2) {
            int row = m0 + rh * 32 + j * 16 + lr;
            if (row >= Mtot) row = Mtot - 1;
            int k   = kk2 * 32 + lq * 8;
            af_x[(j << 2) | kk2] = *(const bf16x8*)(X + (size_t)row * 128 + k);
        }

    floatx4 acc2[4][2];
#pragma unroll
    for (int i = 0; i < 4; ++i)
#pragma unroll
        for (int j = 0; j < 2; ++j) acc2[i][j] = (floatx4)0.f;

    for (int ffc = 0; ffc < 4; ++ffc) {
        if (ffc) __syncthreads();
        {
            const ushort* img = W1 + (size_t)ffc * 16384;
#pragma unroll
            for (int it = 0; it < 8; ++it)
                gld_lds16(img + (size_t)(it * 256 + tid) * 8,
                          Bs + (size_t)(it * 256 + wbase) * 16);
        }
        __syncthreads();

        floatx4 acc1[4][2];
#pragma unroll
        for (int i = 0; i < 4; ++i)
#pragma unroll
            for (int j = 0; j < 2; ++j) acc1[i][j] = (floatx4)0.f;
#pragma unroll
        for (int kk2 = 0; kk2 < 4; ++kk2) {
            int ca = kk2 * 4 + lq;
            bf16x8 wf[4];
#pragma unroll
            for (int i = 0; i < 4; ++i) {
                int rb = chh * 64 + i * 16 + lr;
                wf[i] = *(const bf16x8*)(Bs + rb * 256 + ((ca ^ (rb & 7)) * 16));
            }
#pragma unroll
            for (int i = 0; i < 4; ++i)
#pragma unroll
                for (int j = 0; j < 2; ++j)
                    acc1[i][j] = __builtin_amdgcn_mfma_f32_16x16x32_bf16(
                        wf[i], af_x[(j << 2) | kk2], acc1[i][j], 0, 0, 0);
        }

#pragma unroll
        for (int j = 0; j < 2; ++j) {
            int rowl = rh * 32 + j * 16 + lr;
#pragma unroll
            for (int i = 0; i < 4; ++i) {
                int ch0 = chh * 64 + i * 16 + lq * 4;
                float4 bv = *(const float4*)(b1 + ffc * 128 + ch0);
                float g0, g1, g2, g3, v;
                v = acc1[i][j][0] + bv.x; g0 = 0.5f * v * (1.0f + erff(v * 0.70710678118654752f));
                v = acc1[i][j][1] + bv.y; g1 = 0.5f * v * (1.0f + erff(v * 0.70710678118654752f));
                v = acc1[i][j][2] + bv.z; g2 = 0.5f * v * (1.0f + erff(v * 0.70710678118654752f));
                v = acc1[i][j][3] + bv.w; g3 = 0.5f * v * (1.0f + erff(v * 0.70710678118654752f));
                uint2 u; u.x = pkbf(g0, g1); u.y = pkbf(g2, g3);
                *(uint2*)(Ps + rowl * 136 + ch0) = u;
            }
        }
        __syncthreads();

        {
            const ushort* img = W2 + (size_t)ffc * 16384;
#pragma unroll
            for (int it = 0; it < 8; ++it)
                gld_lds16(img + (size_t)(it * 256 + tid) * 8,
                          Bs + (size_t)(it * 256 + wbase) * 16);
        }
        __syncthreads();

#pragma unroll
        for (int kk2 = 0; kk2 < 4; ++kk2) {
            int ca = kk2 * 4 + lq;
            bf16x8 wf[4], af[2];
#pragma unroll
            for (int i = 0; i < 4; ++i) {
                int rb = chh * 64 + i * 16 + lr;
                wf[i] = *(const bf16x8*)(Bs + rb * 256 + ((ca ^ (rb & 7)) * 16));
            }
#pragma unroll
            for (int j = 0; j < 2; ++j) {
                int rowl = rh * 32 + j * 16 + lr;
                af[j] = *(const bf16x8*)(Ps + rowl * 136 + kk2 * 32 + lq * 8);
            }
#pragma unroll
            for (int i = 0; i < 4; ++i)
#pragma unroll
                for (int j = 0; j < 2; ++j)
                    acc2[i][j] = __builtin_amdgcn_mfma_f32_16x16x32_bf16(
                        wf[i], af[j], acc2[i][j], 0, 0, 0);
        }
    }

    int chb[4], arow[2];
#pragma unroll
    for (int i = 0; i < 4; ++i) chb[i] = chh * 64 + i * 16 + lq * 4;
#pragma unroll
    for (int j = 0; j < 2; ++j) arow[j] = m0 + rh * 32 + j * 16 + lr;

    float4 bias[4], gv[4], bv[4];
#pragma unroll
    for (int i = 0; i < 4; ++i) {
        bias[i] = *(const float4*)(b2 + chb[i]);
        gv[i]   = *(const float4*)(lng + chb[i]);
        bv[i]   = *(const float4*)(lnb + chb[i]);
    }
#pragma unroll
    for (int j = 0; j < 2; ++j) {
        int rowc = arow[j] < Mtot ? arow[j] : Mtot - 1;
#pragma unroll
        for (int i = 0; i < 4; ++i) {
            ushort4 r4 = *(const ushort4*)(X + (size_t)rowc * 128 + chb[i]);
            acc2[i][j][0] += ((const float*)&bias[i])[0] + bf2f(r4.x);
            acc2[i][j][1] += ((const float*)&bias[i])[1] + bf2f(r4.y);
            acc2[i][j][2] += ((const float*)&bias[i])[2] + bf2f(r4.z);
            acc2[i][j][3] += ((const float*)&bias[i])[3] + bf2f(r4.w);
        }
    }
#pragma unroll
    for (int j = 0; j < 2; ++j) {
        float s = 0.f, q = 0.f;
#pragma unroll
        for (int i = 0; i < 4; ++i)
#pragma unroll
            for (int reg = 0; reg < 4; ++reg) {
                float v = acc2[i][j][reg];
                s += v; q += v * v;
            }
        s += __shfl_xor(s, 16); q += __shfl_xor(q, 16);
        s += __shfl_xor(s, 32); q += __shfl_xor(q, 32);
        if (lq == 0) lnS[chh][rh * 32 + j * 16 + lr] = make_float2(s, q);
    }
    __syncthreads();
#pragma unroll
    for (int j = 0; j < 2; ++j) {
        int rl = rh * 32 + j * 16 + lr;
        float2 s0 = lnS[0][rl], s1 = lnS[1][rl];
        float mu  = (s0.x + s1.x) * (1.0f / 128.0f);
        float var = (s0.y + s1.y) * (1.0f / 128.0f) - mu * mu;
        float rstd = rsqrtf(var + 1e-5f);
        if (arow[j] < Mtot) {
#pragma unroll
            for (int i = 0; i < 4; ++i) {
                uint2 u;
                u.x = pkbf((acc2[i][j][0] - mu) * rstd * ((const float*)&gv[i])[0] + ((const float*)&bv[i])[0],
                           (acc2[i][j][1] - mu) * rstd * ((const float*)&gv[i])[1] + ((const float*)&bv[i])[1]);
                u.y = pkbf((acc2[i][j][2] - mu) * rstd * ((const float*)&gv[i])[2] + ((const float*)&bv[i])[2],
                           (acc2[i][j][3] - mu) * rstd * ((const float*)&gv[i])[3] + ((const float*)&bv[i])[3]);
                *(uint2*)(Out + (size_t)arow[j] * 128 + chb[i]) = u;
            }
        }
    }
}

// ---------------------------------------------------------------------------
__global__ void gather_final_kernel(const ushort* __restrict__ xc,
                                    float* __restrict__ out, int b0, int Bc)
{
    int i = blockIdx.x * 256 + threadIdx.x;
    if (i >= Bc * D) return;
    out[(size_t)b0 * D + i] = bf2f(xc[i]);
}

// ---------------------------------------------------------------------------
extern "C" void kernel_launch(void* const* d_in, const int* in_sizes, int n_in,
                              void* d_out, int out_size, void* d_ws, size_t ws_size,
                              hipStream_t stream)
{
    const float* token_emb  = (const float*)d_in[0];
    const float* emb_ln_g   = (const float*)d_in[1];
    const float* emb_ln_b   = (const float*)d_in[2];
    const float* params_log = (const float*)d_in[3];
    const float* in_wr      = (const float*)d_in[4];
    const float* in_wi      = (const float*)d_in[5];
    const float* in_br      = (const float*)d_in[6];
    const float* in_bi      = (const float*)d_in[7];
    const float* out_wr     = (const float*)d_in[8];
    const float* out_wi     = (const float*)d_in[9];
    const float* out_br     = (const float*)d_in[10];
    const float* lru_ln_g   = (const float*)d_in[12];
    const float* lru_ln_b   = (const float*)d_in[13];
    const float* w1         = (const float*)d_in[14];
    const float* b1         = (const float*)d_in[15];
    const float* w2         = (const float*)d_in[16];
    const float* b2         = (const float*)d_in[17];
    const float* ffn_ln_g   = (const float*)d_in[18];
    const float* ffn_ln_b   = (const float*)d_in[19];
    const int*   item_seq   = (const int*)d_in[20];
    const int*   item_seq_len = (const int*)d_in[21];
    float* out = (float*)d_out;

    char* ws = (char*)d_ws;
    ushort* Winb   = (ushort*)ws;                      ws += NLAY * 65536 * 2;
    ushort* W2effb = (ushort*)ws;                      ws += NLAY * 65536 * 2;
    ushort* w1b    = (ushort*)ws;                      ws += NLAY * 65536 * 2;
    ushort* w2b    = (ushort*)ws;                      ws += NLAY * 65536 * 2;
    float* lam_pow = (float*)ws;                       ws += NLAY * 65536 * 4;
    float* scale_in = (float*)ws;                      ws += NLAY * 512 * 4;
    float* bias_in  = (float*)ws;                      ws += NLAY * 512 * 4;
    size_t table_bytes = (size_t)(ws - (char*)d_ws);

    int Bc = B_TOT;
    while (Bc > 32) {
        size_t need = table_bytes + (size_t)Bc * SEQ * (D * 2 + 2 * DH * 2) + 1024;
        if (need <= ws_size) break;
        Bc >>= 1;
    }
    ushort* xb = (ushort*)ws;                          ws += (size_t)Bc * SEQ * D * 2;
    ushort* hb = (ushort*)ws;
    ushort* Hc = hb;                                   // compact H (Bc*512), aliases hb
    ushort* xc = hb + (size_t)Bc * 512;                // compact x (Bc*128)

    setup_all_kernel<<<NLAY * 65536 / 256, 256, 0, stream>>>(
        params_log, in_br, in_bi, in_wr, in_wi, out_wr, out_wi, w1, w2,
        Winb, W2effb, w1b, w2b, lam_pow, scale_in, bias_in);

    for (int b0 = 0; b0 < B_TOT; b0 += Bc) {
        int M = Bc * SEQ;
        embed_ln_kernel<<<M / 4, 256, 0, stream>>>(
            token_emb, item_seq + (size_t)b0 * SEQ, emb_ln_g, emb_ln_b, xb);

        for (int li = 0; li < NLAY; ++li) {
            if (li < NLAY - 1) {
                inproj_scan_kernel<false><<<dim3(16, Bc), 512, 0, stream>>>(
                    xb, Winb + (size_t)li * 65536, hb,
                    (const float2*)(lam_pow + (size_t)li * 65536),
                    item_seq + (size_t)b0 * SEQ, item_seq_len + b0,
                    scale_in + li * 512, bias_in + li * 512);
                outproj_kernel<<<dim3(M / 256), 512, 0, stream>>>(
                    hb, W2effb + (size_t)li * 65536, xb, M,
                    out_br + li * D, xb,
                    lru_ln_g + li * D, lru_ln_b + li * D);
                ffn_fused_kernel<<<dim3(M / 64), 256, 0, stream>>>(
                    xb, w1b + (size_t)li * 65536, w2b + (size_t)li * 65536, xb,
                    b1 + li * DFF, b2 + li * D,
                    ffn_ln_g + li * D, ffn_ln_b + li * D, M);
            } else {
                // R19 last layer: only gathered rows needed downstream
                inproj_scan_kernel<true><<<dim3(16, Bc), 512, 0, stream>>>(
                    xb, Winb + (size_t)li * 65536, Hc,
                    (const float2*)(lam_pow + (size_t)li * 65536),
                    item_seq + (size_t)b0 * SEQ, item_seq_len + b0,
                    scale_in + li * 512, bias_in + li * 512);
                outproj_last_kernel<<<dim3((Bc + 255) / 256), 512, 0, stream>>>(
                    Hc, W2effb + (size_t)li * 65536, xc, Bc,
                    out_br + li * D, xb, item_seq_len + b0,
                    lru_ln_g + li * D, lru_ln_b + li * D);
                ffn_fused_kernel<<<dim3((Bc + 63) / 64), 256, 0, stream>>>(
                    xc, w1b + (size_t)li * 65536, w2b + (size_t)li * 65536, xc,
                    b1 + li * DFF, b2 + li * D,
                    ffn_ln_g + li * D, ffn_ln_b + li * D, Bc);
            }
        }
        gather_final_kernel<<<(Bc * D + 255) / 256, 256, 0, stream>>>(
            xc, out, b0, Bc);
    }
}

// Round 20
// 474.556 us; speedup vs baseline: 1.5520x; 1.0794x over previous
//
#include <hip/hip_runtime.h>
#include <hip/hip_bf16.h>
#include <math.h>

#define B_TOT 512
#define SEQ   200
#define D     128
#define DH    256
#define DFF   512
#define LPAD  256
#define PADL  56
#define NLAY  2
#define SST   18   // scan LDS row stride (floats)

typedef __attribute__((ext_vector_type(8))) short bf16x8;
typedef __attribute__((ext_vector_type(4))) float floatx4;

static __device__ inline float bf2f(ushort u) {
    union { unsigned int i; float f; } v; v.i = ((unsigned int)u) << 16; return v.f;
}
static __device__ inline ushort f2bf(float x) {
    union { float f; unsigned int i; } v; v.f = x;
    unsigned int r = (v.i + 0x7FFFu + ((v.i >> 16) & 1u)) >> 16;   // RNE
    return (ushort)r;
}
// HW packed f32x2 -> bf16x2 (v_cvt_pk_bf16_f32 on gfx950), RNE
static __device__ inline unsigned int pkbf(float a, float b) {
    union { __hip_bfloat162 h; unsigned int u; } v;
    v.h = __float22bfloat162_rn(make_float2(a, b));
    return v.u;
}
// async global->LDS, 16B per lane; LDS dest = wave-uniform base + lane*16
static __device__ inline void gld_lds16(const void* g, void* l) {
    __builtin_amdgcn_global_load_lds(
        (const __attribute__((address_space(1))) unsigned int*)g,
        (__attribute__((address_space(3))) unsigned int*)l, 16, 0, 0);
}

// H layout: [b][g(8)][p(re/im)][s(200)][32 ch] bf16. k in 0..511: k<256 re, else im.
static __device__ inline size_t haddr(int b, int s, int k) {
    int p  = k >> 8;
    int ch = k & 255;
    int g  = ch >> 5;
    int cl = ch & 31;
    return (((((size_t)b * 8 + g) * 2 + p) * SEQ + s) * 32 + cl);
}

// ---------------------------------------------------------------------------
// Unified setup: pre-swizzled weight images + lambda powers/scales.
// ---------------------------------------------------------------------------
__global__ void setup_all_kernel(const float* __restrict__ params_log,
                                 const float* __restrict__ in_br,
                                 const float* __restrict__ in_bi,
                                 const float* __restrict__ in_wr,
                                 const float* __restrict__ in_wi,
                                 const float* __restrict__ out_wr,
                                 const float* __restrict__ out_wi,
                                 const float* __restrict__ w1,
                                 const float* __restrict__ w2,
                                 ushort* __restrict__ Winb,
                                 ushort* __restrict__ W2effb,
                                 ushort* __restrict__ w1b,
                                 ushort* __restrict__ w2b,
                                 float* __restrict__ lam_pow,
                                 float* __restrict__ scale_in,
                                 float* __restrict__ bias_in)
{
    int idx = blockIdx.x * blockDim.x + threadIdx.x;   // NLAY*65536
    int li = idx >> 16;
    int e  = idx & 65535;

    {   // inproj Ws image
        int gp = e >> 12, rem = e & 4095;
        int q = rem >> 3, e8 = rem & 7;
        int r = q >> 4, cs = q & 15;
        int c16 = cs ^ (r & 7);
        int n = (r < 16) ? (gp * 16 + r) : (256 + gp * 16 + (r - 16));
        int d = c16 * 8 + e8;
        float wv = (n < DH) ? in_wr[((size_t)li * DH + n) * D + d]
                            : in_wi[((size_t)li * DH + (n - DH)) * D + d];
        Winb[idx] = f2bf(wv);
    }
    {   // out-proj W2eff image
        int k0c = e >> 13, rem = e & 8191;
        int q = rem >> 3, e8 = rem & 7;
        int r = q >> 3, cs = q & 7;
        int c16 = cs ^ (r & 7);
        int k = k0c * 64 + c16 * 8 + e8;
        float w2v = (k < DH) ? out_wr[((size_t)li * D + r) * DH + k]
                             : -out_wi[((size_t)li * D + r) * DH + (k - DH)];
        W2effb[idx] = f2bf(w2v);
    }
    {   // ffn W1 image: logical [512][128]
        int row = e >> 7, col = e & 127;
        int ffc = row >> 7, rl = row & 127;
        int c16 = col >> 3, e8 = col & 7;
        int cs = c16 ^ (rl & 7);
        w1b[li * 65536 + ffc * 16384 + rl * 128 + cs * 8 + e8] = f2bf(w1[idx]);
    }
    {   // ffn W2 image: logical [128][512]
        int dd2 = e >> 9, kk = e & 511;
        int ffc = kk >> 7, klc = kk & 127;
        int c16 = klc >> 3, e8 = klc & 7;
        int cs = c16 ^ (dd2 & 7);
        w2b[li * 65536 + ffc * 16384 + dd2 * 128 + cs * 8 + e8] = f2bf(w2[idx]);
    }

    if (blockIdx.x < NLAY) {
        int pli = blockIdx.x;
        int c = threadIdx.x;
        const float* pl = params_log + (size_t)pli * 3 * DH;
        float nu = expf(pl[c]);
        float th = expf(pl[DH + c]);
        float ga = expf(pl[2 * DH + c]);
        float mag = expf(-nu);
        float lr = mag * cosf(th);
        float lim = mag * sinf(th);
        float2* lp = (float2*)(lam_pow + (size_t)pli * 65536) + (size_t)c * 128;
        float pr = lr, pi = lim;
        lp[0] = make_float2(pr, pi);
        for (int k = 1; k < 128; ++k) {
            float nr = pr * lr - pi * lim;
            float ni = pr * lim + pi * lr;
            pr = nr; pi = ni;
            lp[k] = make_float2(pr, pi);
        }
        scale_in[pli * 2 * DH + c]      = ga;
        scale_in[pli * 2 * DH + DH + c] = ga;
        bias_in[pli * 2 * DH + c]       = in_br[pli * DH + c] * ga;
        bias_in[pli * 2 * DH + DH + c]  = in_bi[pli * DH + c] * ga;
    }
}

// ---------------------------------------------------------------------------
// Embedding gather + LayerNorm -> bf16 x. R20: skip rows s > len[b]-1
// (causally dead; never read downstream).
// ---------------------------------------------------------------------------
__global__ __launch_bounds__(256) void embed_ln_kernel(
    const float* __restrict__ emb, const int* __restrict__ seq,
    const int* __restrict__ lenp,
    const float* __restrict__ g, const float* __restrict__ bt,
    ushort* __restrict__ x)
{
    int row  = blockIdx.x * 4 + (threadIdx.x >> 6);
    int lane = threadIdx.x & 63;
    int b = row / SEQ, s = row - b * SEQ;
    if (s >= lenp[b]) return;          // per-wave skip, no barriers in kernel
    int item = seq[row];
    float2 v = *(const float2*)(emb + (size_t)item * D + lane * 2);
    float ssum = v.x + v.y;
#pragma unroll
    for (int o = 32; o > 0; o >>= 1) ssum += __shfl_xor(ssum, o);
    float mu = ssum * (1.0f / D);
    float d0 = v.x - mu, d1 = v.y - mu;
    float vs = d0 * d0 + d1 * d1;
#pragma unroll
    for (int o = 32; o > 0; o >>= 1) vs += __shfl_xor(vs, o);
    float rstd = rsqrtf(vs * (1.0f / D) + 1e-5f);
    float2 gg = *(const float2*)(g + lane * 2);
    float2 bb = *(const float2*)(bt + lane * 2);
    unsigned int o2 = pkbf(d0 * rstd * gg.x + bb.x, d1 * rstd * gg.y + bb.y);
    *(unsigned int*)(x + (size_t)row * D + lane * 2) = o2;
}

// ---------------------------------------------------------------------------
// FUSED in-proj + exact tree scan. R20: ALL work truncated at block-uniform
// s_b = len[b]-1 (scan is causal; downstream never reads rows beyond).
// LAST=false: H-layout store of rows <= s_b. LAST=true: compact Hc[b][512].
// ---------------------------------------------------------------------------
template <bool LAST>
__global__ __launch_bounds__(512) void inproj_scan_kernel(
    const ushort* __restrict__ X, const ushort* __restrict__ Win,
    ushort* __restrict__ H, const float2* __restrict__ lamT,
    const int* __restrict__ seq, const int* __restrict__ lenp,
    const float* __restrict__ scale_in, const float* __restrict__ bias_in)
{
    __shared__ __align__(16) char smem[36864];   // Ws 8192 + xs 28672 (phase A)
    __shared__ float mkf[LPAD];
    char*  Wsm = smem;                           // [32][128] bf16, swizzled
    char*  xs  = smem + 8192;                    // [112][128] bf16, swizzled
    float* stR = (float*)smem;                   // [256][SST] (phase B alias)
    float* stI = stR + LPAD * SST;               // ends at 36864 B
    float2* lamS = (float2*)smem;                // [16][130] (tree phase alias)
    float2* bc   = (float2*)(smem + 16 * 130 * 8);

    int gp = blockIdx.x, b = blockIdx.y;
    int tid = threadIdx.x;
    int l = tid & 63, w = tid >> 6;              // 8 waves
    int ct = w & 1;                              // 0=re tile, 1=im tile
    int rq = w >> 1;                             // row quarter 0..3
    int lr = l & 15, lq = l >> 4;
    int wbase = tid & ~63;

    int c  = tid & 15;                           // scan channel
    int tl = tid >> 4;                           // 0..31
    int t0 = tl * 8;

    // R20 causal bounds (block-uniform)
    int s_b = lenp[b] - 1;                       // 0..199
    int tile_max = s_b >> 4;                     // needed MFMA tiles 0..tile_max
    int nrows = (tile_max + 1) * 16;             // staged rows (tile-rounded)
    int tb = s_b + PADL;                         // last needed padded position

    const float2* myl = lamT + (size_t)(gp * 16 + c) * 128;
    float2 l14[4];
#pragma unroll
    for (int k = 0; k < 4; ++k) l14[k] = myl[k];

    if (tid < LPAD) {
        int t = tid;
        float m = 0.f;
        if (t >= PADL) m = (seq[(size_t)b * SEQ + (t - PADL)] > 0) ? 1.f : 0.f;
        mkf[t] = m;
    }

    // ---- Phase A: async Ws stage + x stage A (rows 0..min(112,nrows))
    const ushort* xrow = X + (size_t)b * SEQ * 128;
    gld_lds16(Win + (size_t)gp * 4096 + (size_t)tid * 8,
              Wsm + (size_t)wbase * 16);
#pragma unroll
    for (int it = 0; it < 4; ++it) {
        int idx = it * 512 + tid;
        if (idx < 112 * 16) {
            int r = idx >> 4, c16 = idx & 15;
            if (r < nrows) {
                uint4 v = *(const uint4*)(xrow + (size_t)r * 128 + c16 * 8);
                *(uint4*)(xs + r * 256 + ((c16 ^ (r & 7)) * 16)) = v;
            }
        }
    }
    __syncthreads();

    bf16x8 wf[4];
#pragma unroll
    for (int kk = 0; kk < 4; ++kk) {
        int ca = kk * 4 + lq;
        int wr = ct * 16 + lr;
        wf[kk] = *(const bf16x8*)(Wsm + wr * 256 + ((ca ^ (wr & 7)) * 16));
    }
    int tstart = rq ? (3 * rq + 1) : 0;          // 0 / 4 / 7 / 10
    int tcnt   = rq ? 3 : 4;
    floatx4 acc[4];
#pragma unroll
    for (int tt = 0; tt < 4; ++tt) acc[tt] = (floatx4)0.f;

    if (rq < 2) {
#pragma unroll
        for (int tt = 0; tt < 4; ++tt) {
            if (tt < tcnt && (tstart + tt) <= tile_max) {
                int t  = tstart + tt;
                int ar = t * 16 + lr;
#pragma unroll
                for (int kk = 0; kk < 4; ++kk) {
                    int ca = kk * 4 + lq;
                    bf16x8 af = *(const bf16x8*)(xs + ar * 256 + ((ca ^ (ar & 7)) * 16));
                    acc[tt] = __builtin_amdgcn_mfma_f32_16x16x32_bf16(wf[kk], af, acc[tt], 0, 0, 0);
                }
            }
        }
    }
    __syncthreads();

    // stage B: rows 112..nrows-1 -> xs local rows 0.. (zeros for gr >= 200)
    if (nrows > 112) {
#pragma unroll
        for (int it = 0; it < 3; ++it) {
            int idx = it * 512 + tid;                // 96*16 = 1536
            int r = idx >> 4, c16 = idx & 15;
            int gr = 112 + r;
            if (gr < nrows) {
                uint4 v = make_uint4(0u, 0u, 0u, 0u);
                if (gr < 200) v = *(const uint4*)(xrow + (size_t)gr * 128 + c16 * 8);
                *(uint4*)(xs + r * 256 + ((c16 ^ (r & 7)) * 16)) = v;
            }
        }
    }
    __syncthreads();

    if (rq >= 2) {
#pragma unroll
        for (int tt = 0; tt < 4; ++tt) {
            if (tt < tcnt && (tstart + tt) <= tile_max) {
                int t  = tstart + tt;
                int ar = (t - 7) * 16 + lr;
#pragma unroll
                for (int kk = 0; kk < 4; ++kk) {
                    int ca = kk * 4 + lq;
                    bf16x8 af = *(const bf16x8*)(xs + ar * 256 + ((ca ^ (ar & 7)) * 16));
                    acc[tt] = __builtin_amdgcn_mfma_f32_16x16x32_bf16(wf[kk], af, acc[tt], 0, 0, 0);
                }
            }
        }
    }
    __syncthreads();

    // ---- Phase B: zero pad rows + epilogue (rows <= s_b) -> stR/stI
    for (int idx = tid; idx < PADL * SST; idx += 512) { stR[idx] = 0.f; stI[idx] = 0.f; }
    {
        float4 g4 = *(const float4*)(scale_in + ct * 256 + gp * 16 + lq * 4);
        float4 b4 = *(const float4*)(bias_in  + ct * 256 + gp * 16 + lq * 4);
        float* dst = ct ? stI : stR;
#pragma unroll
        for (int tt = 0; tt < 4; ++tt) {
            if (tt < tcnt && (tstart + tt) <= tile_max) {
                int t = tstart + tt;
                int s = t * 16 + lr;
                if (s <= s_b) {
                    int pos = s + PADL;
                    dst[pos * SST + lq * 4 + 0] = acc[tt][0] * g4.x + b4.x;
                    dst[pos * SST + lq * 4 + 1] = acc[tt][1] * g4.y + b4.y;
                    dst[pos * SST + lq * 4 + 2] = acc[tt][2] * g4.z + b4.z;
                    dst[pos * SST + lq * 4 + 3] = acc[tt][3] * g4.w + b4.w;
                }
            }
        }
    }
    __syncthreads();

    float xr[8], xi[8], mf[8];
#pragma unroll
    for (int k = 0; k < 8; ++k) {
        xr[k] = stR[(t0 + k) * SST + c];
        xi[k] = stI[(t0 + k) * SST + c];
        mf[k] = mkf[t0 + k];
    }
    __syncthreads();

    {
        const char* src = (const char*)(lamT + (size_t)gp * 16 * 128);
#pragma unroll
        for (int it = 0; it < 2; ++it) {
            int idx = it * 512 + tid;
            int row = idx >> 6, c4 = idx & 63;
            *(uint4*)((char*)lamS + row * 1040 + c4 * 16) =
                *(const uint4*)(src + row * 1024 + c4 * 16);
        }
    }

    // levels 1-3: thread-internal (only threads with needed positions)
    if (t0 <= tb) {
#pragma unroll
        for (int k = 0; k < 8; k += 2) {
            float sr = xr[k] * mf[k], si = xi[k] * mf[k];
            xr[k+1] += l14[0].x * sr - l14[0].y * si;
            xi[k+1] += l14[0].x * si + l14[0].y * sr;
        }
#pragma unroll
        for (int k = 1; k < 8; k += 4) {
            float sr = xr[k] * mf[k], si = xi[k] * mf[k];
            xr[k+1] += l14[0].x * sr - l14[0].y * si;
            xi[k+1] += l14[0].x * si + l14[0].y * sr;
            xr[k+2] += l14[1].x * sr - l14[1].y * si;
            xi[k+2] += l14[1].x * si + l14[1].y * sr;
        }
        {
            float sr = xr[3] * mf[3], si = xi[3] * mf[3];
#pragma unroll
            for (int j = 0; j < 4; ++j) {
                xr[4+j] += l14[j].x * sr - l14[j].y * si;
                xi[4+j] += l14[j].x * si + l14[j].y * sr;
            }
        }
    }

    // levels 4-8: LDS end-value broadcast (targets beyond tb skipped)
#pragma unroll
    for (int i = 4; i <= 8; ++i) {
        int half = 1 << (i - 1);
        int buf  = (i & 1) * 544;
        bc[buf + tl * 17 + c] = make_float2(xr[7], xi[7]);
        __syncthreads();
        int off = t0 & ((half << 1) - 1);
        if (off >= half && t0 <= tb) {
            int src = t0 - off + half - 1;
            float m = mkf[src];
            float2 sv = bc[buf + (src >> 3) * 17 + c];
            float sr = sv.x * m, si = sv.y * m;
            int e = off - half;
            const float2* lp = lamS + c * 130 + e;
#pragma unroll
            for (int k = 0; k < 8; ++k) {
                float2 lv = lp[k];
                xr[k] += lv.x * sr - lv.y * si;
                xi[k] += lv.x * si + lv.y * sr;
            }
        }
    }
    __syncthreads();

#pragma unroll
    for (int k = 0; k < 8; ++k) {
        stR[(t0 + k) * SST + c] = xr[k];
        stI[(t0 + k) * SST + c] = xi[k];
    }
    __syncthreads();

    if (LAST) {
        // store only h at position s_b into compact Hc[b][512]
        if (tid < 32) {
            int t = tb;
            int p = tid >> 4, cc = tid & 15;
            float v = (p ? stI : stR)[t * SST + cc];
            H[(size_t)b * 512 + p * 256 + gp * 16 + cc] = f2bf(v);
        }
    } else {
        int g  = gp >> 1;
        int hc = (gp & 1) * 16;
        ushort* baseg = H + (size_t)(b * 8 + g) * 2 * SEQ * 32 + hc;
#pragma unroll
        for (int it = 0; it < 4; ++it) {
            int idx4 = it * 512 + tid;
            if (idx4 < 2 * SEQ * 4) {
                int q  = idx4 & 3;
                int ps = idx4 >> 2;
                int p  = ps >= SEQ;
                int s  = ps - p * SEQ;
                if (s > s_b) continue;           // causally dead, never read
                int t  = s + PADL;
                const float* sp = (p ? stI : stR) + t * SST + q * 4;
                float2 a = *(const float2*)(sp);
                float2 d = *(const float2*)(sp + 2);
                uint2 raw;
                raw.x = pkbf(a.x, a.y);
                raw.y = pkbf(d.x, d.y);
                *(uint2*)(baseg + (size_t)ps * 32 + q * 4) = raw;
            }
        }
    }
}

// ---------------------------------------------------------------------------
// Out-proj GEMM (full path), 512 threads, 256-row M-tile.
// R20: early block exit if every row in [m0, m0+256) is causally dead.
// ---------------------------------------------------------------------------
__global__ __launch_bounds__(512) void outproj_kernel(
    const ushort* __restrict__ A, const ushort* __restrict__ Wimg,
    ushort* __restrict__ Cout, int M, const int* __restrict__ lenp,
    const float* __restrict__ e0,
    const ushort* __restrict__ res,
    const float* __restrict__ lng, const float* __restrict__ lnb)
{
    int m0 = blockIdx.x * 256;
    {   // R20 early exit
        bool any = false;
        int bhi = (m0 + 255 < M ? m0 + 255 : M - 1) / SEQ;
        for (int bb = m0 / SEQ; bb <= bhi; ++bb) {
            int slow = m0 - bb * SEQ; if (slow < 0) slow = 0;
            int shigh = m0 + 255 - bb * SEQ; if (shigh > SEQ - 1) shigh = SEQ - 1;
            if (slow <= shigh && slow <= lenp[bb] - 1) any = true;
        }
        if (!any) return;
    }
    __shared__ __align__(16) char As[32768];
    __shared__ __align__(16) char Bs[16384];
    __shared__ float2 lnS[2][256];
    int tid = threadIdx.x;
    int l = tid & 63, w = tid >> 6;
    int chh = w >> 2;
    int rh  = w & 3;
    int lr = l & 15, lq = l >> 4;
    int wbase = tid & ~63;

    int cst = tid & 7;
    int rr  = tid >> 3;
    int sb[4], ss[4];
#pragma unroll
    for (int it = 0; it < 4; ++it) {
        unsigned int gr = m0 + it * 64 + rr;
        sb[it] = gr / SEQ; ss[it] = gr - sb[it] * SEQ;
    }

    floatx4 acc[4][4];
#pragma unroll
    for (int i = 0; i < 4; ++i)
#pragma unroll
        for (int j = 0; j < 4; ++j) acc[i][j] = (floatx4)0.f;

    for (int k0c = 0; k0c < 8; ++k0c) {
        int k0 = k0c * 64;
        {
            const ushort* img = Wimg + (size_t)k0c * 8192;
#pragma unroll
            for (int it = 0; it < 2; ++it)
                gld_lds16(img + (size_t)(it * 512 + tid) * 8,
                          Bs + (size_t)(it * 512 + wbase) * 16);
        }
#pragma unroll
        for (int it = 0; it < 4; ++it) {
            int r = it * 64 + rr;
            uint4 va = *(const uint4*)(A + haddr(sb[it], ss[it], k0 + cst * 8));
            *(uint4*)(As + r * 128 + ((cst ^ (r & 7)) * 16)) = va;
        }
        __syncthreads();
#pragma unroll
        for (int kk = 0; kk < 2; ++kk) {
            bf16x8 wf[4], af[4];
            int ca = kk * 4 + lq;
#pragma unroll
            for (int i = 0; i < 4; ++i) {
                int rb = chh * 64 + i * 16 + lr;
                wf[i] = *(const bf16x8*)(Bs + rb * 128 + ((ca ^ (rb & 7)) * 16));
                int ra = rh * 64 + i * 16 + lr;
                af[i] = *(const bf16x8*)(As + ra * 128 + ((ca ^ (ra & 7)) * 16));
            }
#pragma unroll
            for (int i = 0; i < 4; ++i)
#pragma unroll
                for (int j = 0; j < 4; ++j)
                    acc[i][j] = __builtin_amdgcn_mfma_f32_16x16x32_bf16(
                        wf[i], af[j], acc[i][j], 0, 0, 0);
        }
        __syncthreads();
    }

    int chb[4], arow[4];
#pragma unroll
    for (int i = 0; i < 4; ++i) chb[i] = chh * 64 + i * 16 + lq * 4;
#pragma unroll
    for (int j = 0; j < 4; ++j) arow[j] = m0 + rh * 64 + j * 16 + lr;

    {
        float4 bias[4], gv[4], bv[4];
#pragma unroll
        for (int i = 0; i < 4; ++i) {
            bias[i] = *(const float4*)(e0 + chb[i]);
            gv[i]   = *(const float4*)(lng + chb[i]);
            bv[i]   = *(const float4*)(lnb + chb[i]);
        }
#pragma unroll
        for (int j = 0; j < 4; ++j) {
#pragma unroll
            for (int i = 0; i < 4; ++i) {
                ushort4 r4 = *(const ushort4*)(res + (size_t)arow[j] * 128 + chb[i]);
                acc[i][j][0] += ((const float*)&bias[i])[0] + bf2f(r4.x);
                acc[i][j][1] += ((const float*)&bias[i])[1] + bf2f(r4.y);
                acc[i][j][2] += ((const float*)&bias[i])[2] + bf2f(r4.z);
                acc[i][j][3] += ((const float*)&bias[i])[3] + bf2f(r4.w);
            }
        }
#pragma unroll
        for (int j = 0; j < 4; ++j) {
            float s = 0.f, q = 0.f;
#pragma unroll
            for (int i = 0; i < 4; ++i)
#pragma unroll
                for (int reg = 0; reg < 4; ++reg) {
                    float v = acc[i][j][reg];
                    s += v; q += v * v;
                }
            s += __shfl_xor(s, 16); q += __shfl_xor(q, 16);
            s += __shfl_xor(s, 32); q += __shfl_xor(q, 32);
            if (lq == 0) lnS[chh][rh * 64 + j * 16 + lr] = make_float2(s, q);
        }
        __syncthreads();
#pragma unroll
        for (int j = 0; j < 4; ++j) {
            int rl = rh * 64 + j * 16 + lr;
            float2 s0 = lnS[0][rl], s1 = lnS[1][rl];
            float mu  = (s0.x + s1.x) * (1.0f / 128.0f);
            float var = (s0.y + s1.y) * (1.0f / 128.0f) - mu * mu;
            float rstd = rsqrtf(var + 1e-5f);
#pragma unroll
            for (int i = 0; i < 4; ++i) {
                uint2 u;
                u.x = pkbf((acc[i][j][0] - mu) * rstd * ((const float*)&gv[i])[0] + ((const float*)&bv[i])[0],
                           (acc[i][j][1] - mu) * rstd * ((const float*)&gv[i])[1] + ((const float*)&bv[i])[1]);
                u.y = pkbf((acc[i][j][2] - mu) * rstd * ((const float*)&gv[i])[2] + ((const float*)&bv[i])[2],
                           (acc[i][j][3] - mu) * rstd * ((const float*)&gv[i])[3] + ((const float*)&bv[i])[3]);
                *(uint2*)(Cout + (size_t)arow[j] * 128 + chb[i]) = u;
            }
        }
    }
}

// ---------------------------------------------------------------------------
// Out-proj LAST (R19): compact M=Bc rows from Hc[b][512].
// ---------------------------------------------------------------------------
__global__ __launch_bounds__(512) void outproj_last_kernel(
    const ushort* __restrict__ Hc, const ushort* __restrict__ Wimg,
    ushort* __restrict__ xc, int Bc,
    const float* __restrict__ e0,
    const ushort* __restrict__ Xres, const int* __restrict__ lenp,
    const float* __restrict__ lng, const float* __restrict__ lnb)
{
    __shared__ __align__(16) char As[32768];
    __shared__ __align__(16) char Bs[16384];
    __shared__ float2 lnS[2][256];
    int tid = threadIdx.x;
    int l = tid & 63, w = tid >> 6;
    int chh = w >> 2;
    int rh  = w & 3;
    int lr = l & 15, lq = l >> 4;
    int m0 = blockIdx.x * 256;
    int wbase = tid & ~63;

    int cst = tid & 7;
    int rr  = tid >> 3;

    floatx4 acc[4][4];
#pragma unroll
    for (int i = 0; i < 4; ++i)
#pragma unroll
        for (int j = 0; j < 4; ++j) acc[i][j] = (floatx4)0.f;

    for (int k0c = 0; k0c < 8; ++k0c) {
        int k0 = k0c * 64;
        {
            const ushort* img = Wimg + (size_t)k0c * 8192;
#pragma unroll
            for (int it = 0; it < 2; ++it)
                gld_lds16(img + (size_t)(it * 512 + tid) * 8,
                          Bs + (size_t)(it * 512 + wbase) * 16);
        }
#pragma unroll
        for (int it = 0; it < 4; ++it) {
            int r = it * 64 + rr;
            int gr = m0 + r; if (gr >= Bc) gr = Bc - 1;
            uint4 va = *(const uint4*)(Hc + (size_t)gr * 512 + k0 + cst * 8);
            *(uint4*)(As + r * 128 + ((cst ^ (r & 7)) * 16)) = va;
        }
        __syncthreads();
#pragma unroll
        for (int kk = 0; kk < 2; ++kk) {
            bf16x8 wf[4], af[4];
            int ca = kk * 4 + lq;
#pragma unroll
            for (int i = 0; i < 4; ++i) {
                int rb = chh * 64 + i * 16 + lr;
                wf[i] = *(const bf16x8*)(Bs + rb * 128 + ((ca ^ (rb & 7)) * 16));
                int ra = rh * 64 + i * 16 + lr;
                af[i] = *(const bf16x8*)(As + ra * 128 + ((ca ^ (ra & 7)) * 16));
            }
#pragma unroll
            for (int i = 0; i < 4; ++i)
#pragma unroll
                for (int j = 0; j < 4; ++j)
                    acc[i][j] = __builtin_amdgcn_mfma_f32_16x16x32_bf16(
                        wf[i], af[j], acc[i][j], 0, 0, 0);
        }
        __syncthreads();
    }

    int chb[4], arow[4];
#pragma unroll
    for (int i = 0; i < 4; ++i) chb[i] = chh * 64 + i * 16 + lq * 4;
#pragma unroll
    for (int j = 0; j < 4; ++j) arow[j] = m0 + rh * 64 + j * 16 + lr;

    {
        float4 bias[4], gv[4], bv[4];
#pragma unroll
        for (int i = 0; i < 4; ++i) {
            bias[i] = *(const float4*)(e0 + chb[i]);
            gv[i]   = *(const float4*)(lng + chb[i]);
            bv[i]   = *(const float4*)(lnb + chb[i]);
        }
#pragma unroll
        for (int j = 0; j < 4; ++j) {
            int br = arow[j] < Bc ? arow[j] : Bc - 1;
            int sb_ = lenp[br] - 1;
            const ushort* rbase = Xres + ((size_t)br * SEQ + sb_) * 128;
#pragma unroll
            for (int i = 0; i < 4; ++i) {
                ushort4 r4 = *(const ushort4*)(rbase + chb[i]);
                acc[i][j][0] += ((const float*)&bias[i])[0] + bf2f(r4.x);
                acc[i][j][1] += ((const float*)&bias[i])[1] + bf2f(r4.y);
                acc[i][j][2] += ((const float*)&bias[i])[2] + bf2f(r4.z);
                acc[i][j][3] += ((const float*)&bias[i])[3] + bf2f(r4.w);
            }
        }
#pragma unroll
        for (int j = 0; j < 4; ++j) {
            float s = 0.f, q = 0.f;
#pragma unroll
            for (int i = 0; i < 4; ++i)
#pragma unroll
                for (int reg = 0; reg < 4; ++reg) {
                    float v = acc[i][j][reg];
                    s += v; q += v * v;
                }
            s += __shfl_xor(s, 16); q += __shfl_xor(q, 16);
            s += __shfl_xor(s, 32); q += __shfl_xor(q, 32);
            if (lq == 0) lnS[chh][rh * 64 + j * 16 + lr] = make_float2(s, q);
        }
        __syncthreads();
#pragma unroll
        for (int j = 0; j < 4; ++j) {
            int rl = rh * 64 + j * 16 + lr;
            float2 s0 = lnS[0][rl], s1 = lnS[1][rl];
            float mu  = (s0.x + s1.x) * (1.0f / 128.0f);
            float var = (s0.y + s1.y) * (1.0f / 128.0f) - mu * mu;
            float rstd = rsqrtf(var + 1e-5f);
            if (arow[j] < Bc) {
#pragma unroll
                for (int i = 0; i < 4; ++i) {
                    uint2 u;
                    u.x = pkbf((acc[i][j][0] - mu) * rstd * ((const float*)&gv[i])[0] + ((const float*)&bv[i])[0],
                               (acc[i][j][1] - mu) * rstd * ((const float*)&gv[i])[1] + ((const float*)&bv[i])[1]);
                    u.y = pkbf((acc[i][j][2] - mu) * rstd * ((const float*)&gv[i])[2] + ((const float*)&bv[i])[2],
                               (acc[i][j][3] - mu) * rstd * ((const float*)&gv[i])[3] + ((const float*)&bv[i])[3]);
                    *(uint2*)(xc + (size_t)arow[j] * 128 + chb[i]) = u;
                }
            }
        }
    }
}

// ---------------------------------------------------------------------------
// Fused FFN v6 + row guards. R20: early block exit when all 64 rows are
// causally dead (lenp != nullptr => full path with flattened (b,s) rows).
// ---------------------------------------------------------------------------
__global__ __launch_bounds__(256) void ffn_fused_kernel(
    const ushort* __restrict__ X, const ushort* __restrict__ W1,
    const ushort* __restrict__ W2, ushort* __restrict__ Out,
    const float* __restrict__ b1, const float* __restrict__ b2,
    const float* __restrict__ lng, const float* __restrict__ lnb,
    int Mtot, const int* __restrict__ lenp)
{
    int m0 = blockIdx.x * 64;
    if (lenp) {   // R20 early exit (full path only)
        bool any = false;
        int bhi = (m0 + 63 < Mtot ? m0 + 63 : Mtot - 1) / SEQ;
        for (int bb = m0 / SEQ; bb <= bhi; ++bb) {
            int slow = m0 - bb * SEQ; if (slow < 0) slow = 0;
            int shigh = m0 + 63 - bb * SEQ; if (shigh > SEQ - 1) shigh = SEQ - 1;
            if (slow <= shigh && slow <= lenp[bb] - 1) any = true;
        }
        if (!any) return;
    }
    __shared__ __align__(16) char Bs[32768];   // pre-swizzled 32KB weight chunk
    __shared__ ushort Ps[64 * 136];     // P tile, row stride 136
    __shared__ float2 lnS[2][64];
    int tid = threadIdx.x;
    int l = tid & 63, w = tid >> 6;
    int chh = w >> 1, rh = w & 1;
    int lr = l & 15, lq = l >> 4;
    int wbase = tid & ~63;              // wave-uniform chunk base

    bf16x8 af_x[8];
#pragma unroll
    for (int j = 0; j < 2; ++j)
#pragma unroll
        for (int kk2 = 0; kk2 < 4; ++kk2) {
            int row = m0 + rh * 32 + j * 16 + lr;
            if (row >= Mtot) row = Mtot - 1;
            int k   = kk2 * 32 + lq * 8;
            af_x[(j << 2) | kk2] = *(const bf16x8*)(X + (size_t)row * 128 + k);
        }

    floatx4 acc2[4][2];
#pragma unroll
    for (int i = 0; i < 4; ++i)
#pragma unroll
        for (int j = 0; j < 2; ++j) acc2[i][j] = (floatx4)0.f;

    for (int ffc = 0; ffc < 4; ++ffc) {
        if (ffc) __syncthreads();
        {
            const ushort* img = W1 + (size_t)ffc * 16384;
#pragma unroll
            for (int it = 0; it < 8; ++it)
                gld_lds16(img + (size_t)(it * 256 + tid) * 8,
                          Bs + (size_t)(it * 256 + wbase) * 16);
        }
        __syncthreads();

        floatx4 acc1[4][2];
#pragma unroll
        for (int i = 0; i < 4; ++i)
#pragma unroll
            for (int j = 0; j < 2; ++j) acc1[i][j] = (floatx4)0.f;
#pragma unroll
        for (int kk2 = 0; kk2 < 4; ++kk2) {
            int ca = kk2 * 4 + lq;
            bf16x8 wf[4];
#pragma unroll
            for (int i = 0; i < 4; ++i) {
                int rb = chh * 64 + i * 16 + lr;
                wf[i] = *(const bf16x8*)(Bs + rb * 256 + ((ca ^ (rb & 7)) * 16));
            }
#pragma unroll
            for (int i = 0; i < 4; ++i)
#pragma unroll
                for (int j = 0; j < 2; ++j)
                    acc1[i][j] = __builtin_amdgcn_mfma_f32_16x16x32_bf16(
                        wf[i], af_x[(j << 2) | kk2], acc1[i][j], 0, 0, 0);
        }

#pragma unroll
        for (int j = 0; j < 2; ++j) {
            int rowl = rh * 32 + j * 16 + lr;
#pragma unroll
            for (int i = 0; i < 4; ++i) {
                int ch0 = chh * 64 + i * 16 + lq * 4;
                float4 bv = *(const float4*)(b1 + ffc * 128 + ch0);
                float g0, g1, g2, g3, v;
                v = acc1[i][j][0] + bv.x; g0 = 0.5f * v * (1.0f + erff(v * 0.70710678118654752f));
                v = acc1[i][j][1] + bv.y; g1 = 0.5f * v * (1.0f + erff(v * 0.70710678118654752f));
                v = acc1[i][j][2] + bv.z; g2 = 0.5f * v * (1.0f + erff(v * 0.70710678118654752f));
                v = acc1[i][j][3] + bv.w; g3 = 0.5f * v * (1.0f + erff(v * 0.70710678118654752f));
                uint2 u; u.x = pkbf(g0, g1); u.y = pkbf(g2, g3);
                *(uint2*)(Ps + rowl * 136 + ch0) = u;
            }
        }
        __syncthreads();

        {
            const ushort* img = W2 + (size_t)ffc * 16384;
#pragma unroll
            for (int it = 0; it < 8; ++it)
                gld_lds16(img + (size_t)(it * 256 + tid) * 8,
                          Bs + (size_t)(it * 256 + wbase) * 16);
        }
        __syncthreads();

#pragma unroll
        for (int kk2 = 0; kk2 < 4; ++kk2) {
            int ca = kk2 * 4 + lq;
            bf16x8 wf[4], af[2];
#pragma unroll
            for (int i = 0; i < 4; ++i) {
                int rb = chh * 64 + i * 16 + lr;
                wf[i] = *(const bf16x8*)(Bs + rb * 256 + ((ca ^ (rb & 7)) * 16));
            }
#pragma unroll
            for (int j = 0; j < 2; ++j) {
                int rowl = rh * 32 + j * 16 + lr;
                af[j] = *(const bf16x8*)(Ps + rowl * 136 + kk2 * 32 + lq * 8);
            }
#pragma unroll
            for (int i = 0; i < 4; ++i)
#pragma unroll
                for (int j = 0; j < 2; ++j)
                    acc2[i][j] = __builtin_amdgcn_mfma_f32_16x16x32_bf16(
                        wf[i], af[j], acc2[i][j], 0, 0, 0);
        }
    }

    int chb[4], arow[2];
#pragma unroll
    for (int i = 0; i < 4; ++i) chb[i] = chh * 64 + i * 16 + lq * 4;
#pragma unroll
    for (int j = 0; j < 2; ++j) arow[j] = m0 + rh * 32 + j * 16 + lr;

    float4 bias[4], gv[4], bv[4];
#pragma unroll
    for (int i = 0; i < 4; ++i) {
        bias[i] = *(const float4*)(b2 + chb[i]);
        gv[i]   = *(const float4*)(lng + chb[i]);
        bv[i]   = *(const float4*)(lnb + chb[i]);
    }
#pragma unroll
    for (int j = 0; j < 2; ++j) {
        int rowc = arow[j] < Mtot ? arow[j] : Mtot - 1;
#pragma unroll
        for (int i = 0; i < 4; ++i) {
            ushort4 r4 = *(const ushort4*)(X + (size_t)rowc * 128 + chb[i]);
            acc2[i][j][0] += ((const float*)&bias[i])[0] + bf2f(r4.x);
            acc2[i][j][1] += ((const float*)&bias[i])[1] + bf2f(r4.y);
            acc2[i][j][2] += ((const float*)&bias[i])[2] + bf2f(r4.z);
            acc2[i][j][3] += ((const float*)&bias[i])[3] + bf2f(r4.w);
        }
    }
#pragma unroll
    for (int j = 0; j < 2; ++j) {
        float s = 0.f, q = 0.f;
#pragma unroll
        for (int i = 0; i < 4; ++i)
#pragma unroll
            for (int reg = 0; reg < 4; ++reg) {
                float v = acc2[i][j][reg];
                s += v; q += v * v;
            }
        s += __shfl_xor(s, 16); q += __shfl_xor(q, 16);
        s += __shfl_xor(s, 32); q += __shfl_xor(q, 32);
        if (lq == 0) lnS[chh][rh * 32 + j * 16 + lr] = make_float2(s, q);
    }
    __syncthreads();
#pragma unroll
    for (int j = 0; j < 2; ++j) {
        int rl = rh * 32 + j * 16 + lr;
        float2 s0 = lnS[0][rl], s1 = lnS[1][rl];
        float mu  = (s0.x + s1.x) * (1.0f / 128.0f);
        float var = (s0.y + s1.y) * (1.0f / 128.0f) - mu * mu;
        float rstd = rsqrtf(var + 1e-5f);
        if (arow[j] < Mtot) {
#pragma unroll
            for (int i = 0; i < 4; ++i) {
                uint2 u;
                u.x = pkbf((acc2[i][j][0] - mu) * rstd * ((const float*)&gv[i])[0] + ((const float*)&bv[i])[0],
                           (acc2[i][j][1] - mu) * rstd * ((const float*)&gv[i])[1] + ((const float*)&bv[i])[1]);
                u.y = pkbf((acc2[i][j][2] - mu) * rstd * ((const float*)&gv[i])[2] + ((const float*)&bv[i])[2],
                           (acc2[i][j][3] - mu) * rstd * ((const float*)&gv[i])[3] + ((const float*)&bv[i])[3]);
                *(uint2*)(Out + (size_t)arow[j] * 128 + chb[i]) = u;
            }
        }
    }
}

// ---------------------------------------------------------------------------
__global__ void gather_final_kernel(const ushort* __restrict__ xc,
                                    float* __restrict__ out, int b0, int Bc)
{
    int i = blockIdx.x * 256 + threadIdx.x;
    if (i >= Bc * D) return;
    out[(size_t)b0 * D + i] = bf2f(xc[i]);
}

// ---------------------------------------------------------------------------
extern "C" void kernel_launch(void* const* d_in, const int* in_sizes, int n_in,
                              void* d_out, int out_size, void* d_ws, size_t ws_size,
                              hipStream_t stream)
{
    const float* token_emb  = (const float*)d_in[0];
    const float* emb_ln_g   = (const float*)d_in[1];
    const float* emb_ln_b   = (const float*)d_in[2];
    const float* params_log = (const float*)d_in[3];
    const float* in_wr      = (const float*)d_in[4];
    const float* in_wi      = (const float*)d_in[5];
    const float* in_br      = (const float*)d_in[6];
    const float* in_bi      = (const float*)d_in[7];
    const float* out_wr     = (const float*)d_in[8];
    const float* out_wi     = (const float*)d_in[9];
    const float* out_br     = (const float*)d_in[10];
    const float* lru_ln_g   = (const float*)d_in[12];
    const float* lru_ln_b   = (const float*)d_in[13];
    const float* w1         = (const float*)d_in[14];
    const float* b1         = (const float*)d_in[15];
    const float* w2         = (const float*)d_in[16];
    const float* b2         = (const float*)d_in[17];
    const float* ffn_ln_g   = (const float*)d_in[18];
    const float* ffn_ln_b   = (const float*)d_in[19];
    const int*   item_seq   = (const int*)d_in[20];
    const int*   item_seq_len = (const int*)d_in[21];
    float* out = (float*)d_out;

    char* ws = (char*)d_ws;
    ushort* Winb   = (ushort*)ws;                      ws += NLAY * 65536 * 2;
    ushort* W2effb = (ushort*)ws;                      ws += NLAY * 65536 * 2;
    ushort* w1b    = (ushort*)ws;                      ws += NLAY * 65536 * 2;
    ushort* w2b    = (ushort*)ws;                      ws += NLAY * 65536 * 2;
    float* lam_pow = (float*)ws;                       ws += NLAY * 65536 * 4;
    float* scale_in = (float*)ws;                      ws += NLAY * 512 * 4;
    float* bias_in  = (float*)ws;                      ws += NLAY * 512 * 4;
    size_t table_bytes = (size_t)(ws - (char*)d_ws);

    int Bc = B_TOT;
    while (Bc > 32) {
        size_t need = table_bytes + (size_t)Bc * SEQ * (D * 2 + 2 * DH * 2) + 1024;
        if (need <= ws_size) break;
        Bc >>= 1;
    }
    ushort* xb = (ushort*)ws;                          ws += (size_t)Bc * SEQ * D * 2;
    ushort* hb = (ushort*)ws;
    ushort* Hc = hb;                                   // compact H (Bc*512), aliases hb
    ushort* xc = hb + (size_t)Bc * 512;                // compact x (Bc*128)

    setup_all_kernel<<<NLAY * 65536 / 256, 256, 0, stream>>>(
        params_log, in_br, in_bi, in_wr, in_wi, out_wr, out_wi, w1, w2,
        Winb, W2effb, w1b, w2b, lam_pow, scale_in, bias_in);

    for (int b0 = 0; b0 < B_TOT; b0 += Bc) {
        int M = Bc * SEQ;
        const int* lenp = item_seq_len + b0;
        embed_ln_kernel<<<M / 4, 256, 0, stream>>>(
            token_emb, item_seq + (size_t)b0 * SEQ, lenp,
            emb_ln_g, emb_ln_b, xb);

        for (int li = 0; li < NLAY; ++li) {
            if (li < NLAY - 1) {
                inproj_scan_kernel<false><<<dim3(16, Bc), 512, 0, stream>>>(
                    xb, Winb + (size_t)li * 65536, hb,
                    (const float2*)(lam_pow + (size_t)li * 65536),
                    item_seq + (size_t)b0 * SEQ, lenp,
                    scale_in + li * 512, bias_in + li * 512);
                outproj_kernel<<<dim3(M / 256), 512, 0, stream>>>(
                    hb, W2effb + (size_t)li * 65536, xb, M, lenp,
                    out_br + li * D, xb,
                    lru_ln_g + li * D, lru_ln_b + li * D);
                ffn_fused_kernel<<<dim3(M / 64), 256, 0, stream>>>(
                    xb, w1b + (size_t)li * 65536, w2b + (size_t)li * 65536, xb,
                    b1 + li * DFF, b2 + li * D,
                    ffn_ln_g + li * D, ffn_ln_b + li * D, M, lenp);
            } else {
                inproj_scan_kernel<true><<<dim3(16, Bc), 512, 0, stream>>>(
                    xb, Winb + (size_t)li * 65536, Hc,
                    (const float2*)(lam_pow + (size_t)li * 65536),
                    item_seq + (size_t)b0 * SEQ, lenp,
                    scale_in + li * 512, bias_in + li * 512);
                outproj_last_kernel<<<dim3((Bc + 255) / 256), 512, 0, stream>>>(
                    Hc, W2effb + (size_t)li * 65536, xc, Bc,
                    out_br + li * D, xb, lenp,
                    lru_ln_g + li * D, lru_ln_b + li * D);
                ffn_fused_kernel<<<dim3((Bc + 63) / 64), 256, 0, stream>>>(
                    xc, w1b + (size_t)li * 65536, w2b + (size_t)li * 65536, xc,
                    b1 + li * DFF, b2 + li * D,
                    ffn_ln_g + li * D, ffn_ln_b + li * D, Bc, (const int*)0);
            }
        }
        gather_final_kernel<<<(Bc * D + 255) / 256, 256, 0, stream>>>(
            xc, out, b0, Bc);
    }
}

// Round 21
// 439.501 us; speedup vs baseline: 1.6758x; 1.0798x over previous
//
#include <hip/hip_runtime.h>
#include <hip/hip_bf16.h>
#include <math.h>

#define B_TOT 512
#define SEQ   200
#define D     128
#define DH    256
#define DFF   512
#define LPAD  256
#define PADL  56
#define NLAY  2
#define SST   18   // scan LDS row stride (floats)

typedef __attribute__((ext_vector_type(8))) short bf16x8;
typedef __attribute__((ext_vector_type(4))) float floatx4;

static __device__ inline float bf2f(ushort u) {
    union { unsigned int i; float f; } v; v.i = ((unsigned int)u) << 16; return v.f;
}
static __device__ inline ushort f2bf(float x) {
    union { float f; unsigned int i; } v; v.f = x;
    unsigned int r = (v.i + 0x7FFFu + ((v.i >> 16) & 1u)) >> 16;   // RNE
    return (ushort)r;
}
// HW packed f32x2 -> bf16x2 (v_cvt_pk_bf16_f32 on gfx950), RNE
static __device__ inline unsigned int pkbf(float a, float b) {
    union { __hip_bfloat162 h; unsigned int u; } v;
    v.h = __float22bfloat162_rn(make_float2(a, b));
    return v.u;
}
// async global->LDS, 16B per lane; LDS dest = wave-uniform base + lane*16
static __device__ inline void gld_lds16(const void* g, void* l) {
    __builtin_amdgcn_global_load_lds(
        (const __attribute__((address_space(1))) unsigned int*)g,
        (__attribute__((address_space(3))) unsigned int*)l, 16, 0, 0);
}

// H layout: [b][g(8)][p(re/im)][s(200)][32 ch] bf16. k in 0..511: k<256 re, else im.
static __device__ inline size_t haddr(int b, int s, int k) {
    int p  = k >> 8;
    int ch = k & 255;
    int g  = ch >> 5;
    int cl = ch & 31;
    return (((((size_t)b * 8 + g) * 2 + p) * SEQ + s) * 32 + cl);
}

// ---------------------------------------------------------------------------
// Unified setup: pre-swizzled weight images + lambda powers/scales.
// ---------------------------------------------------------------------------
__global__ void setup_all_kernel(const float* __restrict__ params_log,
                                 const float* __restrict__ in_br,
                                 const float* __restrict__ in_bi,
                                 const float* __restrict__ in_wr,
                                 const float* __restrict__ in_wi,
                                 const float* __restrict__ out_wr,
                                 const float* __restrict__ out_wi,
                                 const float* __restrict__ w1,
                                 const float* __restrict__ w2,
                                 ushort* __restrict__ Winb,
                                 ushort* __restrict__ W2effb,
                                 ushort* __restrict__ w1b,
                                 ushort* __restrict__ w2b,
                                 float* __restrict__ lam_pow,
                                 float* __restrict__ scale_in,
                                 float* __restrict__ bias_in)
{
    int idx = blockIdx.x * blockDim.x + threadIdx.x;   // NLAY*65536
    int li = idx >> 16;
    int e  = idx & 65535;

    {   // inproj Ws image
        int gp = e >> 12, rem = e & 4095;
        int q = rem >> 3, e8 = rem & 7;
        int r = q >> 4, cs = q & 15;
        int c16 = cs ^ (r & 7);
        int n = (r < 16) ? (gp * 16 + r) : (256 + gp * 16 + (r - 16));
        int d = c16 * 8 + e8;
        float wv = (n < DH) ? in_wr[((size_t)li * DH + n) * D + d]
                            : in_wi[((size_t)li * DH + (n - DH)) * D + d];
        Winb[idx] = f2bf(wv);
    }
    {   // out-proj W2eff image
        int k0c = e >> 13, rem = e & 8191;
        int q = rem >> 3, e8 = rem & 7;
        int r = q >> 3, cs = q & 7;
        int c16 = cs ^ (r & 7);
        int k = k0c * 64 + c16 * 8 + e8;
        float w2v = (k < DH) ? out_wr[((size_t)li * D + r) * DH + k]
                             : -out_wi[((size_t)li * D + r) * DH + (k - DH)];
        W2effb[idx] = f2bf(w2v);
    }
    {   // ffn W1 image: logical [512][128]
        int row = e >> 7, col = e & 127;
        int ffc = row >> 7, rl = row & 127;
        int c16 = col >> 3, e8 = col & 7;
        int cs = c16 ^ (rl & 7);
        w1b[li * 65536 + ffc * 16384 + rl * 128 + cs * 8 + e8] = f2bf(w1[idx]);
    }
    {   // ffn W2 image: logical [128][512]
        int dd2 = e >> 9, kk = e & 511;
        int ffc = kk >> 7, klc = kk & 127;
        int c16 = klc >> 3, e8 = klc & 7;
        int cs = c16 ^ (dd2 & 7);
        w2b[li * 65536 + ffc * 16384 + dd2 * 128 + cs * 8 + e8] = f2bf(w2[idx]);
    }

    if (blockIdx.x < NLAY) {
        int pli = blockIdx.x;
        int c = threadIdx.x;
        const float* pl = params_log + (size_t)pli * 3 * DH;
        float nu = expf(pl[c]);
        float th = expf(pl[DH + c]);
        float ga = expf(pl[2 * DH + c]);
        float mag = expf(-nu);
        float lr = mag * cosf(th);
        float lim = mag * sinf(th);
        float2* lp = (float2*)(lam_pow + (size_t)pli * 65536) + (size_t)c * 128;
        float pr = lr, pi = lim;
        lp[0] = make_float2(pr, pi);
        for (int k = 1; k < 128; ++k) {
            float nr = pr * lr - pi * lim;
            float ni = pr * lim + pi * lr;
            pr = nr; pi = ni;
            lp[k] = make_float2(pr, pi);
        }
        scale_in[pli * 2 * DH + c]      = ga;
        scale_in[pli * 2 * DH + DH + c] = ga;
        bias_in[pli * 2 * DH + c]       = in_br[pli * DH + c] * ga;
        bias_in[pli * 2 * DH + DH + c]  = in_bi[pli * DH + c] * ga;
    }
}

// ---------------------------------------------------------------------------
// R21: build compacted valid-row map. rowmap[i] = flattened (b,s) of the
// i-th valid row (s < len[b]); total[0] = count. One block, 512 threads.
// ---------------------------------------------------------------------------
__global__ __launch_bounds__(512) void build_rowmap_kernel(
    const int* __restrict__ lenp, int Bc,
    int* __restrict__ total, int* __restrict__ rowmap)
{
    __shared__ int pre[513];
    int tid = threadIdx.x;
    int lv = (tid < Bc) ? lenp[tid] : 0;
    pre[tid + 1] = lv;
    if (tid == 0) pre[0] = 0;
    __syncthreads();
    for (int ofs = 1; ofs < 512; ofs <<= 1) {
        int v = pre[tid + 1];
        int vv = (tid + 1 > ofs) ? pre[tid + 1 - ofs] : 0;
        __syncthreads();
        pre[tid + 1] = v + vv;
        __syncthreads();
    }
    if (tid == 0) total[0] = pre[Bc];
    if (tid < Bc) {
        int base = pre[tid];
        int n = lv;
        int rb = tid * SEQ;
        for (int s = 0; s < n; ++s) rowmap[base + s] = rb + s;
    }
}

// ---------------------------------------------------------------------------
// Embedding gather + LayerNorm -> bf16 x (R20: skip causally dead rows).
// ---------------------------------------------------------------------------
__global__ __launch_bounds__(256) void embed_ln_kernel(
    const float* __restrict__ emb, const int* __restrict__ seq,
    const int* __restrict__ lenp,
    const float* __restrict__ g, const float* __restrict__ bt,
    ushort* __restrict__ x)
{
    int row  = blockIdx.x * 4 + (threadIdx.x >> 6);
    int lane = threadIdx.x & 63;
    int b = row / SEQ, s = row - b * SEQ;
    if (s >= lenp[b]) return;
    int item = seq[row];
    float2 v = *(const float2*)(emb + (size_t)item * D + lane * 2);
    float ssum = v.x + v.y;
#pragma unroll
    for (int o = 32; o > 0; o >>= 1) ssum += __shfl_xor(ssum, o);
    float mu = ssum * (1.0f / D);
    float d0 = v.x - mu, d1 = v.y - mu;
    float vs = d0 * d0 + d1 * d1;
#pragma unroll
    for (int o = 32; o > 0; o >>= 1) vs += __shfl_xor(vs, o);
    float rstd = rsqrtf(vs * (1.0f / D) + 1e-5f);
    float2 gg = *(const float2*)(g + lane * 2);
    float2 bb = *(const float2*)(bt + lane * 2);
    unsigned int o2 = pkbf(d0 * rstd * gg.x + bb.x, d1 * rstd * gg.y + bb.y);
    *(unsigned int*)(x + (size_t)row * D + lane * 2) = o2;
}

// ---------------------------------------------------------------------------
// FUSED in-proj + exact tree scan, R20 causal truncation.
// R21: tree levels with half > tb skipped entirely (block-uniform).
// ---------------------------------------------------------------------------
template <bool LAST>
__global__ __launch_bounds__(512) void inproj_scan_kernel(
    const ushort* __restrict__ X, const ushort* __restrict__ Win,
    ushort* __restrict__ H, const float2* __restrict__ lamT,
    const int* __restrict__ seq, const int* __restrict__ lenp,
    const float* __restrict__ scale_in, const float* __restrict__ bias_in)
{
    __shared__ __align__(16) char smem[36864];   // Ws 8192 + xs 28672 (phase A)
    __shared__ float mkf[LPAD];
    char*  Wsm = smem;                           // [32][128] bf16, swizzled
    char*  xs  = smem + 8192;                    // [112][128] bf16, swizzled
    float* stR = (float*)smem;                   // [256][SST] (phase B alias)
    float* stI = stR + LPAD * SST;               // ends at 36864 B
    float2* lamS = (float2*)smem;                // [16][130] (tree phase alias)
    float2* bc   = (float2*)(smem + 16 * 130 * 8);

    int gp = blockIdx.x, b = blockIdx.y;
    int tid = threadIdx.x;
    int l = tid & 63, w = tid >> 6;              // 8 waves
    int ct = w & 1;                              // 0=re tile, 1=im tile
    int rq = w >> 1;                             // row quarter 0..3
    int lr = l & 15, lq = l >> 4;
    int wbase = tid & ~63;

    int c  = tid & 15;                           // scan channel
    int tl = tid >> 4;                           // 0..31
    int t0 = tl * 8;

    // R20 causal bounds (block-uniform)
    int s_b = lenp[b] - 1;                       // 0..199
    int tile_max = s_b >> 4;                     // needed MFMA tiles 0..tile_max
    int nrows = (tile_max + 1) * 16;             // staged rows (tile-rounded)
    int tb = s_b + PADL;                         // last needed padded position

    const float2* myl = lamT + (size_t)(gp * 16 + c) * 128;
    float2 l14[4];
#pragma unroll
    for (int k = 0; k < 4; ++k) l14[k] = myl[k];

    if (tid < LPAD) {
        int t = tid;
        float m = 0.f;
        if (t >= PADL) m = (seq[(size_t)b * SEQ + (t - PADL)] > 0) ? 1.f : 0.f;
        mkf[t] = m;
    }

    // ---- Phase A: async Ws stage + x stage A (rows 0..min(112,nrows))
    const ushort* xrow = X + (size_t)b * SEQ * 128;
    gld_lds16(Win + (size_t)gp * 4096 + (size_t)tid * 8,
              Wsm + (size_t)wbase * 16);
#pragma unroll
    for (int it = 0; it < 4; ++it) {
        int idx = it * 512 + tid;
        if (idx < 112 * 16) {
            int r = idx >> 4, c16 = idx & 15;
            if (r < nrows) {
                uint4 v = *(const uint4*)(xrow + (size_t)r * 128 + c16 * 8);
                *(uint4*)(xs + r * 256 + ((c16 ^ (r & 7)) * 16)) = v;
            }
        }
    }
    __syncthreads();

    bf16x8 wf[4];
#pragma unroll
    for (int kk = 0; kk < 4; ++kk) {
        int ca = kk * 4 + lq;
        int wr = ct * 16 + lr;
        wf[kk] = *(const bf16x8*)(Wsm + wr * 256 + ((ca ^ (wr & 7)) * 16));
    }
    int tstart = rq ? (3 * rq + 1) : 0;          // 0 / 4 / 7 / 10
    int tcnt   = rq ? 3 : 4;
    floatx4 acc[4];
#pragma unroll
    for (int tt = 0; tt < 4; ++tt) acc[tt] = (floatx4)0.f;

    if (rq < 2) {
#pragma unroll
        for (int tt = 0; tt < 4; ++tt) {
            if (tt < tcnt && (tstart + tt) <= tile_max) {
                int t  = tstart + tt;
                int ar = t * 16 + lr;
#pragma unroll
                for (int kk = 0; kk < 4; ++kk) {
                    int ca = kk * 4 + lq;
                    bf16x8 af = *(const bf16x8*)(xs + ar * 256 + ((ca ^ (ar & 7)) * 16));
                    acc[tt] = __builtin_amdgcn_mfma_f32_16x16x32_bf16(wf[kk], af, acc[tt], 0, 0, 0);
                }
            }
        }
    }
    __syncthreads();

    // stage B: rows 112..nrows-1 -> xs local rows 0.. (zeros for gr >= 200)
    if (nrows > 112) {
#pragma unroll
        for (int it = 0; it < 3; ++it) {
            int idx = it * 512 + tid;                // 96*16 = 1536
            int r = idx >> 4, c16 = idx & 15;
            int gr = 112 + r;
            if (gr < nrows) {
                uint4 v = make_uint4(0u, 0u, 0u, 0u);
                if (gr < 200) v = *(const uint4*)(xrow + (size_t)gr * 128 + c16 * 8);
                *(uint4*)(xs + r * 256 + ((c16 ^ (r & 7)) * 16)) = v;
            }
        }
    }
    __syncthreads();

    if (rq >= 2) {
#pragma unroll
        for (int tt = 0; tt < 4; ++tt) {
            if (tt < tcnt && (tstart + tt) <= tile_max) {
                int t  = tstart + tt;
                int ar = (t - 7) * 16 + lr;
#pragma unroll
                for (int kk = 0; kk < 4; ++kk) {
                    int ca = kk * 4 + lq;
                    bf16x8 af = *(const bf16x8*)(xs + ar * 256 + ((ca ^ (ar & 7)) * 16));
                    acc[tt] = __builtin_amdgcn_mfma_f32_16x16x32_bf16(wf[kk], af, acc[tt], 0, 0, 0);
                }
            }
        }
    }
    __syncthreads();

    // ---- Phase B: zero pad rows + epilogue (rows <= s_b) -> stR/stI
    for (int idx = tid; idx < PADL * SST; idx += 512) { stR[idx] = 0.f; stI[idx] = 0.f; }
    {
        float4 g4 = *(const float4*)(scale_in + ct * 256 + gp * 16 + lq * 4);
        float4 b4 = *(const float4*)(bias_in  + ct * 256 + gp * 16 + lq * 4);
        float* dst = ct ? stI : stR;
#pragma unroll
        for (int tt = 0; tt < 4; ++tt) {
            if (tt < tcnt && (tstart + tt) <= tile_max) {
                int t = tstart + tt;
                int s = t * 16 + lr;
                if (s <= s_b) {
                    int pos = s + PADL;
                    dst[pos * SST + lq * 4 + 0] = acc[tt][0] * g4.x + b4.x;
                    dst[pos * SST + lq * 4 + 1] = acc[tt][1] * g4.y + b4.y;
                    dst[pos * SST + lq * 4 + 2] = acc[tt][2] * g4.z + b4.z;
                    dst[pos * SST + lq * 4 + 3] = acc[tt][3] * g4.w + b4.w;
                }
            }
        }
    }
    __syncthreads();

    float xr[8], xi[8], mf[8];
#pragma unroll
    for (int k = 0; k < 8; ++k) {
        xr[k] = stR[(t0 + k) * SST + c];
        xi[k] = stI[(t0 + k) * SST + c];
        mf[k] = mkf[t0 + k];
    }
    __syncthreads();

    {
        const char* src = (const char*)(lamT + (size_t)gp * 16 * 128);
#pragma unroll
        for (int it = 0; it < 2; ++it) {
            int idx = it * 512 + tid;
            int row = idx >> 6, c4 = idx & 63;
            *(uint4*)((char*)lamS + row * 1040 + c4 * 16) =
                *(const uint4*)(src + row * 1024 + c4 * 16);
        }
    }

    // levels 1-3: thread-internal (only threads with needed positions)
    if (t0 <= tb) {
#pragma unroll
        for (int k = 0; k < 8; k += 2) {
            float sr = xr[k] * mf[k], si = xi[k] * mf[k];
            xr[k+1] += l14[0].x * sr - l14[0].y * si;
            xi[k+1] += l14[0].x * si + l14[0].y * sr;
        }
#pragma unroll
        for (int k = 1; k < 8; k += 4) {
            float sr = xr[k] * mf[k], si = xi[k] * mf[k];
            xr[k+1] += l14[0].x * sr - l14[0].y * si;
            xi[k+1] += l14[0].x * si + l14[0].y * sr;
            xr[k+2] += l14[1].x * sr - l14[1].y * si;
            xi[k+2] += l14[1].x * si + l14[1].y * sr;
        }
        {
            float sr = xr[3] * mf[3], si = xi[3] * mf[3];
#pragma unroll
            for (int j = 0; j < 4; ++j) {
                xr[4+j] += l14[j].x * sr - l14[j].y * si;
                xi[4+j] += l14[j].x * si + l14[j].y * sr;
            }
        }
    }

    // levels 4-8: LDS end-value broadcast. R21: skip whole level (incl.
    // barrier) when no target position <= tb exists (half > tb, uniform).
#pragma unroll
    for (int i = 4; i <= 8; ++i) {
        int half = 1 << (i - 1);
        if (half > tb) continue;       // block-uniform: no dst t in (half..tb]
        int buf  = (i & 1) * 544;
        bc[buf + tl * 17 + c] = make_float2(xr[7], xi[7]);
        __syncthreads();
        int off = t0 & ((half << 1) - 1);
        if (off >= half && t0 <= tb) {
            int src = t0 - off + half - 1;
            float m = mkf[src];
            float2 sv = bc[buf + (src >> 3) * 17 + c];
            float sr = sv.x * m, si = sv.y * m;
            int e = off - half;
            const float2* lp = lamS + c * 130 + e;
#pragma unroll
            for (int k = 0; k < 8; ++k) {
                float2 lv = lp[k];
                xr[k] += lv.x * sr - lv.y * si;
                xi[k] += lv.x * si + lv.y * sr;
            }
        }
    }
    __syncthreads();

#pragma unroll
    for (int k = 0; k < 8; ++k) {
        stR[(t0 + k) * SST + c] = xr[k];
        stI[(t0 + k) * SST + c] = xi[k];
    }
    __syncthreads();

    if (LAST) {
        if (tid < 32) {
            int t = tb;
            int p = tid >> 4, cc = tid & 15;
            float v = (p ? stI : stR)[t * SST + cc];
            H[(size_t)b * 512 + p * 256 + gp * 16 + cc] = f2bf(v);
        }
    } else {
        int g  = gp >> 1;
        int hc = (gp & 1) * 16;
        ushort* baseg = H + (size_t)(b * 8 + g) * 2 * SEQ * 32 + hc;
#pragma unroll
        for (int it = 0; it < 4; ++it) {
            int idx4 = it * 512 + tid;
            if (idx4 < 2 * SEQ * 4) {
                int q  = idx4 & 3;
                int ps = idx4 >> 2;
                int p  = ps >= SEQ;
                int s  = ps - p * SEQ;
                if (s > s_b) continue;           // causally dead, never read
                int t  = s + PADL;
                const float* sp = (p ? stI : stR) + t * SST + q * 4;
                float2 a = *(const float2*)(sp);
                float2 d = *(const float2*)(sp + 2);
                uint2 raw;
                raw.x = pkbf(a.x, a.y);
                raw.y = pkbf(d.x, d.y);
                *(uint2*)(baseg + (size_t)ps * 32 + q * 4) = raw;
            }
        }
    }
}

// ---------------------------------------------------------------------------
// Out-proj GEMM (full path), 512 threads, 256-row M-tile over COMPACTED rows
// (R21): row i = rowmap[i]; blocks beyond total exit.
// ---------------------------------------------------------------------------
__global__ __launch_bounds__(512) void outproj_kernel(
    const ushort* __restrict__ A, const ushort* __restrict__ Wimg,
    ushort* __restrict__ Cout,
    const int* __restrict__ rowmap, const int* __restrict__ totalp,
    const float* __restrict__ e0,
    const ushort* __restrict__ res,
    const float* __restrict__ lng, const float* __restrict__ lnb)
{
    int m0 = blockIdx.x * 256;
    int total = totalp[0];
    if (m0 >= total) return;
    __shared__ __align__(16) char As[32768];
    __shared__ __align__(16) char Bs[16384];
    __shared__ float2 lnS[2][256];
    int tid = threadIdx.x;
    int l = tid & 63, w = tid >> 6;
    int chh = w >> 2;
    int rh  = w & 3;
    int lr = l & 15, lq = l >> 4;
    int wbase = tid & ~63;

    int cst = tid & 7;
    int rr  = tid >> 3;
    int sb[4], ss[4];
#pragma unroll
    for (int it = 0; it < 4; ++it) {
        int gr = m0 + it * 64 + rr;
        if (gr >= total) gr = total - 1;
        int rm = rowmap[gr];
        sb[it] = rm / SEQ; ss[it] = rm - sb[it] * SEQ;
    }

    floatx4 acc[4][4];
#pragma unroll
    for (int i = 0; i < 4; ++i)
#pragma unroll
        for (int j = 0; j < 4; ++j) acc[i][j] = (floatx4)0.f;

    for (int k0c = 0; k0c < 8; ++k0c) {
        int k0 = k0c * 64;
        {
            const ushort* img = Wimg + (size_t)k0c * 8192;
#pragma unroll
            for (int it = 0; it < 2; ++it)
                gld_lds16(img + (size_t)(it * 512 + tid) * 8,
                          Bs + (size_t)(it * 512 + wbase) * 16);
        }
#pragma unroll
        for (int it = 0; it < 4; ++it) {
            int r = it * 64 + rr;
            uint4 va = *(const uint4*)(A + haddr(sb[it], ss[it], k0 + cst * 8));
            *(uint4*)(As + r * 128 + ((cst ^ (r & 7)) * 16)) = va;
        }
        __syncthreads();
#pragma unroll
        for (int kk = 0; kk < 2; ++kk) {
            bf16x8 wf[4], af[4];
            int ca = kk * 4 + lq;
#pragma unroll
            for (int i = 0; i < 4; ++i) {
                int rb = chh * 64 + i * 16 + lr;
                wf[i] = *(const bf16x8*)(Bs + rb * 128 + ((ca ^ (rb & 7)) * 16));
                int ra = rh * 64 + i * 16 + lr;
                af[i] = *(const bf16x8*)(As + ra * 128 + ((ca ^ (ra & 7)) * 16));
            }
#pragma unroll
            for (int i = 0; i < 4; ++i)
#pragma unroll
                for (int j = 0; j < 4; ++j)
                    acc[i][j] = __builtin_amdgcn_mfma_f32_16x16x32_bf16(
                        wf[i], af[j], acc[i][j], 0, 0, 0);
        }
        __syncthreads();
    }

    int chb[4], arow[4], rmj[4];
#pragma unroll
    for (int i = 0; i < 4; ++i) chb[i] = chh * 64 + i * 16 + lq * 4;
#pragma unroll
    for (int j = 0; j < 4; ++j) {
        arow[j] = m0 + rh * 64 + j * 16 + lr;
        int rc = arow[j] < total ? arow[j] : total - 1;
        rmj[j] = rowmap[rc];
    }

    {
        float4 bias[4], gv[4], bv[4];
#pragma unroll
        for (int i = 0; i < 4; ++i) {
            bias[i] = *(const float4*)(e0 + chb[i]);
            gv[i]   = *(const float4*)(lng + chb[i]);
            bv[i]   = *(const float4*)(lnb + chb[i]);
        }
#pragma unroll
        for (int j = 0; j < 4; ++j) {
#pragma unroll
            for (int i = 0; i < 4; ++i) {
                ushort4 r4 = *(const ushort4*)(res + (size_t)rmj[j] * 128 + chb[i]);
                acc[i][j][0] += ((const float*)&bias[i])[0] + bf2f(r4.x);
                acc[i][j][1] += ((const float*)&bias[i])[1] + bf2f(r4.y);
                acc[i][j][2] += ((const float*)&bias[i])[2] + bf2f(r4.z);
                acc[i][j][3] += ((const float*)&bias[i])[3] + bf2f(r4.w);
            }
        }
#pragma unroll
        for (int j = 0; j < 4; ++j) {
            float s = 0.f, q = 0.f;
#pragma unroll
            for (int i = 0; i < 4; ++i)
#pragma unroll
                for (int reg = 0; reg < 4; ++reg) {
                    float v = acc[i][j][reg];
                    s += v; q += v * v;
                }
            s += __shfl_xor(s, 16); q += __shfl_xor(q, 16);
            s += __shfl_xor(s, 32); q += __shfl_xor(q, 32);
            if (lq == 0) lnS[chh][rh * 64 + j * 16 + lr] = make_float2(s, q);
        }
        __syncthreads();
#pragma unroll
        for (int j = 0; j < 4; ++j) {
            int rl = rh * 64 + j * 16 + lr;
            float2 s0 = lnS[0][rl], s1 = lnS[1][rl];
            float mu  = (s0.x + s1.x) * (1.0f / 128.0f);
            float var = (s0.y + s1.y) * (1.0f / 128.0f) - mu * mu;
            float rstd = rsqrtf(var + 1e-5f);
            if (arow[j] < total) {
#pragma unroll
                for (int i = 0; i < 4; ++i) {
                    uint2 u;
                    u.x = pkbf((acc[i][j][0] - mu) * rstd * ((const float*)&gv[i])[0] + ((const float*)&bv[i])[0],
                               (acc[i][j][1] - mu) * rstd * ((const float*)&gv[i])[1] + ((const float*)&bv[i])[1]);
                    u.y = pkbf((acc[i][j][2] - mu) * rstd * ((const float*)&gv[i])[2] + ((const float*)&bv[i])[2],
                               (acc[i][j][3] - mu) * rstd * ((const float*)&gv[i])[3] + ((const float*)&bv[i])[3]);
                    *(uint2*)(Cout + (size_t)rmj[j] * 128 + chb[i]) = u;
                }
            }
        }
    }
}

// ---------------------------------------------------------------------------
// Out-proj LAST (R19): compact M=Bc rows from Hc[b][512].
// ---------------------------------------------------------------------------
__global__ __launch_bounds__(512) void outproj_last_kernel(
    const ushort* __restrict__ Hc, const ushort* __restrict__ Wimg,
    ushort* __restrict__ xc, int Bc,
    const float* __restrict__ e0,
    const ushort* __restrict__ Xres, const int* __restrict__ lenp,
    const float* __restrict__ lng, const float* __restrict__ lnb)
{
    __shared__ __align__(16) char As[32768];
    __shared__ __align__(16) char Bs[16384];
    __shared__ float2 lnS[2][256];
    int tid = threadIdx.x;
    int l = tid & 63, w = tid >> 6;
    int chh = w >> 2;
    int rh  = w & 3;
    int lr = l & 15, lq = l >> 4;
    int m0 = blockIdx.x * 256;
    int wbase = tid & ~63;

    int cst = tid & 7;
    int rr  = tid >> 3;

    floatx4 acc[4][4];
#pragma unroll
    for (int i = 0; i < 4; ++i)
#pragma unroll
        for (int j = 0; j < 4; ++j) acc[i][j] = (floatx4)0.f;

    for (int k0c = 0; k0c < 8; ++k0c) {
        int k0 = k0c * 64;
        {
            const ushort* img = Wimg + (size_t)k0c * 8192;
#pragma unroll
            for (int it = 0; it < 2; ++it)
                gld_lds16(img + (size_t)(it * 512 + tid) * 8,
                          Bs + (size_t)(it * 512 + wbase) * 16);
        }
#pragma unroll
        for (int it = 0; it < 4; ++it) {
            int r = it * 64 + rr;
            int gr = m0 + r; if (gr >= Bc) gr = Bc - 1;
            uint4 va = *(const uint4*)(Hc + (size_t)gr * 512 + k0 + cst * 8);
            *(uint4*)(As + r * 128 + ((cst ^ (r & 7)) * 16)) = va;
        }
        __syncthreads();
#pragma unroll
        for (int kk = 0; kk < 2; ++kk) {
            bf16x8 wf[4], af[4];
            int ca = kk * 4 + lq;
#pragma unroll
            for (int i = 0; i < 4; ++i) {
                int rb = chh * 64 + i * 16 + lr;
                wf[i] = *(const bf16x8*)(Bs + rb * 128 + ((ca ^ (rb & 7)) * 16));
                int ra = rh * 64 + i * 16 + lr;
                af[i] = *(const bf16x8*)(As + ra * 128 + ((ca ^ (ra & 7)) * 16));
            }
#pragma unroll
            for (int i = 0; i < 4; ++i)
#pragma unroll
                for (int j = 0; j < 4; ++j)
                    acc[i][j] = __builtin_amdgcn_mfma_f32_16x16x32_bf16(
                        wf[i], af[j], acc[i][j], 0, 0, 0);
        }
        __syncthreads();
    }

    int chb[4], arow[4];
#pragma unroll
    for (int i = 0; i < 4; ++i) chb[i] = chh * 64 + i * 16 + lq * 4;
#pragma unroll
    for (int j = 0; j < 4; ++j) arow[j] = m0 + rh * 64 + j * 16 + lr;

    {
        float4 bias[4], gv[4], bv[4];
#pragma unroll
        for (int i = 0; i < 4; ++i) {
            bias[i] = *(const float4*)(e0 + chb[i]);
            gv[i]   = *(const float4*)(lng + chb[i]);
            bv[i]   = *(const float4*)(lnb + chb[i]);
        }
#pragma unroll
        for (int j = 0; j < 4; ++j) {
            int br = arow[j] < Bc ? arow[j] : Bc - 1;
            int sb_ = lenp[br] - 1;
            const ushort* rbase = Xres + ((size_t)br * SEQ + sb_) * 128;
#pragma unroll
            for (int i = 0; i < 4; ++i) {
                ushort4 r4 = *(const ushort4*)(rbase + chb[i]);
                acc[i][j][0] += ((const float*)&bias[i])[0] + bf2f(r4.x);
                acc[i][j][1] += ((const float*)&bias[i])[1] + bf2f(r4.y);
                acc[i][j][2] += ((const float*)&bias[i])[2] + bf2f(r4.z);
                acc[i][j][3] += ((const float*)&bias[i])[3] + bf2f(r4.w);
            }
        }
#pragma unroll
        for (int j = 0; j < 4; ++j) {
            float s = 0.f, q = 0.f;
#pragma unroll
            for (int i = 0; i < 4; ++i)
#pragma unroll
                for (int reg = 0; reg < 4; ++reg) {
                    float v = acc[i][j][reg];
                    s += v; q += v * v;
                }
            s += __shfl_xor(s, 16); q += __shfl_xor(q, 16);
            s += __shfl_xor(s, 32); q += __shfl_xor(q, 32);
            if (lq == 0) lnS[chh][rh * 64 + j * 16 + lr] = make_float2(s, q);
        }
        __syncthreads();
#pragma unroll
        for (int j = 0; j < 4; ++j) {
            int rl = rh * 64 + j * 16 + lr;
            float2 s0 = lnS[0][rl], s1 = lnS[1][rl];
            float mu  = (s0.x + s1.x) * (1.0f / 128.0f);
            float var = (s0.y + s1.y) * (1.0f / 128.0f) - mu * mu;
            float rstd = rsqrtf(var + 1e-5f);
            if (arow[j] < Bc) {
#pragma unroll
                for (int i = 0; i < 4; ++i) {
                    uint2 u;
                    u.x = pkbf((acc[i][j][0] - mu) * rstd * ((const float*)&gv[i])[0] + ((const float*)&bv[i])[0],
                               (acc[i][j][1] - mu) * rstd * ((const float*)&gv[i])[1] + ((const float*)&bv[i])[1]);
                    u.y = pkbf((acc[i][j][2] - mu) * rstd * ((const float*)&gv[i])[2] + ((const float*)&bv[i])[2],
                               (acc[i][j][3] - mu) * rstd * ((const float*)&gv[i])[3] + ((const float*)&bv[i])[3]);
                    *(uint2*)(xc + (size_t)arow[j] * 128 + chb[i]) = u;
                }
            }
        }
    }
}

// ---------------------------------------------------------------------------
// Fused FFN v6 + R21 row compaction: if rowmap != nullptr, logical rows are
// compacted (actual row = rowmap[i], count = totalp[0]); else rows 0..Mtot.
// ---------------------------------------------------------------------------
__global__ __launch_bounds__(256) void ffn_fused_kernel(
    ushort* __restrict__ X, const ushort* __restrict__ W1,
    const ushort* __restrict__ W2,
    const float* __restrict__ b1, const float* __restrict__ b2,
    const float* __restrict__ lng, const float* __restrict__ lnb,
    int Mtot, const int* __restrict__ rowmap, const int* __restrict__ totalp)
{
    int m0 = blockIdx.x * 64;
    int total = totalp ? totalp[0] : Mtot;
    if (m0 >= total) return;
    __shared__ __align__(16) char Bs[32768];   // pre-swizzled 32KB weight chunk
    __shared__ ushort Ps[64 * 136];     // P tile, row stride 136
    __shared__ float2 lnS[2][64];
    int tid = threadIdx.x;
    int l = tid & 63, w = tid >> 6;
    int chh = w >> 1, rh = w & 1;
    int lr = l & 15, lq = l >> 4;
    int wbase = tid & ~63;              // wave-uniform chunk base

    // logical -> actual row for this thread's 2 rows
    int arow[2], rmrow[2];
#pragma unroll
    for (int j = 0; j < 2; ++j) {
        arow[j] = m0 + rh * 32 + j * 16 + lr;
        int rc = arow[j] < total ? arow[j] : total - 1;
        rmrow[j] = rowmap ? rowmap[rc] : rc;
    }

    bf16x8 af_x[8];
#pragma unroll
    for (int j = 0; j < 2; ++j)
#pragma unroll
        for (int kk2 = 0; kk2 < 4; ++kk2) {
            int k = kk2 * 32 + lq * 8;
            af_x[(j << 2) | kk2] = *(const bf16x8*)(X + (size_t)rmrow[j] * 128 + k);
        }

    floatx4 acc2[4][2];
#pragma unroll
    for (int i = 0; i < 4; ++i)
#pragma unroll
        for (int j = 0; j < 2; ++j) acc2[i][j] = (floatx4)0.f;

    for (int ffc = 0; ffc < 4; ++ffc) {
        if (ffc) __syncthreads();
        {
            const ushort* img = W1 + (size_t)ffc * 16384;
#pragma unroll
            for (int it = 0; it < 8; ++it)
                gld_lds16(img + (size_t)(it * 256 + tid) * 8,
                          Bs + (size_t)(it * 256 + wbase) * 16);
        }
        __syncthreads();

        floatx4 acc1[4][2];
#pragma unroll
        for (int i = 0; i < 4; ++i)
#pragma unroll
            for (int j = 0; j < 2; ++j) acc1[i][j] = (floatx4)0.f;
#pragma unroll
        for (int kk2 = 0; kk2 < 4; ++kk2) {
            int ca = kk2 * 4 + lq;
            bf16x8 wf[4];
#pragma unroll
            for (int i = 0; i < 4; ++i) {
                int rb = chh * 64 + i * 16 + lr;
                wf[i] = *(const bf16x8*)(Bs + rb * 256 + ((ca ^ (rb & 7)) * 16));
            }
#pragma unroll
            for (int i = 0; i < 4; ++i)
#pragma unroll
                for (int j = 0; j < 2; ++j)
                    acc1[i][j] = __builtin_amdgcn_mfma_f32_16x16x32_bf16(
                        wf[i], af_x[(j << 2) | kk2], acc1[i][j], 0, 0, 0);
        }

#pragma unroll
        for (int j = 0; j < 2; ++j) {
            int rowl = rh * 32 + j * 16 + lr;
#pragma unroll
            for (int i = 0; i < 4; ++i) {
                int ch0 = chh * 64 + i * 16 + lq * 4;
                float4 bv = *(const float4*)(b1 + ffc * 128 + ch0);
                float g0, g1, g2, g3, v;
                v = acc1[i][j][0] + bv.x; g0 = 0.5f * v * (1.0f + erff(v * 0.70710678118654752f));
                v = acc1[i][j][1] + bv.y; g1 = 0.5f * v * (1.0f + erff(v * 0.70710678118654752f));
                v = acc1[i][j][2] + bv.z; g2 = 0.5f * v * (1.0f + erff(v * 0.70710678118654752f));
                v = acc1[i][j][3] + bv.w; g3 = 0.5f * v * (1.0f + erff(v * 0.70710678118654752f));
                uint2 u; u.x = pkbf(g0, g1); u.y = pkbf(g2, g3);
                *(uint2*)(Ps + rowl * 136 + ch0) = u;
            }
        }
        __syncthreads();

        {
            const ushort* img = W2 + (size_t)ffc * 16384;
#pragma unroll
            for (int it = 0; it < 8; ++it)
                gld_lds16(img + (size_t)(it * 256 + tid) * 8,
                          Bs + (size_t)(it * 256 + wbase) * 16);
        }
        __syncthreads();

#pragma unroll
        for (int kk2 = 0; kk2 < 4; ++kk2) {
            int ca = kk2 * 4 + lq;
            bf16x8 wf[4], af[2];
#pragma unroll
            for (int i = 0; i < 4; ++i) {
                int rb = chh * 64 + i * 16 + lr;
                wf[i] = *(const bf16x8*)(Bs + rb * 256 + ((ca ^ (rb & 7)) * 16));
            }
#pragma unroll
            for (int j = 0; j < 2; ++j) {
                int rowl = rh * 32 + j * 16 + lr;
                af[j] = *(const bf16x8*)(Ps + rowl * 136 + kk2 * 32 + lq * 8);
            }
#pragma unroll
            for (int i = 0; i < 4; ++i)
#pragma unroll
                for (int j = 0; j < 2; ++j)
                    acc2[i][j] = __builtin_amdgcn_mfma_f32_16x16x32_bf16(
                        wf[i], af[j], acc2[i][j], 0, 0, 0);
        }
    }

    int chb[4];
#pragma unroll
    for (int i = 0; i < 4; ++i) chb[i] = chh * 64 + i * 16 + lq * 4;

    float4 bias[4], gv[4], bv[4];
#pragma unroll
    for (int i = 0; i < 4; ++i) {
        bias[i] = *(const float4*)(b2 + chb[i]);
        gv[i]   = *(const float4*)(lng + chb[i]);
        bv[i]   = *(const float4*)(lnb + chb[i]);
    }
#pragma unroll
    for (int j = 0; j < 2; ++j) {
#pragma unroll
        for (int i = 0; i < 4; ++i) {
            ushort4 r4 = *(const ushort4*)(X + (size_t)rmrow[j] * 128 + chb[i]);
            acc2[i][j][0] += ((const float*)&bias[i])[0] + bf2f(r4.x);
            acc2[i][j][1] += ((const float*)&bias[i])[1] + bf2f(r4.y);
            acc2[i][j][2] += ((const float*)&bias[i])[2] + bf2f(r4.z);
            acc2[i][j][3] += ((const float*)&bias[i])[3] + bf2f(r4.w);
        }
    }
#pragma unroll
    for (int j = 0; j < 2; ++j) {
        float s = 0.f, q = 0.f;
#pragma unroll
        for (int i = 0; i < 4; ++i)
#pragma unroll
            for (int reg = 0; reg < 4; ++reg) {
                float v = acc2[i][j][reg];
                s += v; q += v * v;
            }
        s += __shfl_xor(s, 16); q += __shfl_xor(q, 16);
        s += __shfl_xor(s, 32); q += __shfl_xor(q, 32);
        if (lq == 0) lnS[chh][rh * 32 + j * 16 + lr] = make_float2(s, q);
    }
    __syncthreads();
#pragma unroll
    for (int j = 0; j < 2; ++j) {
        int rl = rh * 32 + j * 16 + lr;
        float2 s0 = lnS[0][rl], s1 = lnS[1][rl];
        float mu  = (s0.x + s1.x) * (1.0f / 128.0f);
        float var = (s0.y + s1.y) * (1.0f / 128.0f) - mu * mu;
        float rstd = rsqrtf(var + 1e-5f);
        if (arow[j] < total) {
#pragma unroll
            for (int i = 0; i < 4; ++i) {
                uint2 u;
                u.x = pkbf((acc2[i][j][0] - mu) * rstd * ((const float*)&gv[i])[0] + ((const float*)&bv[i])[0],
                           (acc2[i][j][1] - mu) * rstd * ((const float*)&gv[i])[1] + ((const float*)&bv[i])[1]);
                u.y = pkbf((acc2[i][j][2] - mu) * rstd * ((const float*)&gv[i])[2] + ((const float*)&bv[i])[2],
                           (acc2[i][j][3] - mu) * rstd * ((const float*)&gv[i])[3] + ((const float*)&bv[i])[3]);
                *(uint2*)(X + (size_t)rmrow[j] * 128 + chb[i]) = u;
            }
        }
    }
}

// ---------------------------------------------------------------------------
__global__ void gather_final_kernel(const ushort* __restrict__ xc,
                                    float* __restrict__ out, int b0, int Bc)
{
    int i = blockIdx.x * 256 + threadIdx.x;
    if (i >= Bc * D) return;
    out[(size_t)b0 * D + i] = bf2f(xc[i]);
}

// ---------------------------------------------------------------------------
extern "C" void kernel_launch(void* const* d_in, const int* in_sizes, int n_in,
                              void* d_out, int out_size, void* d_ws, size_t ws_size,
                              hipStream_t stream)
{
    const float* token_emb  = (const float*)d_in[0];
    const float* emb_ln_g   = (const float*)d_in[1];
    const float* emb_ln_b   = (const float*)d_in[2];
    const float* params_log = (const float*)d_in[3];
    const float* in_wr      = (const float*)d_in[4];
    const float* in_wi      = (const float*)d_in[5];
    const float* in_br      = (const float*)d_in[6];
    const float* in_bi      = (const float*)d_in[7];
    const float* out_wr     = (const float*)d_in[8];
    const float* out_wi     = (const float*)d_in[9];
    const float* out_br     = (const float*)d_in[10];
    const float* lru_ln_g   = (const float*)d_in[12];
    const float* lru_ln_b   = (const float*)d_in[13];
    const float* w1         = (const float*)d_in[14];
    const float* b1         = (const float*)d_in[15];
    const float* w2         = (const float*)d_in[16];
    const float* b2         = (const float*)d_in[17];
    const float* ffn_ln_g   = (const float*)d_in[18];
    const float* ffn_ln_b   = (const float*)d_in[19];
    const int*   item_seq   = (const int*)d_in[20];
    const int*   item_seq_len = (const int*)d_in[21];
    float* out = (float*)d_out;

    char* ws = (char*)d_ws;
    ushort* Winb   = (ushort*)ws;                      ws += NLAY * 65536 * 2;
    ushort* W2effb = (ushort*)ws;                      ws += NLAY * 65536 * 2;
    ushort* w1b    = (ushort*)ws;                      ws += NLAY * 65536 * 2;
    ushort* w2b    = (ushort*)ws;                      ws += NLAY * 65536 * 2;
    float* lam_pow = (float*)ws;                       ws += NLAY * 65536 * 4;
    float* scale_in = (float*)ws;                      ws += NLAY * 512 * 4;
    float* bias_in  = (float*)ws;                      ws += NLAY * 512 * 4;
    size_t table_bytes = (size_t)(ws - (char*)d_ws);

    int Bc = B_TOT;
    while (Bc > 32) {
        size_t need = table_bytes
                    + (size_t)Bc * SEQ * (D * 2 + 2 * DH * 2)
                    + (size_t)(Bc * SEQ + 8) * 4 + 1024;
        if (need <= ws_size) break;
        Bc >>= 1;
    }
    ushort* xb = (ushort*)ws;                          ws += (size_t)Bc * SEQ * D * 2;
    ushort* hb = (ushort*)ws;                          ws += (size_t)Bc * SEQ * 2 * DH * 2;
    int* totalp = (int*)ws;                            ws += 8 * 4;
    int* rowmap = (int*)ws;
    ushort* Hc = hb;                                   // compact H (Bc*512), aliases hb
    ushort* xc = hb + (size_t)Bc * 512;                // compact x (Bc*128)

    setup_all_kernel<<<NLAY * 65536 / 256, 256, 0, stream>>>(
        params_log, in_br, in_bi, in_wr, in_wi, out_wr, out_wi, w1, w2,
        Winb, W2effb, w1b, w2b, lam_pow, scale_in, bias_in);

    for (int b0 = 0; b0 < B_TOT; b0 += Bc) {
        int M = Bc * SEQ;
        const int* lenp = item_seq_len + b0;
        build_rowmap_kernel<<<1, 512, 0, stream>>>(lenp, Bc, totalp, rowmap);
        embed_ln_kernel<<<M / 4, 256, 0, stream>>>(
            token_emb, item_seq + (size_t)b0 * SEQ, lenp,
            emb_ln_g, emb_ln_b, xb);

        for (int li = 0; li < NLAY; ++li) {
            if (li < NLAY - 1) {
                inproj_scan_kernel<false><<<dim3(16, Bc), 512, 0, stream>>>(
                    xb, Winb + (size_t)li * 65536, hb,
                    (const float2*)(lam_pow + (size_t)li * 65536),
                    item_seq + (size_t)b0 * SEQ, lenp,
                    scale_in + li * 512, bias_in + li * 512);
                outproj_kernel<<<dim3(M / 256), 512, 0, stream>>>(
                    hb, W2effb + (size_t)li * 65536, xb, rowmap, totalp,
                    out_br + li * D, xb,
                    lru_ln_g + li * D, lru_ln_b + li * D);
                ffn_fused_kernel<<<dim3(M / 64), 256, 0, stream>>>(
                    xb, w1b + (size_t)li * 65536, w2b + (size_t)li * 65536,
                    b1 + li * DFF, b2 + li * D,
                    ffn_ln_g + li * D, ffn_ln_b + li * D, M, rowmap, totalp);
            } else {
                inproj_scan_kernel<true><<<dim3(16, Bc), 512, 0, stream>>>(
                    xb, Winb + (size_t)li * 65536, Hc,
                    (const float2*)(lam_pow + (size_t)li * 65536),
                    item_seq + (size_t)b0 * SEQ, lenp,
                    scale_in + li * 512, bias_in + li * 512);
                outproj_last_kernel<<<dim3((Bc + 255) / 256), 512, 0, stream>>>(
                    Hc, W2effb + (size_t)li * 65536, xc, Bc,
                    out_br + li * D, xb, lenp,
                    lru_ln_g + li * D, lru_ln_b + li * D);
                ffn_fused_kernel<<<dim3((Bc + 63) / 64), 256, 0, stream>>>(
                    xc, w1b + (size_t)li * 65536, w2b + (size_t)li * 65536,
                    b1 + li * DFF, b2 + li * D,
                    ffn_ln_g + li * D, ffn_ln_b + li * D, Bc,
                    (const int*)0, (const int*)0);
            }
        }
        gather_final_kernel<<<(Bc * D + 255) / 256, 256, 0, stream>>>(
            xc, out, b0, Bc);
    }
}